// Round 2
// baseline (1700.468 us; speedup 1.0000x reference)
//
#include <hip/hip_runtime.h>
#include <hip/hip_bf16.h>

// ---------------- workspace layout (float offsets) ----------------
// q/k/v [32,1024,64]  att [32,1024,64]
// spart[32,16,1024] (+ attT [32,64,1024] at +2M)  score [32,1024]   idx [32,256]
// cout [8,256,64,64]      y     [8,256,64,64]     t1   [8,256,64,64]
// aliases: wt -> xdT region; dwt -> spart region; attT -> spart +2M
//          coutT -> t1 region (dead until k_dw)
//          dpart -> y region (4 x 2M ci-split partials; dead until k_ybuild)
constexpr size_t OFF_XD    = 0;
constexpr size_t OFF_Q     = 2097152;
constexpr size_t OFF_K     = 4194304;
constexpr size_t OFF_V     = 6291456;
constexpr size_t OFF_ATT   = 8388608;
constexpr size_t OFF_SPART = 10485760;
constexpr size_t OFF_SCORE = 14680064;
constexpr size_t OFF_IDX   = 14712832;
constexpr size_t OFF_COUT  = 14721024;
constexpr size_t OFF_Y     = 23109632;
constexpr size_t OFF_T1    = 31498240;
constexpr size_t WS_FLOATS = 39886848;

// ---------------- 0a. transpose down_w [co][ci][kh][kw] -> dwt [ci][kk][co] ----
__global__ __launch_bounds__(256) void k_wt_dn(const float* __restrict__ w,
                                               float* __restrict__ dwt) {
  int idx = blockIdx.x * 256 + threadIdx.x;   // 1,048,576
  int co = idx & 255;
  int kk = (idx >> 8) & 15;
  int ci = idx >> 12;
  dwt[((size_t)(ci * 16 + kk)) * 256 + co] = w[((size_t)(co * 256 + ci)) * 16 + kk];
}

// ---------------- 0b. transpose up_w [ci][co][kh][kw] -> wt [cls][tap][ci][co] --
__global__ __launch_bounds__(256) void k_wt_up(const float* __restrict__ w,
                                               float* __restrict__ wt) {
  int idx = blockIdx.x * 256 + threadIdx.x;   // 1,048,576
  int co = idx & 255;
  int ci = (idx >> 8) & 255;
  int tp = idx >> 16;                         // 0..15
  int cls = tp >> 2, tap = tp & 3;
  int r = cls >> 1, s = cls & 1;
  int kh = (tap < 2) ? (r ? 0 : 1) : (r ? 2 : 3);
  int kw = ((tap & 1) == 0) ? (s ? 0 : 1) : (s ? 2 : 3);
  wt[idx] = w[((size_t)(ci * 256 + co)) * 16 + kh * 4 + kw];
}

// ---------------- 1. down conv v5: ci-split + weights direct from L2 ----------
// grid = 2048: blk = ((ks*8 + b)*4 + cg)*16 + ihp ; 64 ci per block, partial out.
// Weights are wave-broadcast (addr depends only on cg4) -> 1 x 64B L2 line per
// wave per load; no LDS staging for them. LDS holds only the x halo tile.
__global__ __launch_bounds__(256) void k_conv_down3(const float* __restrict__ x,
    const float* __restrict__ dwt, const float* __restrict__ bias,
    float* __restrict__ part) {
  int blk = blockIdx.x;            // ((ks*8 + b)*4 + cg)*16 + ihp
  int ihp = blk & 15;
  int cg = (blk >> 4) & 3;
  int b = (blk >> 6) & 7;
  int ks = blk >> 9;               // 0..3 ci-slice
  int oh0 = ihp * 2;
  int co0 = cg * 64;
  int t = threadIdx.x;
  int cg4 = t >> 4;                // 16 co-groups of 4
  int px = t & 15;
  int i_loc = px >> 3;             // 0..1 (oh row)
  int j0 = (px & 7) << 2;          // 0..28 (ow)

  __shared__ float xs[4][6][66];   // stride 66: i_loc bank shift=4 -> 2-way (free)

  float acc[4][4];
#pragma unroll
  for (int ck = 0; ck < 4; ++ck) {
    float bv = (ks == 0) ? bias[co0 + cg4 * 4 + ck] : 0.f;
#pragma unroll
    for (int jj = 0; jj < 4; ++jj) acc[ck][jj] = bv;
  }
  const float* xb = x + (size_t)b * 256 * 4096;

  int ci_end = ks * 64 + 64;
  for (int ci0 = ks * 64; ci0 < ci_end; ci0 += 4) {
    __syncthreads();
    for (int idx = t; idx < 4 * 6 * 66; idx += 256) {
      int cl = idx / 396;
      int rem = idx - cl * 396;
      int row = rem / 66;
      int col = rem - row * 66;
      int ih = oh0 * 2 - 1 + row;
      int iw = col - 1;
      float v = 0.f;
      if ((unsigned)ih < 64u && (unsigned)iw < 64u)
        v = xb[(size_t)(ci0 + cl) * 4096 + ih * 64 + iw];
      xs[cl][row][col] = v;
    }
    __syncthreads();
#pragma unroll
    for (int cl = 0; cl < 4; ++cl) {
      float xr[4][10];
#pragma unroll
      for (int rr = 0; rr < 4; ++rr) {
        const float* rp = &xs[cl][2 * i_loc + rr][2 * j0];
#pragma unroll
        for (int kp = 0; kp < 5; ++kp) {
          float2 p = *(const float2*)(rp + 2 * kp);
          xr[rr][2 * kp] = p.x;
          xr[rr][2 * kp + 1] = p.y;
        }
      }
      const float* wp = dwt + ((size_t)(ci0 + cl) * 16) * 256 + co0 + cg4 * 4;
#pragma unroll
      for (int kh = 0; kh < 4; ++kh)
#pragma unroll
        for (int kw = 0; kw < 4; ++kw) {
          float4 wq = *(const float4*)(wp + (kh * 4 + kw) * 256);
#pragma unroll
          for (int jj = 0; jj < 4; ++jj) {
            float xv = xr[kh][2 * jj + kw];
            acc[0][jj] = fmaf(xv, wq.x, acc[0][jj]);
            acc[1][jj] = fmaf(xv, wq.y, acc[1][jj]);
            acc[2][jj] = fmaf(xv, wq.z, acc[2][jj]);
            acc[3][jj] = fmaf(xv, wq.w, acc[3][jj]);
          }
        }
    }
  }
  int bn = b * 4 + cg;
  int pixr = (oh0 + i_loc) * 32 + j0;
  float* pb = part + (size_t)ks * 2097152;
#pragma unroll
  for (int jj = 0; jj < 4; ++jj) {
    float4 o4 = make_float4(acc[0][jj], acc[1][jj], acc[2][jj], acc[3][jj]);
    *(float4*)(pb + ((size_t)bn * 1024 + pixr + jj) * 64 + cg4 * 4) = o4;
  }
}

// ---------------- 2. QKV gemm coarse: sums the 4 ci-split partials -------------
__global__ __launch_bounds__(192) void k_qkv_coarse(const float* __restrict__ part,
    const float* __restrict__ W, const float* __restrict__ bias,
    float* __restrict__ q, float* __restrict__ k, float* __restrict__ v) {
  int row = blockIdx.x;              // bn*1024 + i
  __shared__ float t[64];
  if (threadIdx.x < 64) {
    size_t o = (size_t)row * 64 + threadIdx.x;
    t[threadIdx.x] = ((part[o] + part[o + 2097152]) +
                      part[o + 2 * 2097152]) + part[o + 3 * 2097152];
  }
  __syncthreads();
  int e = threadIdx.x;               // 0..191
  float acc = bias[e];
  const float* wr = W + e * 64;
#pragma unroll
  for (int d = 0; d < 64; ++d) acc = fmaf(t[d], wr[d], acc);
  float* dst = (e < 64) ? q : (e < 128) ? k : v;
  dst[(size_t)row * 64 + (e & 63)] = acc;
}

// ---------------- 3. QKV gemm topk: coalesced coutT staging ----------------
__global__ __launch_bounds__(192) void k_qkv_topk(const float* __restrict__ coutT,
    const int* __restrict__ idx, const float* __restrict__ W, const float* __restrict__ bias,
    float* __restrict__ q, float* __restrict__ k, float* __restrict__ v) {
  int row = blockIdx.x;              // bn*1024 + t
  int bn = row >> 10, t = row & 1023;
  int kk = t >> 2, ab = t & 3;
  int a = ab >> 1, bi = ab & 1;
  __shared__ float tl[64];
  __shared__ int ps;
  if (threadIdx.x == 0) ps = idx[bn * 256 + kk] & 1023;
  __syncthreads();
  int p = ps;
  int sh = (p >> 5) * 2 + a, sw = (p & 31) * 2 + bi;
  if (threadIdx.x < 64)
    tl[threadIdx.x] = coutT[((size_t)bn * 4096 + sh * 64 + sw) * 64 + threadIdx.x];
  __syncthreads();
  int e = threadIdx.x;
  float acc = bias[e];
  const float* wr = W + e * 64;
#pragma unroll
  for (int d = 0; d < 64; ++d) acc = fmaf(tl[d], wr[d], acc);
  float* dst = (e < 64) ? q : (e < 128) ? k : v;
  dst[(size_t)row * 64 + (e & 63)] = acc;
}

// ---------------- 4a. attention with score (2-pass; score needs all l_i) ------
__global__ __launch_bounds__(256) void k_attn_score(
    const float* __restrict__ Q, const float* __restrict__ K,
    const float* __restrict__ V, float* __restrict__ O,
    float* __restrict__ spart, float* __restrict__ attT) {
  int bn = blockIdx.x >> 4;
  int it = blockIdx.x & 15;
  int tid = threadIdx.x;
  int rowgrp = tid >> 4;        // 0..15
  int colgrp = tid & 15;        // 0..15
  int i0 = rowgrp * 4;
  int j0 = colgrp * 4;
  const float* qb = Q + (size_t)bn * 65536;
  const float* kb = K + (size_t)bn * 65536;
  const float* vb = V + (size_t)bn * 65536;
  int ibase = it * 64;

  __shared__ float Ks[64][68];   // [d][i] transposed
  __shared__ float QP[64][68];   // Q transposed [d][j], reused as P [j][i]
  __shared__ float Vs[64][68];   // [j][d] natural
  __shared__ float sacc[1024];

  for (int i = tid; i < 1024; i += 256) sacc[i] = 0.f;

  {
    int r = tid >> 4, c4 = tid & 15;
#pragma unroll
    for (int p4 = 0; p4 < 4; ++p4) {
      int i = p4 * 16 + r;
      float4 kv = *(const float4*)(kb + (size_t)(ibase + i) * 64 + c4 * 4);
      Ks[c4 * 4 + 0][i] = kv.x;
      Ks[c4 * 4 + 1][i] = kv.y;
      Ks[c4 * 4 + 2][i] = kv.z;
      Ks[c4 * 4 + 3][i] = kv.w;
    }
  }

  float m[4], l[4];
#pragma unroll
  for (int a = 0; a < 4; ++a) { m[a] = -3.0e38f; l[a] = 0.f; }

  for (int jt = 0; jt < 16; ++jt) {
    __syncthreads();
    {
      int r = tid >> 4, c4 = tid & 15;
#pragma unroll
      for (int p4 = 0; p4 < 4; ++p4) {
        int j = p4 * 16 + r;
        float4 qv = *(const float4*)(qb + (size_t)(jt * 64 + j) * 64 + c4 * 4);
        QP[c4 * 4 + 0][j] = qv.x;
        QP[c4 * 4 + 1][j] = qv.y;
        QP[c4 * 4 + 2][j] = qv.z;
        QP[c4 * 4 + 3][j] = qv.w;
      }
    }
    __syncthreads();
    float s[4][4];
#pragma unroll
    for (int a = 0; a < 4; ++a)
#pragma unroll
      for (int b = 0; b < 4; ++b) s[a][b] = 0.f;
#pragma unroll 4
    for (int d = 0; d < 64; ++d) {
      float4 kv = *(const float4*)&Ks[d][i0];
      float4 qv = *(const float4*)&QP[d][j0];
      s[0][0] = fmaf(kv.x, qv.x, s[0][0]); s[0][1] = fmaf(kv.x, qv.y, s[0][1]);
      s[0][2] = fmaf(kv.x, qv.z, s[0][2]); s[0][3] = fmaf(kv.x, qv.w, s[0][3]);
      s[1][0] = fmaf(kv.y, qv.x, s[1][0]); s[1][1] = fmaf(kv.y, qv.y, s[1][1]);
      s[1][2] = fmaf(kv.y, qv.z, s[1][2]); s[1][3] = fmaf(kv.y, qv.w, s[1][3]);
      s[2][0] = fmaf(kv.z, qv.x, s[2][0]); s[2][1] = fmaf(kv.z, qv.y, s[2][1]);
      s[2][2] = fmaf(kv.z, qv.z, s[2][2]); s[2][3] = fmaf(kv.z, qv.w, s[2][3]);
      s[3][0] = fmaf(kv.w, qv.x, s[3][0]); s[3][1] = fmaf(kv.w, qv.y, s[3][1]);
      s[3][2] = fmaf(kv.w, qv.z, s[3][2]); s[3][3] = fmaf(kv.w, qv.w, s[3][3]);
    }
#pragma unroll
    for (int a = 0; a < 4; ++a) {
      float tm = fmaxf(fmaxf(s[a][0], s[a][1]), fmaxf(s[a][2], s[a][3]));
#pragma unroll
      for (int off = 1; off <= 8; off <<= 1) tm = fmaxf(tm, __shfl_xor(tm, off, 64));
      float mn = fmaxf(m[a], tm);
      float ts = ((expf(s[a][0] - mn) + expf(s[a][1] - mn)) +
                  expf(s[a][2] - mn)) + expf(s[a][3] - mn);
#pragma unroll
      for (int off = 1; off <= 8; off <<= 1) ts += __shfl_xor(ts, off, 64);
      l[a] = l[a] * expf(m[a] - mn) + ts;
      m[a] = mn;
    }
  }
  float inv[4];
#pragma unroll
  for (int a = 0; a < 4; ++a) inv[a] = 1.f / l[a];

  float accO[4][4];
#pragma unroll
  for (int a = 0; a < 4; ++a)
#pragma unroll
    for (int b = 0; b < 4; ++b) accO[a][b] = 0.f;

  for (int jt = 0; jt < 16; ++jt) {
    __syncthreads();
    {
      int r = tid >> 4, c4 = tid & 15;
#pragma unroll
      for (int p4 = 0; p4 < 4; ++p4) {
        int j = p4 * 16 + r;
        float4 qv = *(const float4*)(qb + (size_t)(jt * 64 + j) * 64 + c4 * 4);
        QP[c4 * 4 + 0][j] = qv.x;
        QP[c4 * 4 + 1][j] = qv.y;
        QP[c4 * 4 + 2][j] = qv.z;
        QP[c4 * 4 + 3][j] = qv.w;
        float4 vv = *(const float4*)(vb + (size_t)(jt * 64 + j) * 64 + c4 * 4);
        *(float4*)&Vs[j][c4 * 4] = vv;
      }
    }
    __syncthreads();
    float s[4][4];
#pragma unroll
    for (int a = 0; a < 4; ++a)
#pragma unroll
      for (int b = 0; b < 4; ++b) s[a][b] = 0.f;
#pragma unroll 4
    for (int d = 0; d < 64; ++d) {
      float4 kv = *(const float4*)&Ks[d][i0];
      float4 qv = *(const float4*)&QP[d][j0];
      s[0][0] = fmaf(kv.x, qv.x, s[0][0]); s[0][1] = fmaf(kv.x, qv.y, s[0][1]);
      s[0][2] = fmaf(kv.x, qv.z, s[0][2]); s[0][3] = fmaf(kv.x, qv.w, s[0][3]);
      s[1][0] = fmaf(kv.y, qv.x, s[1][0]); s[1][1] = fmaf(kv.y, qv.y, s[1][1]);
      s[1][2] = fmaf(kv.y, qv.z, s[1][2]); s[1][3] = fmaf(kv.y, qv.w, s[1][3]);
      s[2][0] = fmaf(kv.z, qv.x, s[2][0]); s[2][1] = fmaf(kv.z, qv.y, s[2][1]);
      s[2][2] = fmaf(kv.z, qv.z, s[2][2]); s[2][3] = fmaf(kv.z, qv.w, s[2][3]);
      s[3][0] = fmaf(kv.w, qv.x, s[3][0]); s[3][1] = fmaf(kv.w, qv.y, s[3][1]);
      s[3][2] = fmaf(kv.w, qv.z, s[3][2]); s[3][3] = fmaf(kv.w, qv.w, s[3][3]);
    }
    float p[4][4];
#pragma unroll
    for (int a = 0; a < 4; ++a)
#pragma unroll
      for (int b = 0; b < 4; ++b) p[a][b] = expf(s[a][b] - m[a]) * inv[a];
#pragma unroll
    for (int b = 0; b < 4; ++b) {
      float cs = ((p[0][b] + p[1][b]) + p[2][b]) + p[3][b];
      atomicAdd(&sacc[jt * 64 + j0 + b], cs);
    }
    __syncthreads();
#pragma unroll
    for (int b = 0; b < 4; ++b)
      *(float4*)&QP[j0 + b][i0] = make_float4(p[0][b], p[1][b], p[2][b], p[3][b]);
    __syncthreads();
#pragma unroll 4
    for (int j = 0; j < 64; ++j) {
      float4 pv = *(const float4*)&QP[j][i0];
      float4 vv = *(const float4*)&Vs[j][j0];
      accO[0][0] = fmaf(pv.x, vv.x, accO[0][0]); accO[0][1] = fmaf(pv.x, vv.y, accO[0][1]);
      accO[0][2] = fmaf(pv.x, vv.z, accO[0][2]); accO[0][3] = fmaf(pv.x, vv.w, accO[0][3]);
      accO[1][0] = fmaf(pv.y, vv.x, accO[1][0]); accO[1][1] = fmaf(pv.y, vv.y, accO[1][1]);
      accO[1][2] = fmaf(pv.y, vv.z, accO[1][2]); accO[1][3] = fmaf(pv.y, vv.w, accO[1][3]);
      accO[2][0] = fmaf(pv.z, vv.x, accO[2][0]); accO[2][1] = fmaf(pv.z, vv.y, accO[2][1]);
      accO[2][2] = fmaf(pv.z, vv.z, accO[2][2]); accO[2][3] = fmaf(pv.z, vv.w, accO[2][3]);
      accO[3][0] = fmaf(pv.w, vv.x, accO[3][0]); accO[3][1] = fmaf(pv.w, vv.y, accO[3][1]);
      accO[3][2] = fmaf(pv.w, vv.z, accO[3][2]); accO[3][3] = fmaf(pv.w, vv.w, accO[3][3]);
    }
  }
#pragma unroll
  for (int a = 0; a < 4; ++a) {
    float4 o4 = make_float4(accO[a][0], accO[a][1], accO[a][2], accO[a][3]);
    *(float4*)(O + ((size_t)bn * 1024 + ibase + i0 + a) * 64 + j0) = o4;
  }
  // transposed copy for conv_up staging: attT[bn][d][i]
#pragma unroll
  for (int a = 0; a < 4; ++a)
#pragma unroll
    for (int b = 0; b < 4; ++b)
      attT[((size_t)bn * 64 + j0 + b) * 1024 + ibase + i0 + a] = accO[a][b];
  __syncthreads();
  for (int i = tid; i < 1024; i += 256)
    spart[((size_t)bn * 16 + it) * 1024 + i] = sacc[i];
}

// ---------------- 4b. topk attention: single-pass online softmax ----------------
__global__ __launch_bounds__(256) void k_attn_online(
    const float* __restrict__ Q, const float* __restrict__ K,
    const float* __restrict__ V, float* __restrict__ O) {
  int bn = blockIdx.x >> 4;
  int it = blockIdx.x & 15;
  int tid = threadIdx.x;
  int i0 = (tid >> 4) * 4;
  int j0 = (tid & 15) * 4;
  const float* qb = Q + (size_t)bn * 65536;
  const float* kb = K + (size_t)bn * 65536;
  const float* vb = V + (size_t)bn * 65536;
  int ibase = it * 64;

  __shared__ float Ks[64][68];   // [d][i] transposed
  __shared__ float QP[64][68];   // Q transposed [d][j], reused as P [j][i]
  __shared__ float Vs[64][68];   // [j][d] natural

  {
    int r = tid >> 4, c4 = tid & 15;
#pragma unroll
    for (int p4 = 0; p4 < 4; ++p4) {
      int i = p4 * 16 + r;
      float4 kv = *(const float4*)(kb + (size_t)(ibase + i) * 64 + c4 * 4);
      Ks[c4 * 4 + 0][i] = kv.x;
      Ks[c4 * 4 + 1][i] = kv.y;
      Ks[c4 * 4 + 2][i] = kv.z;
      Ks[c4 * 4 + 3][i] = kv.w;
    }
  }

  float m[4], l[4], accO[4][4];
#pragma unroll
  for (int a = 0; a < 4; ++a) {
    m[a] = -3.0e38f; l[a] = 0.f;
#pragma unroll
    for (int b = 0; b < 4; ++b) accO[a][b] = 0.f;
  }

  for (int jt = 0; jt < 16; ++jt) {
    __syncthreads();
    {
      int r = tid >> 4, c4 = tid & 15;
#pragma unroll
      for (int p4 = 0; p4 < 4; ++p4) {
        int j = p4 * 16 + r;
        float4 qv = *(const float4*)(qb + (size_t)(jt * 64 + j) * 64 + c4 * 4);
        QP[c4 * 4 + 0][j] = qv.x;
        QP[c4 * 4 + 1][j] = qv.y;
        QP[c4 * 4 + 2][j] = qv.z;
        QP[c4 * 4 + 3][j] = qv.w;
        float4 vv = *(const float4*)(vb + (size_t)(jt * 64 + j) * 64 + c4 * 4);
        *(float4*)&Vs[j][c4 * 4] = vv;
      }
    }
    __syncthreads();
    float s[4][4];
#pragma unroll
    for (int a = 0; a < 4; ++a)
#pragma unroll
      for (int b = 0; b < 4; ++b) s[a][b] = 0.f;
#pragma unroll 4
    for (int d = 0; d < 64; ++d) {
      float4 kv = *(const float4*)&Ks[d][i0];
      float4 qv = *(const float4*)&QP[d][j0];
      s[0][0] = fmaf(kv.x, qv.x, s[0][0]); s[0][1] = fmaf(kv.x, qv.y, s[0][1]);
      s[0][2] = fmaf(kv.x, qv.z, s[0][2]); s[0][3] = fmaf(kv.x, qv.w, s[0][3]);
      s[1][0] = fmaf(kv.y, qv.x, s[1][0]); s[1][1] = fmaf(kv.y, qv.y, s[1][1]);
      s[1][2] = fmaf(kv.y, qv.z, s[1][2]); s[1][3] = fmaf(kv.y, qv.w, s[1][3]);
      s[2][0] = fmaf(kv.z, qv.x, s[2][0]); s[2][1] = fmaf(kv.z, qv.y, s[2][1]);
      s[2][2] = fmaf(kv.z, qv.z, s[2][2]); s[2][3] = fmaf(kv.z, qv.w, s[2][3]);
      s[3][0] = fmaf(kv.w, qv.x, s[3][0]); s[3][1] = fmaf(kv.w, qv.y, s[3][1]);
      s[3][2] = fmaf(kv.w, qv.z, s[3][2]); s[3][3] = fmaf(kv.w, qv.w, s[3][3]);
    }
    float p[4][4];
#pragma unroll
    for (int a = 0; a < 4; ++a) {
      float tm = fmaxf(fmaxf(s[a][0], s[a][1]), fmaxf(s[a][2], s[a][3]));
#pragma unroll
      for (int off = 1; off <= 8; off <<= 1) tm = fmaxf(tm, __shfl_xor(tm, off, 64));
      float mn = fmaxf(m[a], tm);
      float sc = expf(m[a] - mn);
      p[a][0] = expf(s[a][0] - mn); p[a][1] = expf(s[a][1] - mn);
      p[a][2] = expf(s[a][2] - mn); p[a][3] = expf(s[a][3] - mn);
      float ts = ((p[a][0] + p[a][1]) + p[a][2]) + p[a][3];
#pragma unroll
      for (int off = 1; off <= 8; off <<= 1) ts += __shfl_xor(ts, off, 64);
      l[a] = l[a] * sc + ts;
      m[a] = mn;
#pragma unroll
      for (int b = 0; b < 4; ++b) accO[a][b] *= sc;
    }
    __syncthreads();
#pragma unroll
    for (int b = 0; b < 4; ++b)
      *(float4*)&QP[j0 + b][i0] = make_float4(p[0][b], p[1][b], p[2][b], p[3][b]);
    __syncthreads();
#pragma unroll 4
    for (int j = 0; j < 64; ++j) {
      float4 pv = *(const float4*)&QP[j][i0];
      float4 vv = *(const float4*)&Vs[j][j0];
      accO[0][0] = fmaf(pv.x, vv.x, accO[0][0]); accO[0][1] = fmaf(pv.x, vv.y, accO[0][1]);
      accO[0][2] = fmaf(pv.x, vv.z, accO[0][2]); accO[0][3] = fmaf(pv.x, vv.w, accO[0][3]);
      accO[1][0] = fmaf(pv.y, vv.x, accO[1][0]); accO[1][1] = fmaf(pv.y, vv.y, accO[1][1]);
      accO[1][2] = fmaf(pv.y, vv.z, accO[1][2]); accO[1][3] = fmaf(pv.y, vv.w, accO[1][3]);
      accO[2][0] = fmaf(pv.z, vv.x, accO[2][0]); accO[2][1] = fmaf(pv.z, vv.y, accO[2][1]);
      accO[2][2] = fmaf(pv.z, vv.z, accO[2][2]); accO[2][3] = fmaf(pv.z, vv.w, accO[2][3]);
      accO[3][0] = fmaf(pv.w, vv.x, accO[3][0]); accO[3][1] = fmaf(pv.w, vv.y, accO[3][1]);
      accO[3][2] = fmaf(pv.w, vv.z, accO[3][2]); accO[3][3] = fmaf(pv.w, vv.w, accO[3][3]);
    }
  }
#pragma unroll
  for (int a = 0; a < 4; ++a) {
    float inv = 1.f / l[a];
    float4 o4 = make_float4(accO[a][0] * inv, accO[a][1] * inv,
                            accO[a][2] * inv, accO[a][3] * inv);
    *(float4*)(O + ((size_t)bn * 1024 + ibase + i0 + a) * 64 + j0) = o4;
  }
}

// ---------------- 5. deterministic score reduction (16 partials) ----------------
__global__ __launch_bounds__(256) void k_score_reduce(const float* __restrict__ part,
                                                      float* __restrict__ score) {
  int j = blockIdx.x * 256 + threadIdx.x;   // 0..32767
  int bn = j >> 10, jj = j & 1023;
  float s = 0.f;
  for (int g = 0; g < 16; ++g) s += part[((size_t)bn * 16 + g) * 1024 + jj];
  score[j] = s;
}

// ---------------- 5b. default-init idx ----------------
__global__ __launch_bounds__(256) void k_idx_init(int* __restrict__ idx) {
  int j = blockIdx.x * 256 + threadIdx.x;
  idx[j] = j & 255;
}

// ---------------- 6. top-K by rank ----------------
__global__ __launch_bounds__(1024) void k_topk(const float* __restrict__ score,
                                               int* __restrict__ idxout) {
  int bn = blockIdx.x;
  int t = threadIdx.x;
  __shared__ float s[1024];
  s[t] = score[bn * 1024 + t];
  __syncthreads();
  float my = s[t];
  int rank = 0;
  for (int j = 0; j < 1024; ++j) {
    float o = s[j];
    rank += (o > my) || (o == my && j < t);
  }
  if (rank < 256) idxout[bn * 256 + rank] = t;
}

// ---------------- 7. transposed conv v4: weights direct from L2 ----------------
__global__ __launch_bounds__(256) void k_conv_up3(const float* __restrict__ attT,
    const float* __restrict__ wt, const float* __restrict__ bias,
    float* __restrict__ cout, float* __restrict__ coutT) {
  int blk = blockIdx.x;              // ((b*4+cls)*4 + cg)*16 + ip
  int ip = blk & 15;
  int cg = (blk >> 4) & 3;
  int cls = (blk >> 6) & 3;
  int b = blk >> 8;
  int r = cls >> 1, s = cls & 1;
  int i0 = ip * 2;
  int co0 = cg * 64;
  int t = threadIdx.x;
  int cg4 = t >> 4;
  int px = t & 15;
  int i_loc = px >> 3;
  int j0 = (px & 7) << 2;

  __shared__ float xs[16][3][36];   // s-shifted: read base j0 (float4-aligned)

  float acc[4][4];
#pragma unroll
  for (int ck = 0; ck < 4; ++ck) {
    float bv = bias[co0 + cg4 * 4 + ck];
#pragma unroll
    for (int jj = 0; jj < 4; ++jj) acc[ck][jj] = bv;
  }
  int rbase = i0 + r;
  const float* ab = attT + (size_t)b * 4 * 65536;

  for (int ci0 = 0; ci0 < 256; ci0 += 16) {
    __syncthreads();
    for (int idx = t; idx < 16 * 99; idx += 256) {
      int cl = idx / 99;
      int rem = idx - cl * 99;
      int rho = rem / 33;
      int c = rem - rho * 33;
      int ih = rbase + rho - 1;
      int iw = c - 1 + s;
      int ci = ci0 + cl;
      int n = ci >> 6, d = ci & 63;
      float v = 0.f;
      if ((unsigned)ih < 32u && (unsigned)iw < 32u)
        v = ab[((size_t)n * 64 + d) * 1024 + ih * 32 + iw];   // coalesced in c
      xs[cl][rho][c] = v;
    }
    __syncthreads();
#pragma unroll
    for (int cl = 0; cl < 16; ++cl) {
      float4 a4 = *(const float4*)&xs[cl][i_loc + 1][j0];
      float a4e = xs[cl][i_loc + 1][j0 + 4];
      float4 b4 = *(const float4*)&xs[cl][i_loc][j0];
      float b4e = xs[cl][i_loc][j0 + 4];
      float xA[5] = {a4.x, a4.y, a4.z, a4.w, a4e};
      float xB[5] = {b4.x, b4.y, b4.z, b4.w, b4e};
      // weights: wave-broadcast 64B L2 lines (addr depends only on cg4)
      const float* wpb = wt + ((size_t)(cls * 4) * 256 + ci0 + cl) * 256 + co0 + cg4 * 4;
      float4 w0 = *(const float4*)(wpb);
      float4 w1 = *(const float4*)(wpb + 65536);
      float4 w2 = *(const float4*)(wpb + 2 * 65536);
      float4 w3 = *(const float4*)(wpb + 3 * 65536);
      const float* w0p = (const float*)&w0;
      const float* w1p = (const float*)&w1;
      const float* w2p = (const float*)&w2;
      const float* w3p = (const float*)&w3;
#pragma unroll
      for (int ck = 0; ck < 4; ++ck) {
        float wAA = w0p[ck], wAB = w1p[ck], wBA = w2p[ck], wBB = w3p[ck];
#pragma unroll
        for (int jj = 0; jj < 4; ++jj) {
          float a = acc[ck][jj];
          a = fmaf(xA[jj + 1], wAA, a);
          a = fmaf(xA[jj],     wAB, a);
          a = fmaf(xB[jj + 1], wBA, a);
          a = fmaf(xB[jj],     wBB, a);
          acc[ck][jj] = a;
        }
      }
    }
  }
  int oh = 2 * (i0 + i_loc) + r;
#pragma unroll
  for (int ck = 0; ck < 4; ++ck) {
#pragma unroll
    for (int jj = 0; jj < 4; ++jj) {
      int ow = 2 * (j0 + jj) + s;
      cout[((size_t)b * 256 + co0 + cg4 * 4 + ck) * 4096 + oh * 64 + ow] = acc[ck][jj];
    }
  }
  int bn = b * 4 + cg;
#pragma unroll
  for (int jj = 0; jj < 4; ++jj) {
    int ow = 2 * (j0 + jj) + s;
    float4 o4 = make_float4(acc[0][jj], acc[1][jj], acc[2][jj], acc[3][jj]);
    *(float4*)(coutT + ((size_t)bn * 4096 + oh * 64 + ow) * 64 + cg4 * 4) = o4;
  }
}

// ---------------- 8. y = coarse_out + region ----------------
__global__ __launch_bounds__(256) void k_ybuild(const float* __restrict__ cout,
                                                float* __restrict__ y) {
  size_t e = (size_t)blockIdx.x * 256 + threadIdx.x;
  int flat = (int)(e & 4095);
  size_t bc = e >> 12;
  int p = flat >> 2, ab = flat & 3;
  int a = ab >> 1, bi = ab & 1;
  int src = ((p >> 5) * 2 + a) * 64 + (p & 31) * 2 + bi;
  const float* cb = cout + bc * 4096;
  y[e] = cb[flat] + cb[src];
}

// ---------------- 9. scatter-add attended tokens ----------------
__global__ __launch_bounds__(256) void k_scatter(const float* __restrict__ out2,
    const int* __restrict__ idx, float* __restrict__ y) {
  int e = blockIdx.x * 256 + threadIdx.x;
  int d = e & 63;
  int r = e >> 6;
  int ab = r & 3;
  int r2 = r >> 2;
  int kk = r2 & 255;
  int bn = r2 >> 8;
  int b = bn >> 2, n = bn & 3;
  int p = idx[bn * 256 + kk] & 1023;
  int flat = p * 4 + ab;
  int t = kk * 4 + ab;
  y[((size_t)(b * 256 + n * 64 + d)) * 4096 + flat] +=
      out2[((size_t)bn * 1024 + t) * 64 + d];
}

// ---------------- 10. depthwise 3x3 + BN + relu6 ----------------
__global__ __launch_bounds__(256) void k_dw(const float* __restrict__ y,
    const float* __restrict__ w, const float* __restrict__ g, const float* __restrict__ bb,
    const float* __restrict__ mm, const float* __restrict__ vv, float* __restrict__ t1) {
  size_t e = (size_t)blockIdx.x * 256 + threadIdx.x;
  int pix = (int)(e & 4095);
  int c = (int)((e >> 12) & 255);
  int oh = pix >> 6, ow = pix & 63;
  const float* yb = y + (e - pix);
  float acc = 0.f;
#pragma unroll
  for (int kh = 0; kh < 3; ++kh) {
    int ih = oh - 1 + kh;
    if ((unsigned)ih >= 64u) continue;
#pragma unroll
    for (int kw = 0; kw < 3; ++kw) {
      int iw = ow - 1 + kw;
      if ((unsigned)iw >= 64u) continue;
      acc = fmaf(yb[ih * 64 + iw], w[c * 9 + kh * 3 + kw], acc);
    }
  }
  float s = g[c] * rsqrtf(vv[c] + 1e-5f);
  float val = acc * s + (bb[c] - mm[c] * s);
  t1[e] = fminf(fmaxf(val, 0.f), 6.f);
}

// ---------------- 11. pointwise v2: 4 co per block, 16 FMA per 16B load --------
__global__ __launch_bounds__(256) void k_pw2(const float* __restrict__ t1,
    const float* __restrict__ w, const float* __restrict__ g, const float* __restrict__ bb,
    const float* __restrict__ mm, const float* __restrict__ vv, float* __restrict__ out) {
  int blk = blockIdx.x;              // (b*64 + cog)*4 + tile
  int tile = blk & 3;
  int cog = (blk >> 2) & 63;
  int b = blk >> 8;
  int co0 = cog * 4;
  int t = threadIdx.x;
  __shared__ float wl[256][4];
  for (int idx = t; idx < 1024; idx += 256) {
    int cof = idx >> 8;
    int ci = idx & 255;
    wl[ci][cof] = w[(co0 + cof) * 256 + ci];
  }
  __syncthreads();
  int px0 = tile * 1024 + t * 4;
  const float* tb = t1 + (size_t)b * 256 * 4096 + px0;
  float acc[4][4];
#pragma unroll
  for (int a = 0; a < 4; ++a)
#pragma unroll
    for (int jj = 0; jj < 4; ++jj) acc[a][jj] = 0.f;
  for (int ci = 0; ci < 256; ++ci) {
    float4 tv = *(const float4*)(tb + (size_t)ci * 4096);
    float4 wv = *(const float4*)&wl[ci][0];
    acc[0][0] = fmaf(tv.x, wv.x, acc[0][0]); acc[0][1] = fmaf(tv.y, wv.x, acc[0][1]);
    acc[0][2] = fmaf(tv.z, wv.x, acc[0][2]); acc[0][3] = fmaf(tv.w, wv.x, acc[0][3]);
    acc[1][0] = fmaf(tv.x, wv.y, acc[1][0]); acc[1][1] = fmaf(tv.y, wv.y, acc[1][1]);
    acc[1][2] = fmaf(tv.z, wv.y, acc[1][2]); acc[1][3] = fmaf(tv.w, wv.y, acc[1][3]);
    acc[2][0] = fmaf(tv.x, wv.z, acc[2][0]); acc[2][1] = fmaf(tv.y, wv.z, acc[2][1]);
    acc[2][2] = fmaf(tv.z, wv.z, acc[2][2]); acc[2][3] = fmaf(tv.w, wv.z, acc[2][3]);
    acc[3][0] = fmaf(tv.x, wv.w, acc[3][0]); acc[3][1] = fmaf(tv.y, wv.w, acc[3][1]);
    acc[3][2] = fmaf(tv.z, wv.w, acc[3][2]); acc[3][3] = fmaf(tv.w, wv.w, acc[3][3]);
  }
#pragma unroll
  for (int a = 0; a < 4; ++a) {
    int co = co0 + a;
    float s = g[co] * rsqrtf(vv[co] + 1e-5f);
    float bias = bb[co] - mm[co] * s;
    float4 o4;
    o4.x = fminf(fmaxf(acc[a][0] * s + bias, 0.f), 6.f);
    o4.y = fminf(fmaxf(acc[a][1] * s + bias, 0.f), 6.f);
    o4.z = fminf(fmaxf(acc[a][2] * s + bias, 0.f), 6.f);
    o4.w = fminf(fmaxf(acc[a][3] * s + bias, 0.f), 6.f);
    *(float4*)(out + ((size_t)(b * 256 + co)) * 4096 + px0) = o4;
  }
}

// ---------------- launcher ----------------
extern "C" void kernel_launch(void* const* d_in, const int* in_sizes, int n_in,
                              void* d_out, int out_size, void* d_ws, size_t ws_size,
                              hipStream_t stream) {
  if (ws_size < WS_FLOATS * sizeof(float)) return;

  const float* x      = (const float*)d_in[0];
  const float* down_w = (const float*)d_in[1];
  const float* down_b = (const float*)d_in[2];
  const float* up_w   = (const float*)d_in[3];
  const float* up_b   = (const float*)d_in[4];
  const float* cqkv_w = (const float*)d_in[5];
  const float* cqkv_b = (const float*)d_in[6];
  const float* tqkv_w = (const float*)d_in[7];
  const float* tqkv_b = (const float*)d_in[8];
  const float* dww    = (const float*)d_in[9];
  const float* bn1g   = (const float*)d_in[10];
  const float* bn1b   = (const float*)d_in[11];
  const float* bn1m   = (const float*)d_in[12];
  const float* bn1v   = (const float*)d_in[13];
  const float* pww    = (const float*)d_in[14];
  const float* bn2g   = (const float*)d_in[15];
  const float* bn2b   = (const float*)d_in[16];
  const float* bn2m   = (const float*)d_in[17];
  const float* bn2v   = (const float*)d_in[18];

  float* ws    = (float*)d_ws;
  float* q     = ws + OFF_Q;
  float* k     = ws + OFF_K;
  float* v     = ws + OFF_V;
  float* att   = ws + OFF_ATT;
  float* spart = ws + OFF_SPART;
  float* score = ws + OFF_SCORE;
  int*   idx   = (int*)(ws + OFF_IDX);
  float* cout  = ws + OFF_COUT;
  float* y     = ws + OFF_Y;
  float* t1    = ws + OFF_T1;
  float* dwt   = ws + OFF_SPART;             // dead after k_conv_down3
  float* attT  = ws + OFF_SPART + 2097152;   // upper half of spart region
  float* wt    = ws + OFF_XD;                // xdT region (free; used as wt)
  float* coutT = ws + OFF_T1;                // t1 region dead until k_dw
  float* dpart = ws + OFF_Y;                 // 4 x 2M ci-split partials (dead until k_ybuild)

  k_wt_dn<<<4096, 256, 0, stream>>>(down_w, dwt);
  k_conv_down3<<<2048, 256, 0, stream>>>(x, dwt, down_b, dpart);
  k_qkv_coarse<<<32768, 192, 0, stream>>>(dpart, cqkv_w, cqkv_b, q, k, v);
  k_wt_up<<<4096, 256, 0, stream>>>(up_w, wt);          // overwrites xdT region
  k_attn_score<<<512, 256, 0, stream>>>(q, k, v, att, spart, attT);
  k_score_reduce<<<128, 256, 0, stream>>>(spart, score);
  k_idx_init<<<32, 256, 0, stream>>>(idx);
  k_topk<<<32, 1024, 0, stream>>>(score, idx);
  k_conv_up3<<<2048, 256, 0, stream>>>(attT, wt, up_b, cout, coutT);
  k_qkv_topk<<<32768, 192, 0, stream>>>(coutT, idx, tqkv_w, tqkv_b, q, k, v);
  k_attn_online<<<512, 256, 0, stream>>>(q, k, v, att);
  k_ybuild<<<32768, 256, 0, stream>>>(cout, y);
  k_scatter<<<8192, 256, 0, stream>>>(att, idx, y);
  k_dw<<<32768, 256, 0, stream>>>(y, dww, bn1g, bn1b, bn1m, bn1v, t1);
  k_pw2<<<2048, 256, 0, stream>>>(t1, pww, bn2g, bn2b, bn2m, bn2v, (float*)d_out);
}

// Round 3
// 1545.245 us; speedup vs baseline: 1.1005x; 1.1005x over previous
//
#include <hip/hip_runtime.h>

typedef short short8 __attribute__((ext_vector_type(8)));
typedef float f32x4 __attribute__((ext_vector_type(4)));

__device__ inline unsigned short f32_to_bf16_rne(float f) {
  unsigned int u = __float_as_uint(f);
  unsigned int r = (u + 0x7fffu + ((u >> 16) & 1u)) >> 16;
  return (unsigned short)r;
}
__device__ inline float bf16_to_f32(unsigned short h) {
  return __uint_as_float(((unsigned int)h) << 16);
}

// ---------------- workspace layout (float offsets) ----------------
// q/k/v [32,1024,64]  att [32,1024,64]
// spart[32,16,1024] (+ attT [32,64,1024] at +2M)  score [32,1024]   idx [32,256]
// cout [8,256,64,64]      y     [8,256,64,64]     t1   [8,256,64,64]
// aliases: whi/wlo (bf16 up-weights) -> XD region; dwt -> spart region
//          attT -> spart +2M; coutT -> t1 region (dead until k_dw)
//          dpart -> y region (4 x 2M ci-split partials; dead until k_ybuild)
constexpr size_t OFF_XD    = 0;
constexpr size_t OFF_Q     = 2097152;
constexpr size_t OFF_K     = 4194304;
constexpr size_t OFF_V     = 6291456;
constexpr size_t OFF_ATT   = 8388608;
constexpr size_t OFF_SPART = 10485760;
constexpr size_t OFF_SCORE = 14680064;
constexpr size_t OFF_IDX   = 14712832;
constexpr size_t OFF_COUT  = 14721024;
constexpr size_t OFF_Y     = 23109632;
constexpr size_t OFF_T1    = 31498240;
constexpr size_t WS_FLOATS = 39886848;

// ---------------- 0a. transpose down_w [co][ci][kh][kw] -> dwt [ci][kk][co] ----
__global__ __launch_bounds__(256) void k_wt_dn(const float* __restrict__ w,
                                               float* __restrict__ dwt) {
  int idx = blockIdx.x * 256 + threadIdx.x;   // 1,048,576
  int co = idx & 255;
  int kk = (idx >> 8) & 15;
  int ci = idx >> 12;
  dwt[((size_t)(ci * 16 + kk)) * 256 + co] = w[((size_t)(co * 256 + ci)) * 16 + kk];
}

// ---------------- 0b. up_w -> split-bf16 whi/wlo [cls][tap][co][ci] ----------
// tap = a*2 + b ; contribution: out(I,J)_cls += grid(I+r-a, J+s-b) * W[tap]
__global__ __launch_bounds__(256) void k_wt_upb(const float* __restrict__ w,
    unsigned short* __restrict__ whi, unsigned short* __restrict__ wlo) {
  int idx = blockIdx.x * 256 + threadIdx.x;   // 1,048,576
  int ci = idx & 255;
  int co = (idx >> 8) & 255;
  int tp = idx >> 16;                         // 0..15
  int cls = tp >> 2, tap = tp & 3;
  int r = cls >> 1, s = cls & 1;
  int a_ = tap >> 1, b_ = tap & 1;
  int kh = a_ ? (r ? 2 : 3) : (r ? 0 : 1);
  int kw = b_ ? (s ? 2 : 3) : (s ? 0 : 1);
  float v = w[((size_t)(ci * 256 + co)) * 16 + kh * 4 + kw];
  unsigned short h = f32_to_bf16_rne(v);
  unsigned short l = f32_to_bf16_rne(v - bf16_to_f32(h));
  whi[idx] = h;
  wlo[idx] = l;
}

// ---------------- 1. down conv (R1 form): ci-split, ws staged in LDS ----------
__global__ __launch_bounds__(256) void k_conv_down3(const float* __restrict__ x,
    const float* __restrict__ dwt, const float* __restrict__ bias,
    float* __restrict__ part) {
  int blk = blockIdx.x;            // ((ks*8 + b)*4 + cg)*16 + ihp
  int ihp = blk & 15;
  int cg = (blk >> 4) & 3;
  int b = (blk >> 6) & 7;
  int ks = blk >> 9;               // 0..3 ci-slice
  int oh0 = ihp * 2;
  int co0 = cg * 64;
  int t = threadIdx.x;
  int cg4 = t >> 4;                // 16 co-groups of 4
  int px = t & 15;
  int i_loc = px >> 3;             // 0..1 (oh row)
  int j0 = (px & 7) << 2;          // 0..28 (ow)

  __shared__ float xs[4][6][66];   // stride 66: i_loc bank shift=4 -> 2-way (free)
  __shared__ float ws[4][16][64];

  float acc[4][4];
#pragma unroll
  for (int ck = 0; ck < 4; ++ck) {
    float bv = (ks == 0) ? bias[co0 + cg4 * 4 + ck] : 0.f;
#pragma unroll
    for (int jj = 0; jj < 4; ++jj) acc[ck][jj] = bv;
  }
  const float* xb = x + (size_t)b * 256 * 4096;

  int ci_end = ks * 64 + 64;
  for (int ci0 = ks * 64; ci0 < ci_end; ci0 += 4) {
    __syncthreads();
    for (int idx = t; idx < 4 * 6 * 66; idx += 256) {
      int cl = idx / 396;
      int rem = idx - cl * 396;
      int row = rem / 66;
      int col = rem - row * 66;
      int ih = oh0 * 2 - 1 + row;
      int iw = col - 1;
      float v = 0.f;
      if ((unsigned)ih < 64u && (unsigned)iw < 64u)
        v = xb[(size_t)(ci0 + cl) * 4096 + ih * 64 + iw];
      xs[cl][row][col] = v;
    }
    for (int idx = t; idx < 4 * 16 * 64; idx += 256) {
      int cl = idx >> 10;
      int kk = (idx >> 6) & 15;
      int c = idx & 63;
      ws[cl][kk][c] = dwt[((size_t)(ci0 + cl) * 16 + kk) * 256 + co0 + c];
    }
    __syncthreads();
#pragma unroll
    for (int cl = 0; cl < 4; ++cl) {
      float xr[4][10];
#pragma unroll
      for (int rr = 0; rr < 4; ++rr) {
        const float* rp = &xs[cl][2 * i_loc + rr][2 * j0];
#pragma unroll
        for (int kp = 0; kp < 5; ++kp) {
          float2 p = *(const float2*)(rp + 2 * kp);
          xr[rr][2 * kp] = p.x;
          xr[rr][2 * kp + 1] = p.y;
        }
      }
#pragma unroll
      for (int kh = 0; kh < 4; ++kh)
#pragma unroll
        for (int kw = 0; kw < 4; ++kw) {
          float4 wq = *(const float4*)&ws[cl][kh * 4 + kw][cg4 * 4];
#pragma unroll
          for (int jj = 0; jj < 4; ++jj) {
            float xv = xr[kh][2 * jj + kw];
            acc[0][jj] = fmaf(xv, wq.x, acc[0][jj]);
            acc[1][jj] = fmaf(xv, wq.y, acc[1][jj]);
            acc[2][jj] = fmaf(xv, wq.z, acc[2][jj]);
            acc[3][jj] = fmaf(xv, wq.w, acc[3][jj]);
          }
        }
    }
  }
  int bn = b * 4 + cg;
  int pixr = (oh0 + i_loc) * 32 + j0;
  float* pb = part + (size_t)ks * 2097152;
#pragma unroll
  for (int jj = 0; jj < 4; ++jj) {
    float4 o4 = make_float4(acc[0][jj], acc[1][jj], acc[2][jj], acc[3][jj]);
    *(float4*)(pb + ((size_t)bn * 1024 + pixr + jj) * 64 + cg4 * 4) = o4;
  }
}

// ---------------- 2. QKV gemm coarse: sums the 4 ci-split partials -------------
__global__ __launch_bounds__(192) void k_qkv_coarse(const float* __restrict__ part,
    const float* __restrict__ W, const float* __restrict__ bias,
    float* __restrict__ q, float* __restrict__ k, float* __restrict__ v) {
  int row = blockIdx.x;              // bn*1024 + i
  __shared__ float t[64];
  if (threadIdx.x < 64) {
    size_t o = (size_t)row * 64 + threadIdx.x;
    t[threadIdx.x] = ((part[o] + part[o + 2097152]) +
                      part[o + 2 * 2097152]) + part[o + 3 * 2097152];
  }
  __syncthreads();
  int e = threadIdx.x;               // 0..191
  float acc = bias[e];
  const float* wr = W + e * 64;
#pragma unroll
  for (int d = 0; d < 64; ++d) acc = fmaf(t[d], wr[d], acc);
  float* dst = (e < 64) ? q : (e < 128) ? k : v;
  dst[(size_t)row * 64 + (e & 63)] = acc;
}

// ---------------- 3. QKV gemm topk: coalesced coutT staging ----------------
__global__ __launch_bounds__(192) void k_qkv_topk(const float* __restrict__ coutT,
    const int* __restrict__ idx, const float* __restrict__ W, const float* __restrict__ bias,
    float* __restrict__ q, float* __restrict__ k, float* __restrict__ v) {
  int row = blockIdx.x;              // bn*1024 + t
  int bn = row >> 10, t = row & 1023;
  int kk = t >> 2, ab = t & 3;
  int a = ab >> 1, bi = ab & 1;
  __shared__ float tl[64];
  __shared__ int ps;
  if (threadIdx.x == 0) ps = idx[bn * 256 + kk] & 1023;
  __syncthreads();
  int p = ps;
  int sh = (p >> 5) * 2 + a, sw = (p & 31) * 2 + bi;
  if (threadIdx.x < 64)
    tl[threadIdx.x] = coutT[((size_t)bn * 4096 + sh * 64 + sw) * 64 + threadIdx.x];
  __syncthreads();
  int e = threadIdx.x;
  float acc = bias[e];
  const float* wr = W + e * 64;
#pragma unroll
  for (int d = 0; d < 64; ++d) acc = fmaf(tl[d], wr[d], acc);
  float* dst = (e < 64) ? q : (e < 128) ? k : v;
  dst[(size_t)row * 64 + (e & 63)] = acc;
}

// ---------------- 4a. attention with score (2-pass; score needs all l_i) ------
__global__ __launch_bounds__(256) void k_attn_score(
    const float* __restrict__ Q, const float* __restrict__ K,
    const float* __restrict__ V, float* __restrict__ O,
    float* __restrict__ spart, float* __restrict__ attT) {
  int bn = blockIdx.x >> 4;
  int it = blockIdx.x & 15;
  int tid = threadIdx.x;
  int rowgrp = tid >> 4;        // 0..15
  int colgrp = tid & 15;        // 0..15
  int i0 = rowgrp * 4;
  int j0 = colgrp * 4;
  const float* qb = Q + (size_t)bn * 65536;
  const float* kb = K + (size_t)bn * 65536;
  const float* vb = V + (size_t)bn * 65536;
  int ibase = it * 64;

  __shared__ float Ks[64][68];   // [d][i] transposed
  __shared__ float QP[64][68];   // Q transposed [d][j], reused as P [j][i]
  __shared__ float Vs[64][68];   // [j][d] natural
  __shared__ float sacc[1024];

  for (int i = tid; i < 1024; i += 256) sacc[i] = 0.f;

  {
    int r = tid >> 4, c4 = tid & 15;
#pragma unroll
    for (int p4 = 0; p4 < 4; ++p4) {
      int i = p4 * 16 + r;
      float4 kv = *(const float4*)(kb + (size_t)(ibase + i) * 64 + c4 * 4);
      Ks[c4 * 4 + 0][i] = kv.x;
      Ks[c4 * 4 + 1][i] = kv.y;
      Ks[c4 * 4 + 2][i] = kv.z;
      Ks[c4 * 4 + 3][i] = kv.w;
    }
  }

  float m[4], l[4];
#pragma unroll
  for (int a = 0; a < 4; ++a) { m[a] = -3.0e38f; l[a] = 0.f; }

  for (int jt = 0; jt < 16; ++jt) {
    __syncthreads();
    {
      int r = tid >> 4, c4 = tid & 15;
#pragma unroll
      for (int p4 = 0; p4 < 4; ++p4) {
        int j = p4 * 16 + r;
        float4 qv = *(const float4*)(qb + (size_t)(jt * 64 + j) * 64 + c4 * 4);
        QP[c4 * 4 + 0][j] = qv.x;
        QP[c4 * 4 + 1][j] = qv.y;
        QP[c4 * 4 + 2][j] = qv.z;
        QP[c4 * 4 + 3][j] = qv.w;
      }
    }
    __syncthreads();
    float s[4][4];
#pragma unroll
    for (int a = 0; a < 4; ++a)
#pragma unroll
      for (int b = 0; b < 4; ++b) s[a][b] = 0.f;
#pragma unroll 4
    for (int d = 0; d < 64; ++d) {
      float4 kv = *(const float4*)&Ks[d][i0];
      float4 qv = *(const float4*)&QP[d][j0];
      s[0][0] = fmaf(kv.x, qv.x, s[0][0]); s[0][1] = fmaf(kv.x, qv.y, s[0][1]);
      s[0][2] = fmaf(kv.x, qv.z, s[0][2]); s[0][3] = fmaf(kv.x, qv.w, s[0][3]);
      s[1][0] = fmaf(kv.y, qv.x, s[1][0]); s[1][1] = fmaf(kv.y, qv.y, s[1][1]);
      s[1][2] = fmaf(kv.y, qv.z, s[1][2]); s[1][3] = fmaf(kv.y, qv.w, s[1][3]);
      s[2][0] = fmaf(kv.z, qv.x, s[2][0]); s[2][1] = fmaf(kv.z, qv.y, s[2][1]);
      s[2][2] = fmaf(kv.z, qv.z, s[2][2]); s[2][3] = fmaf(kv.z, qv.w, s[2][3]);
      s[3][0] = fmaf(kv.w, qv.x, s[3][0]); s[3][1] = fmaf(kv.w, qv.y, s[3][1]);
      s[3][2] = fmaf(kv.w, qv.z, s[3][2]); s[3][3] = fmaf(kv.w, qv.w, s[3][3]);
    }
#pragma unroll
    for (int a = 0; a < 4; ++a) {
      float tm = fmaxf(fmaxf(s[a][0], s[a][1]), fmaxf(s[a][2], s[a][3]));
#pragma unroll
      for (int off = 1; off <= 8; off <<= 1) tm = fmaxf(tm, __shfl_xor(tm, off, 64));
      float mn = fmaxf(m[a], tm);
      float ts = ((expf(s[a][0] - mn) + expf(s[a][1] - mn)) +
                  expf(s[a][2] - mn)) + expf(s[a][3] - mn);
#pragma unroll
      for (int off = 1; off <= 8; off <<= 1) ts += __shfl_xor(ts, off, 64);
      l[a] = l[a] * expf(m[a] - mn) + ts;
      m[a] = mn;
    }
  }
  float inv[4];
#pragma unroll
  for (int a = 0; a < 4; ++a) inv[a] = 1.f / l[a];

  float accO[4][4];
#pragma unroll
  for (int a = 0; a < 4; ++a)
#pragma unroll
    for (int b = 0; b < 4; ++b) accO[a][b] = 0.f;

  for (int jt = 0; jt < 16; ++jt) {
    __syncthreads();
    {
      int r = tid >> 4, c4 = tid & 15;
#pragma unroll
      for (int p4 = 0; p4 < 4; ++p4) {
        int j = p4 * 16 + r;
        float4 qv = *(const float4*)(qb + (size_t)(jt * 64 + j) * 64 + c4 * 4);
        QP[c4 * 4 + 0][j] = qv.x;
        QP[c4 * 4 + 1][j] = qv.y;
        QP[c4 * 4 + 2][j] = qv.z;
        QP[c4 * 4 + 3][j] = qv.w;
        float4 vv = *(const float4*)(vb + (size_t)(jt * 64 + j) * 64 + c4 * 4);
        *(float4*)&Vs[j][c4 * 4] = vv;
      }
    }
    __syncthreads();
    float s[4][4];
#pragma unroll
    for (int a = 0; a < 4; ++a)
#pragma unroll
      for (int b = 0; b < 4; ++b) s[a][b] = 0.f;
#pragma unroll 4
    for (int d = 0; d < 64; ++d) {
      float4 kv = *(const float4*)&Ks[d][i0];
      float4 qv = *(const float4*)&QP[d][j0];
      s[0][0] = fmaf(kv.x, qv.x, s[0][0]); s[0][1] = fmaf(kv.x, qv.y, s[0][1]);
      s[0][2] = fmaf(kv.x, qv.z, s[0][2]); s[0][3] = fmaf(kv.x, qv.w, s[0][3]);
      s[1][0] = fmaf(kv.y, qv.x, s[1][0]); s[1][1] = fmaf(kv.y, qv.y, s[1][1]);
      s[1][2] = fmaf(kv.y, qv.z, s[1][2]); s[1][3] = fmaf(kv.y, qv.w, s[1][3]);
      s[2][0] = fmaf(kv.z, qv.x, s[2][0]); s[2][1] = fmaf(kv.z, qv.y, s[2][1]);
      s[2][2] = fmaf(kv.z, qv.z, s[2][2]); s[2][3] = fmaf(kv.z, qv.w, s[2][3]);
      s[3][0] = fmaf(kv.w, qv.x, s[3][0]); s[3][1] = fmaf(kv.w, qv.y, s[3][1]);
      s[3][2] = fmaf(kv.w, qv.z, s[3][2]); s[3][3] = fmaf(kv.w, qv.w, s[3][3]);
    }
    float p[4][4];
#pragma unroll
    for (int a = 0; a < 4; ++a)
#pragma unroll
      for (int b = 0; b < 4; ++b) p[a][b] = expf(s[a][b] - m[a]) * inv[a];
#pragma unroll
    for (int b = 0; b < 4; ++b) {
      float cs = ((p[0][b] + p[1][b]) + p[2][b]) + p[3][b];
      atomicAdd(&sacc[jt * 64 + j0 + b], cs);
    }
    __syncthreads();
#pragma unroll
    for (int b = 0; b < 4; ++b)
      *(float4*)&QP[j0 + b][i0] = make_float4(p[0][b], p[1][b], p[2][b], p[3][b]);
    __syncthreads();
#pragma unroll 4
    for (int j = 0; j < 64; ++j) {
      float4 pv = *(const float4*)&QP[j][i0];
      float4 vv = *(const float4*)&Vs[j][j0];
      accO[0][0] = fmaf(pv.x, vv.x, accO[0][0]); accO[0][1] = fmaf(pv.x, vv.y, accO[0][1]);
      accO[0][2] = fmaf(pv.x, vv.z, accO[0][2]); accO[0][3] = fmaf(pv.x, vv.w, accO[0][3]);
      accO[1][0] = fmaf(pv.y, vv.x, accO[1][0]); accO[1][1] = fmaf(pv.y, vv.y, accO[1][1]);
      accO[1][2] = fmaf(pv.y, vv.z, accO[1][2]); accO[1][3] = fmaf(pv.y, vv.w, accO[1][3]);
      accO[2][0] = fmaf(pv.z, vv.x, accO[2][0]); accO[2][1] = fmaf(pv.z, vv.y, accO[2][1]);
      accO[2][2] = fmaf(pv.z, vv.z, accO[2][2]); accO[2][3] = fmaf(pv.z, vv.w, accO[2][3]);
      accO[3][0] = fmaf(pv.w, vv.x, accO[3][0]); accO[3][1] = fmaf(pv.w, vv.y, accO[3][1]);
      accO[3][2] = fmaf(pv.w, vv.z, accO[3][2]); accO[3][3] = fmaf(pv.w, vv.w, accO[3][3]);
    }
  }
#pragma unroll
  for (int a = 0; a < 4; ++a) {
    float4 o4 = make_float4(accO[a][0], accO[a][1], accO[a][2], accO[a][3]);
    *(float4*)(O + ((size_t)bn * 1024 + ibase + i0 + a) * 64 + j0) = o4;
  }
  // transposed copy for conv_up staging: attT[bn][d][i]
#pragma unroll
  for (int a = 0; a < 4; ++a)
#pragma unroll
    for (int b = 0; b < 4; ++b)
      attT[((size_t)bn * 64 + j0 + b) * 1024 + ibase + i0 + a] = accO[a][b];
  __syncthreads();
  for (int i = tid; i < 1024; i += 256)
    spart[((size_t)bn * 16 + it) * 1024 + i] = sacc[i];
}

// ---------------- 4b. topk attention: single-pass online softmax ----------------
__global__ __launch_bounds__(256) void k_attn_online(
    const float* __restrict__ Q, const float* __restrict__ K,
    const float* __restrict__ V, float* __restrict__ O) {
  int bn = blockIdx.x >> 4;
  int it = blockIdx.x & 15;
  int tid = threadIdx.x;
  int i0 = (tid >> 4) * 4;
  int j0 = (tid & 15) * 4;
  const float* qb = Q + (size_t)bn * 65536;
  const float* kb = K + (size_t)bn * 65536;
  const float* vb = V + (size_t)bn * 65536;
  int ibase = it * 64;

  __shared__ float Ks[64][68];   // [d][i] transposed
  __shared__ float QP[64][68];   // Q transposed [d][j], reused as P [j][i]
  __shared__ float Vs[64][68];   // [j][d] natural

  {
    int r = tid >> 4, c4 = tid & 15;
#pragma unroll
    for (int p4 = 0; p4 < 4; ++p4) {
      int i = p4 * 16 + r;
      float4 kv = *(const float4*)(kb + (size_t)(ibase + i) * 64 + c4 * 4);
      Ks[c4 * 4 + 0][i] = kv.x;
      Ks[c4 * 4 + 1][i] = kv.y;
      Ks[c4 * 4 + 2][i] = kv.z;
      Ks[c4 * 4 + 3][i] = kv.w;
    }
  }

  float m[4], l[4], accO[4][4];
#pragma unroll
  for (int a = 0; a < 4; ++a) {
    m[a] = -3.0e38f; l[a] = 0.f;
#pragma unroll
    for (int b = 0; b < 4; ++b) accO[a][b] = 0.f;
  }

  for (int jt = 0; jt < 16; ++jt) {
    __syncthreads();
    {
      int r = tid >> 4, c4 = tid & 15;
#pragma unroll
      for (int p4 = 0; p4 < 4; ++p4) {
        int j = p4 * 16 + r;
        float4 qv = *(const float4*)(qb + (size_t)(jt * 64 + j) * 64 + c4 * 4);
        QP[c4 * 4 + 0][j] = qv.x;
        QP[c4 * 4 + 1][j] = qv.y;
        QP[c4 * 4 + 2][j] = qv.z;
        QP[c4 * 4 + 3][j] = qv.w;
        float4 vv = *(const float4*)(vb + (size_t)(jt * 64 + j) * 64 + c4 * 4);
        *(float4*)&Vs[j][c4 * 4] = vv;
      }
    }
    __syncthreads();
    float s[4][4];
#pragma unroll
    for (int a = 0; a < 4; ++a)
#pragma unroll
      for (int b = 0; b < 4; ++b) s[a][b] = 0.f;
#pragma unroll 4
    for (int d = 0; d < 64; ++d) {
      float4 kv = *(const float4*)&Ks[d][i0];
      float4 qv = *(const float4*)&QP[d][j0];
      s[0][0] = fmaf(kv.x, qv.x, s[0][0]); s[0][1] = fmaf(kv.x, qv.y, s[0][1]);
      s[0][2] = fmaf(kv.x, qv.z, s[0][2]); s[0][3] = fmaf(kv.x, qv.w, s[0][3]);
      s[1][0] = fmaf(kv.y, qv.x, s[1][0]); s[1][1] = fmaf(kv.y, qv.y, s[1][1]);
      s[1][2] = fmaf(kv.y, qv.z, s[1][2]); s[1][3] = fmaf(kv.y, qv.w, s[1][3]);
      s[2][0] = fmaf(kv.z, qv.x, s[2][0]); s[2][1] = fmaf(kv.z, qv.y, s[2][1]);
      s[2][2] = fmaf(kv.z, qv.z, s[2][2]); s[2][3] = fmaf(kv.z, qv.w, s[2][3]);
      s[3][0] = fmaf(kv.w, qv.x, s[3][0]); s[3][1] = fmaf(kv.w, qv.y, s[3][1]);
      s[3][2] = fmaf(kv.w, qv.z, s[3][2]); s[3][3] = fmaf(kv.w, qv.w, s[3][3]);
    }
    float p[4][4];
#pragma unroll
    for (int a = 0; a < 4; ++a) {
      float tm = fmaxf(fmaxf(s[a][0], s[a][1]), fmaxf(s[a][2], s[a][3]));
#pragma unroll
      for (int off = 1; off <= 8; off <<= 1) tm = fmaxf(tm, __shfl_xor(tm, off, 64));
      float mn = fmaxf(m[a], tm);
      float sc = expf(m[a] - mn);
      p[a][0] = expf(s[a][0] - mn); p[a][1] = expf(s[a][1] - mn);
      p[a][2] = expf(s[a][2] - mn); p[a][3] = expf(s[a][3] - mn);
      float ts = ((p[a][0] + p[a][1]) + p[a][2]) + p[a][3];
#pragma unroll
      for (int off = 1; off <= 8; off <<= 1) ts += __shfl_xor(ts, off, 64);
      l[a] = l[a] * sc + ts;
      m[a] = mn;
#pragma unroll
      for (int b = 0; b < 4; ++b) accO[a][b] *= sc;
    }
    __syncthreads();
#pragma unroll
    for (int b = 0; b < 4; ++b)
      *(float4*)&QP[j0 + b][i0] = make_float4(p[0][b], p[1][b], p[2][b], p[3][b]);
    __syncthreads();
#pragma unroll 4
    for (int j = 0; j < 64; ++j) {
      float4 pv = *(const float4*)&QP[j][i0];
      float4 vv = *(const float4*)&Vs[j][j0];
      accO[0][0] = fmaf(pv.x, vv.x, accO[0][0]); accO[0][1] = fmaf(pv.x, vv.y, accO[0][1]);
      accO[0][2] = fmaf(pv.x, vv.z, accO[0][2]); accO[0][3] = fmaf(pv.x, vv.w, accO[0][3]);
      accO[1][0] = fmaf(pv.y, vv.x, accO[1][0]); accO[1][1] = fmaf(pv.y, vv.y, accO[1][1]);
      accO[1][2] = fmaf(pv.y, vv.z, accO[1][2]); accO[1][3] = fmaf(pv.y, vv.w, accO[1][3]);
      accO[2][0] = fmaf(pv.z, vv.x, accO[2][0]); accO[2][1] = fmaf(pv.z, vv.y, accO[2][1]);
      accO[2][2] = fmaf(pv.z, vv.z, accO[2][2]); accO[2][3] = fmaf(pv.z, vv.w, accO[2][3]);
      accO[3][0] = fmaf(pv.w, vv.x, accO[3][0]); accO[3][1] = fmaf(pv.w, vv.y, accO[3][1]);
      accO[3][2] = fmaf(pv.w, vv.z, accO[3][2]); accO[3][3] = fmaf(pv.w, vv.w, accO[3][3]);
    }
  }
#pragma unroll
  for (int a = 0; a < 4; ++a) {
    float inv = 1.f / l[a];
    float4 o4 = make_float4(accO[a][0] * inv, accO[a][1] * inv,
                            accO[a][2] * inv, accO[a][3] * inv);
    *(float4*)(O + ((size_t)bn * 1024 + ibase + i0 + a) * 64 + j0) = o4;
  }
}

// ---------------- 5. deterministic score reduction (16 partials) ----------------
__global__ __launch_bounds__(256) void k_score_reduce(const float* __restrict__ part,
                                                      float* __restrict__ score) {
  int j = blockIdx.x * 256 + threadIdx.x;   // 0..32767
  int bn = j >> 10, jj = j & 1023;
  float s = 0.f;
  for (int g = 0; g < 16; ++g) s += part[((size_t)bn * 16 + g) * 1024 + jj];
  score[j] = s;
}

// ---------------- 5b. default-init idx ----------------
__global__ __launch_bounds__(256) void k_idx_init(int* __restrict__ idx) {
  int j = blockIdx.x * 256 + threadIdx.x;
  idx[j] = j & 255;
}

// ---------------- 6. top-K by rank ----------------
__global__ __launch_bounds__(1024) void k_topk(const float* __restrict__ score,
                                               int* __restrict__ idxout) {
  int bn = blockIdx.x;
  int t = threadIdx.x;
  __shared__ float s[1024];
  s[t] = score[bn * 1024 + t];
  __syncthreads();
  float my = s[t];
  int rank = 0;
  for (int j = 0; j < 1024; ++j) {
    float o = s[j];
    rank += (o > my) || (o == my && j < t);
  }
  if (rank < 256) idxout[bn * 256 + rank] = t;
}

// ---------------- 7. transposed conv: split-bf16 MFMA implicit GEMM -----------
// per (b, cls): out(I,J)[co] = bias + sum_ci sum_{a,b} grid(I+r-a, J+s-b)[ci] * W[tap(a,b)][ci][co]
// block: 64 patches (2 I-rows x 32 J) x 64 co; 4 waves = 2 I-rows x 2 co-halves.
// A staged in LDS as bf16 hi/lo [3][33][40-stride]; B direct from whi/wlo [cls][tap][co][ci].
__global__ __launch_bounds__(256) void k_conv_up_mfma(
    const float* __restrict__ attT, const unsigned short* __restrict__ whi,
    const unsigned short* __restrict__ wlo, const float* __restrict__ bias,
    float* __restrict__ cout, float* __restrict__ coutT) {
  int blk = blockIdx.x;              // ((b*4 + cls)*16 + pt)*4 + ct
  int ct = blk & 3;
  int pt = (blk >> 2) & 15;
  int cls = (blk >> 6) & 3;
  int b = blk >> 8;
  int r = cls >> 1, s = cls & 1;
  int Ib = pt * 2;
  int co0 = ct * 64;
  int tid = threadIdx.x;
  int w = tid >> 6;                  // wave 0..3
  int lane = tid & 63;
  int lq = lane >> 4;                // quarter 0..3
  int lr = lane & 15;
  int wr = w >> 1;                   // I-row within tile
  int wc = w & 1;                    // co half
  int co0w = co0 + wc * 32;

  __shared__ __align__(16) unsigned short AH[3][33][40];
  __shared__ __align__(16) unsigned short AL[3][33][40];

  f32x4 acc[2][2];
#pragma unroll
  for (int pf = 0; pf < 2; ++pf)
#pragma unroll
    for (int cf = 0; cf < 2; ++cf) acc[pf][cf] = (f32x4){0.f, 0.f, 0.f, 0.f};

  const float* ab = attT + (size_t)b * 4 * 65536;
  int ih_base = Ib + r - 1;
  int iw_base = s - 1;

  for (int ci0 = 0; ci0 < 256; ci0 += 32) {
    int n = ci0 >> 6, d0 = ci0 & 63;
    __syncthreads();
    // stage A tile: 3 ih x 33 iw x 32 ci, fp32 -> bf16 hi/lo
    for (int idx = tid; idx < 3168; idx += 256) {
      int ciL = idx / 99;            // 0..31
      int rem = idx - ciL * 99;
      int rho = rem / 33;
      int c = rem - rho * 33;
      int ih = ih_base + rho;
      int iw = iw_base + c;
      float v = 0.f;
      if ((unsigned)ih < 32u && (unsigned)iw < 32u)
        v = ab[((size_t)n * 64 + d0 + ciL) * 1024 + ih * 32 + iw];
      unsigned short h = f32_to_bf16_rne(v);
      unsigned short lo = f32_to_bf16_rne(v - bf16_to_f32(h));
      AH[rho][c][ciL] = h;
      AL[rho][c][ciL] = lo;
    }
    __syncthreads();
#pragma unroll
    for (int tap = 0; tap < 4; ++tap) {
      int a_ = tap >> 1, b_ = tap & 1;
      int rho = wr + 1 - a_;
      short8 ah[2], al[2];
#pragma unroll
      for (int pf = 0; pf < 2; ++pf) {
        int col = pf * 16 + lr + 1 - b_;
        ah[pf] = *(const short8*)&AH[rho][col][8 * lq];
        al[pf] = *(const short8*)&AL[rho][col][8 * lq];
      }
      size_t wb = (size_t)(cls * 4 + tap) * 65536;
      short8 bh[2], bl[2];
#pragma unroll
      for (int cf = 0; cf < 2; ++cf) {
        size_t off = wb + (size_t)(co0w + cf * 16 + lr) * 256 + ci0 + 8 * lq;
        bh[cf] = *(const short8*)&whi[off];
        bl[cf] = *(const short8*)&wlo[off];
      }
#pragma unroll
      for (int pf = 0; pf < 2; ++pf)
#pragma unroll
        for (int cf = 0; cf < 2; ++cf) {
          acc[pf][cf] = __builtin_amdgcn_mfma_f32_16x16x32_bf16(ah[pf], bh[cf], acc[pf][cf], 0, 0, 0);
          acc[pf][cf] = __builtin_amdgcn_mfma_f32_16x16x32_bf16(al[pf], bh[cf], acc[pf][cf], 0, 0, 0);
          acc[pf][cf] = __builtin_amdgcn_mfma_f32_16x16x32_bf16(ah[pf], bl[cf], acc[pf][cf], 0, 0, 0);
        }
    }
  }

  int I = Ib + wr;
  int oh = 2 * I + r;
#pragma unroll
  for (int pf = 0; pf < 2; ++pf)
#pragma unroll
    for (int cf = 0; cf < 2; ++cf) {
      int co = co0w + cf * 16 + lr;
      float bv = bias[co];
      size_t cbase = ((size_t)b * 256 + co) * 4096 + oh * 64;
      size_t tbase = ((size_t)(b * 4 + (co >> 6)) * 4096 + oh * 64);
#pragma unroll
      for (int qd = 0; qd < 4; ++qd) {
        int J = pf * 16 + lq * 4 + qd;
        int ow = 2 * J + s;
        float val = acc[pf][cf][qd] + bv;
        cout[cbase + ow] = val;
        coutT[(tbase + ow) * 64 + (co & 63)] = val;
      }
    }
}

// ---------------- 8. y = coarse_out + region ----------------
__global__ __launch_bounds__(256) void k_ybuild(const float* __restrict__ cout,
                                                float* __restrict__ y) {
  size_t e = (size_t)blockIdx.x * 256 + threadIdx.x;
  int flat = (int)(e & 4095);
  size_t bc = e >> 12;
  int p = flat >> 2, ab = flat & 3;
  int a = ab >> 1, bi = ab & 1;
  int src = ((p >> 5) * 2 + a) * 64 + (p & 31) * 2 + bi;
  const float* cb = cout + bc * 4096;
  y[e] = cb[flat] + cb[src];
}

// ---------------- 9. scatter-add attended tokens ----------------
__global__ __launch_bounds__(256) void k_scatter(const float* __restrict__ out2,
    const int* __restrict__ idx, float* __restrict__ y) {
  int e = blockIdx.x * 256 + threadIdx.x;
  int d = e & 63;
  int r = e >> 6;
  int ab = r & 3;
  int r2 = r >> 2;
  int kk = r2 & 255;
  int bn = r2 >> 8;
  int b = bn >> 2, n = bn & 3;
  int p = idx[bn * 256 + kk] & 1023;
  int flat = p * 4 + ab;
  int t = kk * 4 + ab;
  y[((size_t)(b * 256 + n * 64 + d)) * 4096 + flat] +=
      out2[((size_t)bn * 1024 + t) * 64 + d];
}

// ---------------- 10. depthwise 3x3 + BN + relu6 ----------------
__global__ __launch_bounds__(256) void k_dw(const float* __restrict__ y,
    const float* __restrict__ w, const float* __restrict__ g, const float* __restrict__ bb,
    const float* __restrict__ mm, const float* __restrict__ vv, float* __restrict__ t1) {
  size_t e = (size_t)blockIdx.x * 256 + threadIdx.x;
  int pix = (int)(e & 4095);
  int c = (int)((e >> 12) & 255);
  int oh = pix >> 6, ow = pix & 63;
  const float* yb = y + (e - pix);
  float acc = 0.f;
#pragma unroll
  for (int kh = 0; kh < 3; ++kh) {
    int ih = oh - 1 + kh;
    if ((unsigned)ih >= 64u) continue;
#pragma unroll
    for (int kw = 0; kw < 3; ++kw) {
      int iw = ow - 1 + kw;
      if ((unsigned)iw >= 64u) continue;
      acc = fmaf(yb[ih * 64 + iw], w[c * 9 + kh * 3 + kw], acc);
    }
  }
  float s = g[c] * rsqrtf(vv[c] + 1e-5f);
  float val = acc * s + (bb[c] - mm[c] * s);
  t1[e] = fminf(fmaxf(val, 0.f), 6.f);
}

// ---------------- 11. pointwise v2: 4 co per block, 16 FMA per 16B load --------
__global__ __launch_bounds__(256) void k_pw2(const float* __restrict__ t1,
    const float* __restrict__ w, const float* __restrict__ g, const float* __restrict__ bb,
    const float* __restrict__ mm, const float* __restrict__ vv, float* __restrict__ out) {
  int blk = blockIdx.x;              // (b*64 + cog)*4 + tile
  int tile = blk & 3;
  int cog = (blk >> 2) & 63;
  int b = blk >> 8;
  int co0 = cog * 4;
  int t = threadIdx.x;
  __shared__ float wl[256][4];
  for (int idx = t; idx < 1024; idx += 256) {
    int cof = idx >> 8;
    int ci = idx & 255;
    wl[ci][cof] = w[(co0 + cof) * 256 + ci];
  }
  __syncthreads();
  int px0 = tile * 1024 + t * 4;
  const float* tb = t1 + (size_t)b * 256 * 4096 + px0;
  float acc[4][4];
#pragma unroll
  for (int a = 0; a < 4; ++a)
#pragma unroll
    for (int jj = 0; jj < 4; ++jj) acc[a][jj] = 0.f;
  for (int ci = 0; ci < 256; ++ci) {
    float4 tv = *(const float4*)(tb + (size_t)ci * 4096);
    float4 wv = *(const float4*)&wl[ci][0];
    acc[0][0] = fmaf(tv.x, wv.x, acc[0][0]); acc[0][1] = fmaf(tv.y, wv.x, acc[0][1]);
    acc[0][2] = fmaf(tv.z, wv.x, acc[0][2]); acc[0][3] = fmaf(tv.w, wv.x, acc[0][3]);
    acc[1][0] = fmaf(tv.x, wv.y, acc[1][0]); acc[1][1] = fmaf(tv.y, wv.y, acc[1][1]);
    acc[1][2] = fmaf(tv.z, wv.y, acc[1][2]); acc[1][3] = fmaf(tv.w, wv.y, acc[1][3]);
    acc[2][0] = fmaf(tv.x, wv.z, acc[2][0]); acc[2][1] = fmaf(tv.y, wv.z, acc[2][1]);
    acc[2][2] = fmaf(tv.z, wv.z, acc[2][2]); acc[2][3] = fmaf(tv.w, wv.z, acc[2][3]);
    acc[3][0] = fmaf(tv.x, wv.w, acc[3][0]); acc[3][1] = fmaf(tv.y, wv.w, acc[3][1]);
    acc[3][2] = fmaf(tv.z, wv.w, acc[3][2]); acc[3][3] = fmaf(tv.w, wv.w, acc[3][3]);
  }
#pragma unroll
  for (int a = 0; a < 4; ++a) {
    int co = co0 + a;
    float s = g[co] * rsqrtf(vv[co] + 1e-5f);
    float bias = bb[co] - mm[co] * s;
    float4 o4;
    o4.x = fminf(fmaxf(acc[a][0] * s + bias, 0.f), 6.f);
    o4.y = fminf(fmaxf(acc[a][1] * s + bias, 0.f), 6.f);
    o4.z = fminf(fmaxf(acc[a][2] * s + bias, 0.f), 6.f);
    o4.w = fminf(fmaxf(acc[a][3] * s + bias, 0.f), 6.f);
    *(float4*)(out + ((size_t)(b * 256 + co)) * 4096 + px0) = o4;
  }
}

// ---------------- launcher ----------------
extern "C" void kernel_launch(void* const* d_in, const int* in_sizes, int n_in,
                              void* d_out, int out_size, void* d_ws, size_t ws_size,
                              hipStream_t stream) {
  if (ws_size < WS_FLOATS * sizeof(float)) return;

  const float* x      = (const float*)d_in[0];
  const float* down_w = (const float*)d_in[1];
  const float* down_b = (const float*)d_in[2];
  const float* up_w   = (const float*)d_in[3];
  const float* up_b   = (const float*)d_in[4];
  const float* cqkv_w = (const float*)d_in[5];
  const float* cqkv_b = (const float*)d_in[6];
  const float* tqkv_w = (const float*)d_in[7];
  const float* tqkv_b = (const float*)d_in[8];
  const float* dww    = (const float*)d_in[9];
  const float* bn1g   = (const float*)d_in[10];
  const float* bn1b   = (const float*)d_in[11];
  const float* bn1m   = (const float*)d_in[12];
  const float* bn1v   = (const float*)d_in[13];
  const float* pww    = (const float*)d_in[14];
  const float* bn2g   = (const float*)d_in[15];
  const float* bn2b   = (const float*)d_in[16];
  const float* bn2m   = (const float*)d_in[17];
  const float* bn2v   = (const float*)d_in[18];

  float* ws    = (float*)d_ws;
  float* q     = ws + OFF_Q;
  float* k     = ws + OFF_K;
  float* v     = ws + OFF_V;
  float* att   = ws + OFF_ATT;
  float* spart = ws + OFF_SPART;
  float* score = ws + OFF_SCORE;
  int*   idx   = (int*)(ws + OFF_IDX);
  float* cout  = ws + OFF_COUT;
  float* y     = ws + OFF_Y;
  float* t1    = ws + OFF_T1;
  float* dwt   = ws + OFF_SPART;             // dead after k_conv_down3
  float* attT  = ws + OFF_SPART + 2097152;   // upper half of spart region
  unsigned short* whi = (unsigned short*)(ws + OFF_XD);            // 1M u16
  unsigned short* wlo = (unsigned short*)(ws + OFF_XD + 524288);   // 1M u16
  float* coutT = ws + OFF_T1;                // t1 region dead until k_dw
  float* dpart = ws + OFF_Y;                 // 4 x 2M ci-split partials (dead until k_ybuild)

  k_wt_dn<<<4096, 256, 0, stream>>>(down_w, dwt);
  k_conv_down3<<<2048, 256, 0, stream>>>(x, dwt, down_b, dpart);
  k_qkv_coarse<<<32768, 192, 0, stream>>>(dpart, cqkv_w, cqkv_b, q, k, v);
  k_wt_upb<<<4096, 256, 0, stream>>>(up_w, whi, wlo);
  k_attn_score<<<512, 256, 0, stream>>>(q, k, v, att, spart, attT);
  k_score_reduce<<<128, 256, 0, stream>>>(spart, score);
  k_idx_init<<<32, 256, 0, stream>>>(idx);
  k_topk<<<32, 1024, 0, stream>>>(score, idx);
  k_conv_up_mfma<<<2048, 256, 0, stream>>>(attT, whi, wlo, up_b, cout, coutT);
  k_qkv_topk<<<32768, 192, 0, stream>>>(coutT, idx, tqkv_w, tqkv_b, q, k, v);
  k_attn_online<<<512, 256, 0, stream>>>(q, k, v, att);
  k_ybuild<<<32768, 256, 0, stream>>>(cout, y);
  k_scatter<<<8192, 256, 0, stream>>>(att, idx, y);
  k_dw<<<32768, 256, 0, stream>>>(y, dww, bn1g, bn1b, bn1m, bn1v, t1);
  k_pw2<<<2048, 256, 0, stream>>>(t1, pww, bn2g, bn2b, bn2m, bn2v, (float*)d_out);
}

// Round 4
// 1418.048 us; speedup vs baseline: 1.1992x; 1.0897x over previous
//
#include <hip/hip_runtime.h>

typedef short short8 __attribute__((ext_vector_type(8)));
typedef float f32x4 __attribute__((ext_vector_type(4)));

__device__ inline unsigned short f32_to_bf16_rne(float f) {
  unsigned int u = __float_as_uint(f);
  unsigned int r = (u + 0x7fffu + ((u >> 16) & 1u)) >> 16;
  return (unsigned short)r;
}
__device__ inline float bf16_to_f32(unsigned short h) {
  return __uint_as_float(((unsigned int)h) << 16);
}

// ---------------- workspace layout (float offsets) ----------------
// q/k/v [32,1024,64]  att [32,1024,64]
// spart[32,16,1024] (+ attT [32,64,1024] at +2M)  score [32,1024]   idx [32,256]
// cout [8,256,64,64]      y     [8,256,64,64]     t1   [8,256,64,64]
// aliases: whi/wlo (bf16 up-w) -> XD; dwhi/dwlo (bf16 down-w) -> SPART
//          xbh -> Q..K regions (8.4M u16), xbl -> V..ATT regions (dead after conv_down)
//          attT -> spart +2M; coutT -> t1 region; dpart -> y region
constexpr size_t OFF_XD    = 0;
constexpr size_t OFF_Q     = 2097152;
constexpr size_t OFF_K     = 4194304;
constexpr size_t OFF_V     = 6291456;
constexpr size_t OFF_ATT   = 8388608;
constexpr size_t OFF_SPART = 10485760;
constexpr size_t OFF_SCORE = 14680064;
constexpr size_t OFF_IDX   = 14712832;
constexpr size_t OFF_COUT  = 14721024;
constexpr size_t OFF_Y     = 23109632;
constexpr size_t OFF_T1    = 31498240;
constexpr size_t WS_FLOATS = 39886848;

// ---------------- 0a. x NCHW -> NHWC split-bf16 (xbh/xbl [b][ih][iw][ci]) ------
__global__ __launch_bounds__(256) void k_x2bf(const float* __restrict__ x,
    unsigned short* __restrict__ xbh, unsigned short* __restrict__ xbl) {
  int bid = blockIdx.x;              // b*128 + ih*2 + iwh
  int b = bid >> 7;
  int ih = (bid >> 1) & 63;
  int iwh = bid & 1;
  int t = threadIdx.x;
  __shared__ float ts[256][33];
  for (int it = 0; it < 32; ++it) {
    int idx = it * 256 + t;
    int ci = idx >> 5;
    int iwl = idx & 31;
    ts[ci][iwl] = x[(((size_t)(b * 256 + ci) * 64 + ih) * 64) + iwh * 32 + iwl];
  }
  __syncthreads();
  int iwl = t >> 3;
  int cb = (t & 7) * 32;
  size_t base = (((size_t)(b * 64 + ih) * 64) + iwh * 32 + iwl) * 256 + cb;
#pragma unroll
  for (int j = 0; j < 32; j += 2) {
    float v0 = ts[cb + j][iwl];
    float v1 = ts[cb + j + 1][iwl];
    unsigned short h0 = f32_to_bf16_rne(v0);
    unsigned short h1 = f32_to_bf16_rne(v1);
    unsigned short l0 = f32_to_bf16_rne(v0 - bf16_to_f32(h0));
    unsigned short l1 = f32_to_bf16_rne(v1 - bf16_to_f32(h1));
    *(ushort2*)&xbh[base + j] = make_ushort2(h0, h1);
    *(ushort2*)&xbl[base + j] = make_ushort2(l0, l1);
  }
}

// ---------------- 0b. down_w -> split-bf16 dwhi/dwlo [kk][co][ci] --------------
__global__ __launch_bounds__(256) void k_wt_dnb(const float* __restrict__ w,
    unsigned short* __restrict__ dwhi, unsigned short* __restrict__ dwlo) {
  int idx = blockIdx.x * 256 + threadIdx.x;   // 1,048,576 = (kk*256+co)*256+ci
  int ci = idx & 255;
  int co = (idx >> 8) & 255;
  int kk = idx >> 16;
  float v = w[((size_t)(co * 256 + ci)) * 16 + kk];
  unsigned short h = f32_to_bf16_rne(v);
  unsigned short l = f32_to_bf16_rne(v - bf16_to_f32(h));
  dwhi[idx] = h;
  dwlo[idx] = l;
}

// ---------------- 0c. up_w -> split-bf16 whi/wlo [cls][tap][co][ci] ----------
__global__ __launch_bounds__(256) void k_wt_upb(const float* __restrict__ w,
    unsigned short* __restrict__ whi, unsigned short* __restrict__ wlo) {
  int idx = blockIdx.x * 256 + threadIdx.x;   // 1,048,576
  int ci = idx & 255;
  int co = (idx >> 8) & 255;
  int tp = idx >> 16;                         // 0..15
  int cls = tp >> 2, tap = tp & 3;
  int r = cls >> 1, s = cls & 1;
  int a_ = tap >> 1, b_ = tap & 1;
  int kh = a_ ? (r ? 2 : 3) : (r ? 0 : 1);
  int kw = b_ ? (s ? 2 : 3) : (s ? 0 : 1);
  float v = w[((size_t)(ci * 256 + co)) * 16 + kh * 4 + kw];
  unsigned short h = f32_to_bf16_rne(v);
  unsigned short l = f32_to_bf16_rne(v - bf16_to_f32(h));
  whi[idx] = h;
  wlo[idx] = l;
}

// ---------------- 1. down conv: split-bf16 MFMA implicit GEMM ------------------
// out(oh,ow)[co] = sum_{ci,kh,kw} x[ci][2oh-1+kh][2ow-1+kw] * w[co][ci][kh][kw]
// block: 32 pixels (2oh x 16ow) x 64 co; 4 waves = N-split (16 co each).
// ci-split x4 -> dpart partials (bias on ks==0). A halo tile [6][34][40] hi/lo LDS.
__global__ __launch_bounds__(256) void k_conv_down_mfma(
    const unsigned short* __restrict__ xbh, const unsigned short* __restrict__ xbl,
    const unsigned short* __restrict__ dwhi, const unsigned short* __restrict__ dwlo,
    const float* __restrict__ bias, float* __restrict__ part) {
  int blk = blockIdx.x;              // ((ks*8 + b)*4 + ct)*32 + pt
  int pt = blk & 31;
  int ct = (blk >> 5) & 3;
  int b = (blk >> 7) & 7;
  int ks = blk >> 10;
  int oh2 = pt >> 1;                 // 0..15 (pair of oh rows)
  int owh = pt & 1;                  // ow half (16)
  int tid = threadIdx.x;
  int w = tid >> 6;                  // wave 0..3 -> co quarter
  int lane = tid & 63;
  int lq = lane >> 4;
  int lr = lane & 15;
  int co = ct * 64 + w * 16 + lr;

  __shared__ __align__(16) unsigned short AH[6][34][40];
  __shared__ __align__(16) unsigned short AL[6][34][40];

  f32x4 acc[2];
  acc[0] = (f32x4){0.f, 0.f, 0.f, 0.f};
  acc[1] = (f32x4){0.f, 0.f, 0.f, 0.f};

  int ih0 = 4 * oh2 - 1;             // tile row 0
  int iw0 = owh * 32 - 1;            // tile col 0
  const short8 zero8 = {0, 0, 0, 0, 0, 0, 0, 0};

  for (int ch = 0; ch < 2; ++ch) {
    int ci0 = ks * 64 + ch * 32;
    __syncthreads();
    // stage A tile: 6 rows x 34 cols x 32 ci (hi+lo), 16B per (cell,quarter)
    for (int idx = tid; idx < 6 * 34 * 4; idx += 256) {
      int q = idx & 3;
      int cell = idx >> 2;
      int row = cell / 34;
      int col = cell - row * 34;
      int ih = ih0 + row;
      int iw = iw0 + col;
      short8 h = zero8, l = zero8;
      if ((unsigned)ih < 64u && (unsigned)iw < 64u) {
        size_t g = (((size_t)(b * 64 + ih) * 64) + iw) * 256 + ci0 + q * 8;
        h = *(const short8*)&xbh[g];
        l = *(const short8*)&xbl[g];
      }
      *(short8*)&AH[row][col][q * 8] = h;
      *(short8*)&AL[row][col][q * 8] = l;
    }
    __syncthreads();
#pragma unroll
    for (int tap = 0; tap < 16; ++tap) {
      int kh = tap >> 2, kw = tap & 3;
      // B frags: dw[tap][co][ci], ci contiguous (wave-broadcast rows, L2)
      size_t woff = ((size_t)tap * 256 + co) * 256 + ci0 + 8 * lq;
      short8 bh = *(const short8*)&dwhi[woff];
      short8 bl = *(const short8*)&dwlo[woff];
#pragma unroll
      for (int pf = 0; pf < 2; ++pf) {
        short8 ah = *(const short8*)&AH[2 * pf + kh][2 * lr + kw][8 * lq];
        short8 al = *(const short8*)&AL[2 * pf + kh][2 * lr + kw][8 * lq];
        acc[pf] = __builtin_amdgcn_mfma_f32_16x16x32_bf16(ah, bh, acc[pf], 0, 0, 0);
        acc[pf] = __builtin_amdgcn_mfma_f32_16x16x32_bf16(al, bh, acc[pf], 0, 0, 0);
        acc[pf] = __builtin_amdgcn_mfma_f32_16x16x32_bf16(ah, bl, acc[pf], 0, 0, 0);
      }
    }
  }

  float bv = (ks == 0) ? bias[co] : 0.f;
  int bn = b * 4 + ct;
  int d = w * 16 + lr;
  float* pb = part + (size_t)ks * 2097152;
#pragma unroll
  for (int pf = 0; pf < 2; ++pf) {
    int oh = 2 * oh2 + pf;
#pragma unroll
    for (int reg = 0; reg < 4; ++reg) {
      int ow = owh * 16 + lq * 4 + reg;
      int pix = oh * 32 + ow;
      pb[((size_t)bn * 1024 + pix) * 64 + d] = acc[pf][reg] + bv;
    }
  }
}

// ---------------- 2. QKV gemm coarse: sums the 4 ci-split partials -------------
__global__ __launch_bounds__(192) void k_qkv_coarse(const float* __restrict__ part,
    const float* __restrict__ W, const float* __restrict__ bias,
    float* __restrict__ q, float* __restrict__ k, float* __restrict__ v) {
  int row = blockIdx.x;              // bn*1024 + i
  __shared__ float t[64];
  if (threadIdx.x < 64) {
    size_t o = (size_t)row * 64 + threadIdx.x;
    t[threadIdx.x] = ((part[o] + part[o + 2097152]) +
                      part[o + 2 * 2097152]) + part[o + 3 * 2097152];
  }
  __syncthreads();
  int e = threadIdx.x;               // 0..191
  float acc = bias[e];
  const float* wr = W + e * 64;
#pragma unroll
  for (int d = 0; d < 64; ++d) acc = fmaf(t[d], wr[d], acc);
  float* dst = (e < 64) ? q : (e < 128) ? k : v;
  dst[(size_t)row * 64 + (e & 63)] = acc;
}

// ---------------- 3. QKV gemm topk: coalesced coutT staging ----------------
__global__ __launch_bounds__(192) void k_qkv_topk(const float* __restrict__ coutT,
    const int* __restrict__ idx, const float* __restrict__ W, const float* __restrict__ bias,
    float* __restrict__ q, float* __restrict__ k, float* __restrict__ v) {
  int row = blockIdx.x;              // bn*1024 + t
  int bn = row >> 10, t = row & 1023;
  int kk = t >> 2, ab = t & 3;
  int a = ab >> 1, bi = ab & 1;
  __shared__ float tl[64];
  __shared__ int ps;
  if (threadIdx.x == 0) ps = idx[bn * 256 + kk] & 1023;
  __syncthreads();
  int p = ps;
  int sh = (p >> 5) * 2 + a, sw = (p & 31) * 2 + bi;
  if (threadIdx.x < 64)
    tl[threadIdx.x] = coutT[((size_t)bn * 4096 + sh * 64 + sw) * 64 + threadIdx.x];
  __syncthreads();
  int e = threadIdx.x;
  float acc = bias[e];
  const float* wr = W + e * 64;
#pragma unroll
  for (int d = 0; d < 64; ++d) acc = fmaf(tl[d], wr[d], acc);
  float* dst = (e < 64) ? q : (e < 128) ? k : v;
  dst[(size_t)row * 64 + (e & 63)] = acc;
}

// ---------------- 4a. attention with score (2-pass; score needs all l_i) ------
__global__ __launch_bounds__(256) void k_attn_score(
    const float* __restrict__ Q, const float* __restrict__ K,
    const float* __restrict__ V, float* __restrict__ O,
    float* __restrict__ spart, float* __restrict__ attT) {
  int bn = blockIdx.x >> 4;
  int it = blockIdx.x & 15;
  int tid = threadIdx.x;
  int rowgrp = tid >> 4;        // 0..15
  int colgrp = tid & 15;        // 0..15
  int i0 = rowgrp * 4;
  int j0 = colgrp * 4;
  const float* qb = Q + (size_t)bn * 65536;
  const float* kb = K + (size_t)bn * 65536;
  const float* vb = V + (size_t)bn * 65536;
  int ibase = it * 64;

  __shared__ float Ks[64][68];   // [d][i] transposed
  __shared__ float QP[64][68];   // Q transposed [d][j], reused as P [j][i]
  __shared__ float Vs[64][68];   // [j][d] natural
  __shared__ float sacc[1024];

  for (int i = tid; i < 1024; i += 256) sacc[i] = 0.f;

  {
    int r = tid >> 4, c4 = tid & 15;
#pragma unroll
    for (int p4 = 0; p4 < 4; ++p4) {
      int i = p4 * 16 + r;
      float4 kv = *(const float4*)(kb + (size_t)(ibase + i) * 64 + c4 * 4);
      Ks[c4 * 4 + 0][i] = kv.x;
      Ks[c4 * 4 + 1][i] = kv.y;
      Ks[c4 * 4 + 2][i] = kv.z;
      Ks[c4 * 4 + 3][i] = kv.w;
    }
  }

  float m[4], l[4];
#pragma unroll
  for (int a = 0; a < 4; ++a) { m[a] = -3.0e38f; l[a] = 0.f; }

  for (int jt = 0; jt < 16; ++jt) {
    __syncthreads();
    {
      int r = tid >> 4, c4 = tid & 15;
#pragma unroll
      for (int p4 = 0; p4 < 4; ++p4) {
        int j = p4 * 16 + r;
        float4 qv = *(const float4*)(qb + (size_t)(jt * 64 + j) * 64 + c4 * 4);
        QP[c4 * 4 + 0][j] = qv.x;
        QP[c4 * 4 + 1][j] = qv.y;
        QP[c4 * 4 + 2][j] = qv.z;
        QP[c4 * 4 + 3][j] = qv.w;
      }
    }
    __syncthreads();
    float s[4][4];
#pragma unroll
    for (int a = 0; a < 4; ++a)
#pragma unroll
      for (int b = 0; b < 4; ++b) s[a][b] = 0.f;
#pragma unroll 4
    for (int d = 0; d < 64; ++d) {
      float4 kv = *(const float4*)&Ks[d][i0];
      float4 qv = *(const float4*)&QP[d][j0];
      s[0][0] = fmaf(kv.x, qv.x, s[0][0]); s[0][1] = fmaf(kv.x, qv.y, s[0][1]);
      s[0][2] = fmaf(kv.x, qv.z, s[0][2]); s[0][3] = fmaf(kv.x, qv.w, s[0][3]);
      s[1][0] = fmaf(kv.y, qv.x, s[1][0]); s[1][1] = fmaf(kv.y, qv.y, s[1][1]);
      s[1][2] = fmaf(kv.y, qv.z, s[1][2]); s[1][3] = fmaf(kv.y, qv.w, s[1][3]);
      s[2][0] = fmaf(kv.z, qv.x, s[2][0]); s[2][1] = fmaf(kv.z, qv.y, s[2][1]);
      s[2][2] = fmaf(kv.z, qv.z, s[2][2]); s[2][3] = fmaf(kv.z, qv.w, s[2][3]);
      s[3][0] = fmaf(kv.w, qv.x, s[3][0]); s[3][1] = fmaf(kv.w, qv.y, s[3][1]);
      s[3][2] = fmaf(kv.w, qv.z, s[3][2]); s[3][3] = fmaf(kv.w, qv.w, s[3][3]);
    }
#pragma unroll
    for (int a = 0; a < 4; ++a) {
      float tm = fmaxf(fmaxf(s[a][0], s[a][1]), fmaxf(s[a][2], s[a][3]));
#pragma unroll
      for (int off = 1; off <= 8; off <<= 1) tm = fmaxf(tm, __shfl_xor(tm, off, 64));
      float mn = fmaxf(m[a], tm);
      float ts = ((expf(s[a][0] - mn) + expf(s[a][1] - mn)) +
                  expf(s[a][2] - mn)) + expf(s[a][3] - mn);
#pragma unroll
      for (int off = 1; off <= 8; off <<= 1) ts += __shfl_xor(ts, off, 64);
      l[a] = l[a] * expf(m[a] - mn) + ts;
      m[a] = mn;
    }
  }
  float inv[4];
#pragma unroll
  for (int a = 0; a < 4; ++a) inv[a] = 1.f / l[a];

  float accO[4][4];
#pragma unroll
  for (int a = 0; a < 4; ++a)
#pragma unroll
    for (int b = 0; b < 4; ++b) accO[a][b] = 0.f;

  for (int jt = 0; jt < 16; ++jt) {
    __syncthreads();
    {
      int r = tid >> 4, c4 = tid & 15;
#pragma unroll
      for (int p4 = 0; p4 < 4; ++p4) {
        int j = p4 * 16 + r;
        float4 qv = *(const float4*)(qb + (size_t)(jt * 64 + j) * 64 + c4 * 4);
        QP[c4 * 4 + 0][j] = qv.x;
        QP[c4 * 4 + 1][j] = qv.y;
        QP[c4 * 4 + 2][j] = qv.z;
        QP[c4 * 4 + 3][j] = qv.w;
        float4 vv = *(const float4*)(vb + (size_t)(jt * 64 + j) * 64 + c4 * 4);
        *(float4*)&Vs[j][c4 * 4] = vv;
      }
    }
    __syncthreads();
    float s[4][4];
#pragma unroll
    for (int a = 0; a < 4; ++a)
#pragma unroll
      for (int b = 0; b < 4; ++b) s[a][b] = 0.f;
#pragma unroll 4
    for (int d = 0; d < 64; ++d) {
      float4 kv = *(const float4*)&Ks[d][i0];
      float4 qv = *(const float4*)&QP[d][j0];
      s[0][0] = fmaf(kv.x, qv.x, s[0][0]); s[0][1] = fmaf(kv.x, qv.y, s[0][1]);
      s[0][2] = fmaf(kv.x, qv.z, s[0][2]); s[0][3] = fmaf(kv.x, qv.w, s[0][3]);
      s[1][0] = fmaf(kv.y, qv.x, s[1][0]); s[1][1] = fmaf(kv.y, qv.y, s[1][1]);
      s[1][2] = fmaf(kv.y, qv.z, s[1][2]); s[1][3] = fmaf(kv.y, qv.w, s[1][3]);
      s[2][0] = fmaf(kv.z, qv.x, s[2][0]); s[2][1] = fmaf(kv.z, qv.y, s[2][1]);
      s[2][2] = fmaf(kv.z, qv.z, s[2][2]); s[2][3] = fmaf(kv.z, qv.w, s[2][3]);
      s[3][0] = fmaf(kv.w, qv.x, s[3][0]); s[3][1] = fmaf(kv.w, qv.y, s[3][1]);
      s[3][2] = fmaf(kv.w, qv.z, s[3][2]); s[3][3] = fmaf(kv.w, qv.w, s[3][3]);
    }
    float p[4][4];
#pragma unroll
    for (int a = 0; a < 4; ++a)
#pragma unroll
      for (int b = 0; b < 4; ++b) p[a][b] = expf(s[a][b] - m[a]) * inv[a];
#pragma unroll
    for (int b = 0; b < 4; ++b) {
      float cs = ((p[0][b] + p[1][b]) + p[2][b]) + p[3][b];
      atomicAdd(&sacc[jt * 64 + j0 + b], cs);
    }
    __syncthreads();
#pragma unroll
    for (int b = 0; b < 4; ++b)
      *(float4*)&QP[j0 + b][i0] = make_float4(p[0][b], p[1][b], p[2][b], p[3][b]);
    __syncthreads();
#pragma unroll 4
    for (int j = 0; j < 64; ++j) {
      float4 pv = *(const float4*)&QP[j][i0];
      float4 vv = *(const float4*)&Vs[j][j0];
      accO[0][0] = fmaf(pv.x, vv.x, accO[0][0]); accO[0][1] = fmaf(pv.x, vv.y, accO[0][1]);
      accO[0][2] = fmaf(pv.x, vv.z, accO[0][2]); accO[0][3] = fmaf(pv.x, vv.w, accO[0][3]);
      accO[1][0] = fmaf(pv.y, vv.x, accO[1][0]); accO[1][1] = fmaf(pv.y, vv.y, accO[1][1]);
      accO[1][2] = fmaf(pv.y, vv.z, accO[1][2]); accO[1][3] = fmaf(pv.y, vv.w, accO[1][3]);
      accO[2][0] = fmaf(pv.z, vv.x, accO[2][0]); accO[2][1] = fmaf(pv.z, vv.y, accO[2][1]);
      accO[2][2] = fmaf(pv.z, vv.z, accO[2][2]); accO[2][3] = fmaf(pv.z, vv.w, accO[2][3]);
      accO[3][0] = fmaf(pv.w, vv.x, accO[3][0]); accO[3][1] = fmaf(pv.w, vv.y, accO[3][1]);
      accO[3][2] = fmaf(pv.w, vv.z, accO[3][2]); accO[3][3] = fmaf(pv.w, vv.w, accO[3][3]);
    }
  }
#pragma unroll
  for (int a = 0; a < 4; ++a) {
    float4 o4 = make_float4(accO[a][0], accO[a][1], accO[a][2], accO[a][3]);
    *(float4*)(O + ((size_t)bn * 1024 + ibase + i0 + a) * 64 + j0) = o4;
  }
  // transposed copy for conv_up staging: attT[bn][d][i]
#pragma unroll
  for (int a = 0; a < 4; ++a)
#pragma unroll
    for (int b = 0; b < 4; ++b)
      attT[((size_t)bn * 64 + j0 + b) * 1024 + ibase + i0 + a] = accO[a][b];
  __syncthreads();
  for (int i = tid; i < 1024; i += 256)
    spart[((size_t)bn * 16 + it) * 1024 + i] = sacc[i];
}

// ---------------- 4b. topk attention: single-pass online softmax ----------------
__global__ __launch_bounds__(256) void k_attn_online(
    const float* __restrict__ Q, const float* __restrict__ K,
    const float* __restrict__ V, float* __restrict__ O) {
  int bn = blockIdx.x >> 4;
  int it = blockIdx.x & 15;
  int tid = threadIdx.x;
  int i0 = (tid >> 4) * 4;
  int j0 = (tid & 15) * 4;
  const float* qb = Q + (size_t)bn * 65536;
  const float* kb = K + (size_t)bn * 65536;
  const float* vb = V + (size_t)bn * 65536;
  int ibase = it * 64;

  __shared__ float Ks[64][68];   // [d][i] transposed
  __shared__ float QP[64][68];   // Q transposed [d][j], reused as P [j][i]
  __shared__ float Vs[64][68];   // [j][d] natural

  {
    int r = tid >> 4, c4 = tid & 15;
#pragma unroll
    for (int p4 = 0; p4 < 4; ++p4) {
      int i = p4 * 16 + r;
      float4 kv = *(const float4*)(kb + (size_t)(ibase + i) * 64 + c4 * 4);
      Ks[c4 * 4 + 0][i] = kv.x;
      Ks[c4 * 4 + 1][i] = kv.y;
      Ks[c4 * 4 + 2][i] = kv.z;
      Ks[c4 * 4 + 3][i] = kv.w;
    }
  }

  float m[4], l[4], accO[4][4];
#pragma unroll
  for (int a = 0; a < 4; ++a) {
    m[a] = -3.0e38f; l[a] = 0.f;
#pragma unroll
    for (int b = 0; b < 4; ++b) accO[a][b] = 0.f;
  }

  for (int jt = 0; jt < 16; ++jt) {
    __syncthreads();
    {
      int r = tid >> 4, c4 = tid & 15;
#pragma unroll
      for (int p4 = 0; p4 < 4; ++p4) {
        int j = p4 * 16 + r;
        float4 qv = *(const float4*)(qb + (size_t)(jt * 64 + j) * 64 + c4 * 4);
        QP[c4 * 4 + 0][j] = qv.x;
        QP[c4 * 4 + 1][j] = qv.y;
        QP[c4 * 4 + 2][j] = qv.z;
        QP[c4 * 4 + 3][j] = qv.w;
        float4 vv = *(const float4*)(vb + (size_t)(jt * 64 + j) * 64 + c4 * 4);
        *(float4*)&Vs[j][c4 * 4] = vv;
      }
    }
    __syncthreads();
    float s[4][4];
#pragma unroll
    for (int a = 0; a < 4; ++a)
#pragma unroll
      for (int b = 0; b < 4; ++b) s[a][b] = 0.f;
#pragma unroll 4
    for (int d = 0; d < 64; ++d) {
      float4 kv = *(const float4*)&Ks[d][i0];
      float4 qv = *(const float4*)&QP[d][j0];
      s[0][0] = fmaf(kv.x, qv.x, s[0][0]); s[0][1] = fmaf(kv.x, qv.y, s[0][1]);
      s[0][2] = fmaf(kv.x, qv.z, s[0][2]); s[0][3] = fmaf(kv.x, qv.w, s[0][3]);
      s[1][0] = fmaf(kv.y, qv.x, s[1][0]); s[1][1] = fmaf(kv.y, qv.y, s[1][1]);
      s[1][2] = fmaf(kv.y, qv.z, s[1][2]); s[1][3] = fmaf(kv.y, qv.w, s[1][3]);
      s[2][0] = fmaf(kv.z, qv.x, s[2][0]); s[2][1] = fmaf(kv.z, qv.y, s[2][1]);
      s[2][2] = fmaf(kv.z, qv.z, s[2][2]); s[2][3] = fmaf(kv.z, qv.w, s[2][3]);
      s[3][0] = fmaf(kv.w, qv.x, s[3][0]); s[3][1] = fmaf(kv.w, qv.y, s[3][1]);
      s[3][2] = fmaf(kv.w, qv.z, s[3][2]); s[3][3] = fmaf(kv.w, qv.w, s[3][3]);
    }
    float p[4][4];
#pragma unroll
    for (int a = 0; a < 4; ++a) {
      float tm = fmaxf(fmaxf(s[a][0], s[a][1]), fmaxf(s[a][2], s[a][3]));
#pragma unroll
      for (int off = 1; off <= 8; off <<= 1) tm = fmaxf(tm, __shfl_xor(tm, off, 64));
      float mn = fmaxf(m[a], tm);
      float sc = expf(m[a] - mn);
      p[a][0] = expf(s[a][0] - mn); p[a][1] = expf(s[a][1] - mn);
      p[a][2] = expf(s[a][2] - mn); p[a][3] = expf(s[a][3] - mn);
      float ts = ((p[a][0] + p[a][1]) + p[a][2]) + p[a][3];
#pragma unroll
      for (int off = 1; off <= 8; off <<= 1) ts += __shfl_xor(ts, off, 64);
      l[a] = l[a] * sc + ts;
      m[a] = mn;
#pragma unroll
      for (int b = 0; b < 4; ++b) accO[a][b] *= sc;
    }
    __syncthreads();
#pragma unroll
    for (int b = 0; b < 4; ++b)
      *(float4*)&QP[j0 + b][i0] = make_float4(p[0][b], p[1][b], p[2][b], p[3][b]);
    __syncthreads();
#pragma unroll 4
    for (int j = 0; j < 64; ++j) {
      float4 pv = *(const float4*)&QP[j][i0];
      float4 vv = *(const float4*)&Vs[j][j0];
      accO[0][0] = fmaf(pv.x, vv.x, accO[0][0]); accO[0][1] = fmaf(pv.x, vv.y, accO[0][1]);
      accO[0][2] = fmaf(pv.x, vv.z, accO[0][2]); accO[0][3] = fmaf(pv.x, vv.w, accO[0][3]);
      accO[1][0] = fmaf(pv.y, vv.x, accO[1][0]); accO[1][1] = fmaf(pv.y, vv.y, accO[1][1]);
      accO[1][2] = fmaf(pv.y, vv.z, accO[1][2]); accO[1][3] = fmaf(pv.y, vv.w, accO[1][3]);
      accO[2][0] = fmaf(pv.z, vv.x, accO[2][0]); accO[2][1] = fmaf(pv.z, vv.y, accO[2][1]);
      accO[2][2] = fmaf(pv.z, vv.z, accO[2][2]); accO[2][3] = fmaf(pv.z, vv.w, accO[2][3]);
      accO[3][0] = fmaf(pv.w, vv.x, accO[3][0]); accO[3][1] = fmaf(pv.w, vv.y, accO[3][1]);
      accO[3][2] = fmaf(pv.w, vv.z, accO[3][2]); accO[3][3] = fmaf(pv.w, vv.w, accO[3][3]);
    }
  }
#pragma unroll
  for (int a = 0; a < 4; ++a) {
    float inv = 1.f / l[a];
    float4 o4 = make_float4(accO[a][0] * inv, accO[a][1] * inv,
                            accO[a][2] * inv, accO[a][3] * inv);
    *(float4*)(O + ((size_t)bn * 1024 + ibase + i0 + a) * 64 + j0) = o4;
  }
}

// ---------------- 5. deterministic score reduction (16 partials) ----------------
__global__ __launch_bounds__(256) void k_score_reduce(const float* __restrict__ part,
                                                      float* __restrict__ score) {
  int j = blockIdx.x * 256 + threadIdx.x;   // 0..32767
  int bn = j >> 10, jj = j & 1023;
  float s = 0.f;
  for (int g = 0; g < 16; ++g) s += part[((size_t)bn * 16 + g) * 1024 + jj];
  score[j] = s;
}

// ---------------- 5b. default-init idx ----------------
__global__ __launch_bounds__(256) void k_idx_init(int* __restrict__ idx) {
  int j = blockIdx.x * 256 + threadIdx.x;
  idx[j] = j & 255;
}

// ---------------- 6. top-K by rank ----------------
__global__ __launch_bounds__(1024) void k_topk(const float* __restrict__ score,
                                               int* __restrict__ idxout) {
  int bn = blockIdx.x;
  int t = threadIdx.x;
  __shared__ float s[1024];
  s[t] = score[bn * 1024 + t];
  __syncthreads();
  float my = s[t];
  int rank = 0;
  for (int j = 0; j < 1024; ++j) {
    float o = s[j];
    rank += (o > my) || (o == my && j < t);
  }
  if (rank < 256) idxout[bn * 256 + rank] = t;
}

// ---------------- 7. transposed conv: split-bf16 MFMA implicit GEMM -----------
__global__ __launch_bounds__(256) void k_conv_up_mfma(
    const float* __restrict__ attT, const unsigned short* __restrict__ whi,
    const unsigned short* __restrict__ wlo, const float* __restrict__ bias,
    float* __restrict__ cout, float* __restrict__ coutT) {
  int blk = blockIdx.x;              // ((b*4 + cls)*16 + pt)*4 + ct
  int ct = blk & 3;
  int pt = (blk >> 2) & 15;
  int cls = (blk >> 6) & 3;
  int b = blk >> 8;
  int r = cls >> 1, s = cls & 1;
  int Ib = pt * 2;
  int co0 = ct * 64;
  int tid = threadIdx.x;
  int w = tid >> 6;                  // wave 0..3
  int lane = tid & 63;
  int lq = lane >> 4;                // quarter 0..3
  int lr = lane & 15;
  int wr = w >> 1;                   // I-row within tile
  int wc = w & 1;                    // co half
  int co0w = co0 + wc * 32;

  __shared__ __align__(16) unsigned short AH[3][33][40];
  __shared__ __align__(16) unsigned short AL[3][33][40];

  f32x4 acc[2][2];
#pragma unroll
  for (int pf = 0; pf < 2; ++pf)
#pragma unroll
    for (int cf = 0; cf < 2; ++cf) acc[pf][cf] = (f32x4){0.f, 0.f, 0.f, 0.f};

  const float* ab = attT + (size_t)b * 4 * 65536;
  int ih_base = Ib + r - 1;
  int iw_base = s - 1;

  for (int ci0 = 0; ci0 < 256; ci0 += 32) {
    int n = ci0 >> 6, d0 = ci0 & 63;
    __syncthreads();
    // stage A tile: 3 ih x 33 iw x 32 ci, fp32 -> bf16 hi/lo
    for (int idx = tid; idx < 3168; idx += 256) {
      int ciL = idx / 99;            // 0..31
      int rem = idx - ciL * 99;
      int rho = rem / 33;
      int c = rem - rho * 33;
      int ih = ih_base + rho;
      int iw = iw_base + c;
      float v = 0.f;
      if ((unsigned)ih < 32u && (unsigned)iw < 32u)
        v = ab[((size_t)n * 64 + d0 + ciL) * 1024 + ih * 32 + iw];
      unsigned short h = f32_to_bf16_rne(v);
      unsigned short lo = f32_to_bf16_rne(v - bf16_to_f32(h));
      AH[rho][c][ciL] = h;
      AL[rho][c][ciL] = lo;
    }
    __syncthreads();
#pragma unroll
    for (int tap = 0; tap < 4; ++tap) {
      int a_ = tap >> 1, b_ = tap & 1;
      int rho = wr + 1 - a_;
      short8 ah[2], al[2];
#pragma unroll
      for (int pf = 0; pf < 2; ++pf) {
        int col = pf * 16 + lr + 1 - b_;
        ah[pf] = *(const short8*)&AH[rho][col][8 * lq];
        al[pf] = *(const short8*)&AL[rho][col][8 * lq];
      }
      size_t wb = (size_t)(cls * 4 + tap) * 65536;
      short8 bh[2], bl[2];
#pragma unroll
      for (int cf = 0; cf < 2; ++cf) {
        size_t off = wb + (size_t)(co0w + cf * 16 + lr) * 256 + ci0 + 8 * lq;
        bh[cf] = *(const short8*)&whi[off];
        bl[cf] = *(const short8*)&wlo[off];
      }
#pragma unroll
      for (int pf = 0; pf < 2; ++pf)
#pragma unroll
        for (int cf = 0; cf < 2; ++cf) {
          acc[pf][cf] = __builtin_amdgcn_mfma_f32_16x16x32_bf16(ah[pf], bh[cf], acc[pf][cf], 0, 0, 0);
          acc[pf][cf] = __builtin_amdgcn_mfma_f32_16x16x32_bf16(al[pf], bh[cf], acc[pf][cf], 0, 0, 0);
          acc[pf][cf] = __builtin_amdgcn_mfma_f32_16x16x32_bf16(ah[pf], bl[cf], acc[pf][cf], 0, 0, 0);
        }
    }
  }

  int I = Ib + wr;
  int oh = 2 * I + r;
#pragma unroll
  for (int pf = 0; pf < 2; ++pf)
#pragma unroll
    for (int cf = 0; cf < 2; ++cf) {
      int co = co0w + cf * 16 + lr;
      float bv = bias[co];
      size_t cbase = ((size_t)b * 256 + co) * 4096 + oh * 64;
      size_t tbase = ((size_t)(b * 4 + (co >> 6)) * 4096 + oh * 64);
#pragma unroll
      for (int qd = 0; qd < 4; ++qd) {
        int J = pf * 16 + lq * 4 + qd;
        int ow = 2 * J + s;
        float val = acc[pf][cf][qd] + bv;
        cout[cbase + ow] = val;
        coutT[(tbase + ow) * 64 + (co & 63)] = val;
      }
    }
}

// ---------------- 8. y = coarse_out + region ----------------
__global__ __launch_bounds__(256) void k_ybuild(const float* __restrict__ cout,
                                                float* __restrict__ y) {
  size_t e = (size_t)blockIdx.x * 256 + threadIdx.x;
  int flat = (int)(e & 4095);
  size_t bc = e >> 12;
  int p = flat >> 2, ab = flat & 3;
  int a = ab >> 1, bi = ab & 1;
  int src = ((p >> 5) * 2 + a) * 64 + (p & 31) * 2 + bi;
  const float* cb = cout + bc * 4096;
  y[e] = cb[flat] + cb[src];
}

// ---------------- 9. scatter-add attended tokens ----------------
__global__ __launch_bounds__(256) void k_scatter(const float* __restrict__ out2,
    const int* __restrict__ idx, float* __restrict__ y) {
  int e = blockIdx.x * 256 + threadIdx.x;
  int d = e & 63;
  int r = e >> 6;
  int ab = r & 3;
  int r2 = r >> 2;
  int kk = r2 & 255;
  int bn = r2 >> 8;
  int b = bn >> 2, n = bn & 3;
  int p = idx[bn * 256 + kk] & 1023;
  int flat = p * 4 + ab;
  int t = kk * 4 + ab;
  y[((size_t)(b * 256 + n * 64 + d)) * 4096 + flat] +=
      out2[((size_t)bn * 1024 + t) * 64 + d];
}

// ---------------- 10. depthwise 3x3 + BN + relu6 ----------------
__global__ __launch_bounds__(256) void k_dw(const float* __restrict__ y,
    const float* __restrict__ w, const float* __restrict__ g, const float* __restrict__ bb,
    const float* __restrict__ mm, const float* __restrict__ vv, float* __restrict__ t1) {
  size_t e = (size_t)blockIdx.x * 256 + threadIdx.x;
  int pix = (int)(e & 4095);
  int c = (int)((e >> 12) & 255);
  int oh = pix >> 6, ow = pix & 63;
  const float* yb = y + (e - pix);
  float acc = 0.f;
#pragma unroll
  for (int kh = 0; kh < 3; ++kh) {
    int ih = oh - 1 + kh;
    if ((unsigned)ih >= 64u) continue;
#pragma unroll
    for (int kw = 0; kw < 3; ++kw) {
      int iw = ow - 1 + kw;
      if ((unsigned)iw >= 64u) continue;
      acc = fmaf(yb[ih * 64 + iw], w[c * 9 + kh * 3 + kw], acc);
    }
  }
  float s = g[c] * rsqrtf(vv[c] + 1e-5f);
  float val = acc * s + (bb[c] - mm[c] * s);
  t1[e] = fminf(fmaxf(val, 0.f), 6.f);
}

// ---------------- 11. pointwise v2: 4 co per block, 16 FMA per 16B load --------
__global__ __launch_bounds__(256) void k_pw2(const float* __restrict__ t1,
    const float* __restrict__ w, const float* __restrict__ g, const float* __restrict__ bb,
    const float* __restrict__ mm, const float* __restrict__ vv, float* __restrict__ out) {
  int blk = blockIdx.x;              // (b*64 + cog)*4 + tile
  int tile = blk & 3;
  int cog = (blk >> 2) & 63;
  int b = blk >> 8;
  int co0 = cog * 4;
  int t = threadIdx.x;
  __shared__ float wl[256][4];
  for (int idx = t; idx < 1024; idx += 256) {
    int cof = idx >> 8;
    int ci = idx & 255;
    wl[ci][cof] = w[(co0 + cof) * 256 + ci];
  }
  __syncthreads();
  int px0 = tile * 1024 + t * 4;
  const float* tb = t1 + (size_t)b * 256 * 4096 + px0;
  float acc[4][4];
#pragma unroll
  for (int a = 0; a < 4; ++a)
#pragma unroll
    for (int jj = 0; jj < 4; ++jj) acc[a][jj] = 0.f;
  for (int ci = 0; ci < 256; ++ci) {
    float4 tv = *(const float4*)(tb + (size_t)ci * 4096);
    float4 wv = *(const float4*)&wl[ci][0];
    acc[0][0] = fmaf(tv.x, wv.x, acc[0][0]); acc[0][1] = fmaf(tv.y, wv.x, acc[0][1]);
    acc[0][2] = fmaf(tv.z, wv.x, acc[0][2]); acc[0][3] = fmaf(tv.w, wv.x, acc[0][3]);
    acc[1][0] = fmaf(tv.x, wv.y, acc[1][0]); acc[1][1] = fmaf(tv.y, wv.y, acc[1][1]);
    acc[1][2] = fmaf(tv.z, wv.y, acc[1][2]); acc[1][3] = fmaf(tv.w, wv.y, acc[1][3]);
    acc[2][0] = fmaf(tv.x, wv.z, acc[2][0]); acc[2][1] = fmaf(tv.y, wv.z, acc[2][1]);
    acc[2][2] = fmaf(tv.z, wv.z, acc[2][2]); acc[2][3] = fmaf(tv.w, wv.z, acc[2][3]);
    acc[3][0] = fmaf(tv.x, wv.w, acc[3][0]); acc[3][1] = fmaf(tv.y, wv.w, acc[3][1]);
    acc[3][2] = fmaf(tv.z, wv.w, acc[3][2]); acc[3][3] = fmaf(tv.w, wv.w, acc[3][3]);
  }
#pragma unroll
  for (int a = 0; a < 4; ++a) {
    int co = co0 + a;
    float s = g[co] * rsqrtf(vv[co] + 1e-5f);
    float bias = bb[co] - mm[co] * s;
    float4 o4;
    o4.x = fminf(fmaxf(acc[a][0] * s + bias, 0.f), 6.f);
    o4.y = fminf(fmaxf(acc[a][1] * s + bias, 0.f), 6.f);
    o4.z = fminf(fmaxf(acc[a][2] * s + bias, 0.f), 6.f);
    o4.w = fminf(fmaxf(acc[a][3] * s + bias, 0.f), 6.f);
    *(float4*)(out + ((size_t)(b * 256 + co)) * 4096 + px0) = o4;
  }
}

// ---------------- launcher ----------------
extern "C" void kernel_launch(void* const* d_in, const int* in_sizes, int n_in,
                              void* d_out, int out_size, void* d_ws, size_t ws_size,
                              hipStream_t stream) {
  if (ws_size < WS_FLOATS * sizeof(float)) return;

  const float* x      = (const float*)d_in[0];
  const float* down_w = (const float*)d_in[1];
  const float* down_b = (const float*)d_in[2];
  const float* up_w   = (const float*)d_in[3];
  const float* up_b   = (const float*)d_in[4];
  const float* cqkv_w = (const float*)d_in[5];
  const float* cqkv_b = (const float*)d_in[6];
  const float* tqkv_w = (const float*)d_in[7];
  const float* tqkv_b = (const float*)d_in[8];
  const float* dww    = (const float*)d_in[9];
  const float* bn1g   = (const float*)d_in[10];
  const float* bn1b   = (const float*)d_in[11];
  const float* bn1m   = (const float*)d_in[12];
  const float* bn1v   = (const float*)d_in[13];
  const float* pww    = (const float*)d_in[14];
  const float* bn2g   = (const float*)d_in[15];
  const float* bn2b   = (const float*)d_in[16];
  const float* bn2m   = (const float*)d_in[17];
  const float* bn2v   = (const float*)d_in[18];

  float* ws    = (float*)d_ws;
  float* q     = ws + OFF_Q;
  float* k     = ws + OFF_K;
  float* v     = ws + OFF_V;
  float* att   = ws + OFF_ATT;
  float* spart = ws + OFF_SPART;
  float* score = ws + OFF_SCORE;
  int*   idx   = (int*)(ws + OFF_IDX);
  float* cout  = ws + OFF_COUT;
  float* y     = ws + OFF_Y;
  float* t1    = ws + OFF_T1;
  float* attT  = ws + OFF_SPART + 2097152;   // upper half of spart region
  unsigned short* whi  = (unsigned short*)(ws + OFF_XD);            // up-w hi
  unsigned short* wlo  = (unsigned short*)(ws + OFF_XD + 524288);   // up-w lo
  unsigned short* dwhi = (unsigned short*)(ws + OFF_SPART);             // down-w hi (dead after conv_down)
  unsigned short* dwlo = (unsigned short*)(ws + OFF_SPART + 524288);    // down-w lo
  unsigned short* xbh  = (unsigned short*)(ws + OFF_Q);   // x hi [b][ih][iw][ci] (Q..K, dead after conv_down)
  unsigned short* xbl  = (unsigned short*)(ws + OFF_V);   // x lo (V..ATT, dead after conv_down)
  float* coutT = ws + OFF_T1;                // t1 region dead until k_dw
  float* dpart = ws + OFF_Y;                 // 4 x 2M ci-split partials (dead until k_ybuild)

  k_x2bf<<<1024, 256, 0, stream>>>(x, xbh, xbl);
  k_wt_dnb<<<4096, 256, 0, stream>>>(down_w, dwhi, dwlo);
  k_conv_down_mfma<<<4096, 256, 0, stream>>>(xbh, xbl, dwhi, dwlo, down_b, dpart);
  k_qkv_coarse<<<32768, 192, 0, stream>>>(dpart, cqkv_w, cqkv_b, q, k, v);
  k_wt_upb<<<4096, 256, 0, stream>>>(up_w, whi, wlo);
  k_attn_score<<<512, 256, 0, stream>>>(q, k, v, att, spart, attT);
  k_score_reduce<<<128, 256, 0, stream>>>(spart, score);
  k_idx_init<<<32, 256, 0, stream>>>(idx);
  k_topk<<<32, 1024, 0, stream>>>(score, idx);
  k_conv_up_mfma<<<2048, 256, 0, stream>>>(attT, whi, wlo, up_b, cout, coutT);
  k_qkv_topk<<<32768, 192, 0, stream>>>(coutT, idx, tqkv_w, tqkv_b, q, k, v);
  k_attn_online<<<512, 256, 0, stream>>>(q, k, v, att);
  k_ybuild<<<32768, 256, 0, stream>>>(cout, y);
  k_scatter<<<8192, 256, 0, stream>>>(att, idx, y);
  k_dw<<<32768, 256, 0, stream>>>(y, dww, bn1g, bn1b, bn1m, bn1v, t1);
  k_pw2<<<2048, 256, 0, stream>>>(t1, pww, bn2g, bn2b, bn2m, bn2v, (float*)d_out);
}

// Round 6
// 1362.099 us; speedup vs baseline: 1.2484x; 1.0411x over previous
//
#include <hip/hip_runtime.h>

typedef short short8 __attribute__((ext_vector_type(8)));
typedef float f32x4 __attribute__((ext_vector_type(4)));

__device__ inline unsigned short f32_to_bf16_rne(float f) {
  unsigned int u = __float_as_uint(f);
  unsigned int r = (u + 0x7fffu + ((u >> 16) & 1u)) >> 16;
  return (unsigned short)r;
}
__device__ inline float bf16_to_f32(unsigned short h) {
  return __uint_as_float(((unsigned int)h) << 16);
}

// ---------------- workspace layout (float offsets) ----------------
// bf16 qkv: qh/ql -> Q region, kh/kl -> K region, vth/vtl (V^T [d][j]) -> V region
// att (O, fp32) -> ATT.  spart -> SPART (+ attT at +2M)  score / idx / cout / y / t1
// aliases: whi/wlo (up-w) -> XD; dwhi/dwlo (down-w) -> SPART (dead before spart use)
//          xbh -> Q..K, xbl -> V..ATT (dead after conv_down)
//          coutT -> t1 region; dpart -> y region
constexpr size_t OFF_XD    = 0;
constexpr size_t OFF_Q     = 2097152;
constexpr size_t OFF_K     = 4194304;
constexpr size_t OFF_V     = 6291456;
constexpr size_t OFF_ATT   = 8388608;
constexpr size_t OFF_SPART = 10485760;
constexpr size_t OFF_SCORE = 14680064;
constexpr size_t OFF_IDX   = 14712832;
constexpr size_t OFF_COUT  = 14721024;
constexpr size_t OFF_Y     = 23109632;
constexpr size_t OFF_T1    = 31498240;
constexpr size_t WS_FLOATS = 39886848;

// ---------------- 0a. x NCHW -> NHWC split-bf16 (xbh/xbl [b][ih][iw][ci]) ------
__global__ __launch_bounds__(256) void k_x2bf(const float* __restrict__ x,
    unsigned short* __restrict__ xbh, unsigned short* __restrict__ xbl) {
  int bid = blockIdx.x;              // b*128 + ih*2 + iwh
  int b = bid >> 7;
  int ih = (bid >> 1) & 63;
  int iwh = bid & 1;
  int t = threadIdx.x;
  __shared__ float ts[256][33];
  for (int it = 0; it < 32; ++it) {
    int idx = it * 256 + t;
    int ci = idx >> 5;
    int iwl = idx & 31;
    ts[ci][iwl] = x[(((size_t)(b * 256 + ci) * 64 + ih) * 64) + iwh * 32 + iwl];
  }
  __syncthreads();
  int iwl = t >> 3;
  int cb = (t & 7) * 32;
  size_t base = (((size_t)(b * 64 + ih) * 64) + iwh * 32 + iwl) * 256 + cb;
#pragma unroll
  for (int j = 0; j < 32; j += 2) {
    float v0 = ts[cb + j][iwl];
    float v1 = ts[cb + j + 1][iwl];
    unsigned short h0 = f32_to_bf16_rne(v0);
    unsigned short h1 = f32_to_bf16_rne(v1);
    unsigned short l0 = f32_to_bf16_rne(v0 - bf16_to_f32(h0));
    unsigned short l1 = f32_to_bf16_rne(v1 - bf16_to_f32(h1));
    *(ushort2*)&xbh[base + j] = make_ushort2(h0, h1);
    *(ushort2*)&xbl[base + j] = make_ushort2(l0, l1);
  }
}

// ---------------- 0b. down_w -> split-bf16 dwhi/dwlo [kk][co][ci] --------------
__global__ __launch_bounds__(256) void k_wt_dnb(const float* __restrict__ w,
    unsigned short* __restrict__ dwhi, unsigned short* __restrict__ dwlo) {
  int idx = blockIdx.x * 256 + threadIdx.x;   // 1,048,576 = (kk*256+co)*256+ci
  int ci = idx & 255;
  int co = (idx >> 8) & 255;
  int kk = idx >> 16;
  float v = w[((size_t)(co * 256 + ci)) * 16 + kk];
  unsigned short h = f32_to_bf16_rne(v);
  unsigned short l = f32_to_bf16_rne(v - bf16_to_f32(h));
  dwhi[idx] = h;
  dwlo[idx] = l;
}

// ---------------- 0c. up_w -> split-bf16 whi/wlo [cls][tap][co][ci] ----------
__global__ __launch_bounds__(256) void k_wt_upb(const float* __restrict__ w,
    unsigned short* __restrict__ whi, unsigned short* __restrict__ wlo) {
  int idx = blockIdx.x * 256 + threadIdx.x;   // 1,048,576
  int ci = idx & 255;
  int co = (idx >> 8) & 255;
  int tp = idx >> 16;                         // 0..15
  int cls = tp >> 2, tap = tp & 3;
  int r = cls >> 1, s = cls & 1;
  int a_ = tap >> 1, b_ = tap & 1;
  int kh = a_ ? (r ? 2 : 3) : (r ? 0 : 1);
  int kw = b_ ? (s ? 2 : 3) : (s ? 0 : 1);
  float v = w[((size_t)(ci * 256 + co)) * 16 + kh * 4 + kw];
  unsigned short h = f32_to_bf16_rne(v);
  unsigned short l = f32_to_bf16_rne(v - bf16_to_f32(h));
  whi[idx] = h;
  wlo[idx] = l;
}

// ---------------- 1. down conv: split-bf16 MFMA implicit GEMM ------------------
__global__ __launch_bounds__(256) void k_conv_down_mfma(
    const unsigned short* __restrict__ xbh, const unsigned short* __restrict__ xbl,
    const unsigned short* __restrict__ dwhi, const unsigned short* __restrict__ dwlo,
    const float* __restrict__ bias, float* __restrict__ part) {
  int blk = blockIdx.x;              // ((ks*8 + b)*4 + ct)*32 + pt
  int pt = blk & 31;
  int ct = (blk >> 5) & 3;
  int b = (blk >> 7) & 7;
  int ks = blk >> 10;
  int oh2 = pt >> 1;                 // 0..15 (pair of oh rows)
  int owh = pt & 1;                  // ow half (16)
  int tid = threadIdx.x;
  int w = tid >> 6;                  // wave 0..3 -> co quarter
  int lane = tid & 63;
  int lq = lane >> 4;
  int lr = lane & 15;
  int co = ct * 64 + w * 16 + lr;

  __shared__ __align__(16) unsigned short AH[6][34][40];
  __shared__ __align__(16) unsigned short AL[6][34][40];

  f32x4 acc[2];
  acc[0] = (f32x4){0.f, 0.f, 0.f, 0.f};
  acc[1] = (f32x4){0.f, 0.f, 0.f, 0.f};

  int ih0 = 4 * oh2 - 1;             // tile row 0
  int iw0 = owh * 32 - 1;            // tile col 0
  const short8 zero8 = {0, 0, 0, 0, 0, 0, 0, 0};

  for (int ch = 0; ch < 2; ++ch) {
    int ci0 = ks * 64 + ch * 32;
    __syncthreads();
    for (int idx = tid; idx < 6 * 34 * 4; idx += 256) {
      int q = idx & 3;
      int cell = idx >> 2;
      int row = cell / 34;
      int col = cell - row * 34;
      int ih = ih0 + row;
      int iw = iw0 + col;
      short8 h = zero8, l = zero8;
      if ((unsigned)ih < 64u && (unsigned)iw < 64u) {
        size_t gg = (((size_t)(b * 64 + ih) * 64) + iw) * 256 + ci0 + q * 8;
        h = *(const short8*)&xbh[gg];
        l = *(const short8*)&xbl[gg];
      }
      *(short8*)&AH[row][col][q * 8] = h;
      *(short8*)&AL[row][col][q * 8] = l;
    }
    __syncthreads();
#pragma unroll
    for (int tap = 0; tap < 16; ++tap) {
      int kh = tap >> 2, kw = tap & 3;
      size_t woff = ((size_t)tap * 256 + co) * 256 + ci0 + 8 * lq;
      short8 bh = *(const short8*)&dwhi[woff];
      short8 bl = *(const short8*)&dwlo[woff];
#pragma unroll
      for (int pf = 0; pf < 2; ++pf) {
        short8 ah = *(const short8*)&AH[2 * pf + kh][2 * lr + kw][8 * lq];
        short8 al = *(const short8*)&AL[2 * pf + kh][2 * lr + kw][8 * lq];
        acc[pf] = __builtin_amdgcn_mfma_f32_16x16x32_bf16(ah, bh, acc[pf], 0, 0, 0);
        acc[pf] = __builtin_amdgcn_mfma_f32_16x16x32_bf16(al, bh, acc[pf], 0, 0, 0);
        acc[pf] = __builtin_amdgcn_mfma_f32_16x16x32_bf16(ah, bl, acc[pf], 0, 0, 0);
      }
    }
  }

  float bv = (ks == 0) ? bias[co] : 0.f;
  int bn = b * 4 + ct;
  int d = w * 16 + lr;
  float* pb = part + (size_t)ks * 2097152;
#pragma unroll
  for (int pf = 0; pf < 2; ++pf) {
    int oh = 2 * oh2 + pf;
#pragma unroll
    for (int reg = 0; reg < 4; ++reg) {
      int ow = owh * 16 + lq * 4 + reg;
      int pix = oh * 32 + ow;
      pb[((size_t)bn * 1024 + pix) * 64 + d] = acc[pf][reg] + bv;
    }
  }
}

// ---------------- 2. QKV gemm coarse -> bf16 hi/lo q,k + V^T -------------------
__global__ __launch_bounds__(192) void k_qkv_coarse(const float* __restrict__ part,
    const float* __restrict__ W, const float* __restrict__ bias,
    unsigned short* __restrict__ qh, unsigned short* __restrict__ ql,
    unsigned short* __restrict__ kh, unsigned short* __restrict__ kl,
    unsigned short* __restrict__ vth, unsigned short* __restrict__ vtl) {
  int row = blockIdx.x;              // bn*1024 + i
  int bn = row >> 10, i = row & 1023;
  __shared__ float t[64];
  if (threadIdx.x < 64) {
    size_t o = (size_t)row * 64 + threadIdx.x;
    t[threadIdx.x] = ((part[o] + part[o + 2097152]) +
                      part[o + 2 * 2097152]) + part[o + 3 * 2097152];
  }
  __syncthreads();
  int e = threadIdx.x;               // 0..191
  float acc = bias[e];
  const float* wr = W + e * 64;
#pragma unroll
  for (int d = 0; d < 64; ++d) acc = fmaf(t[d], wr[d], acc);
  unsigned short h = f32_to_bf16_rne(acc);
  unsigned short lo = f32_to_bf16_rne(acc - bf16_to_f32(h));
  if (e < 64) {
    qh[(size_t)row * 64 + e] = h;
    ql[(size_t)row * 64 + e] = lo;
  } else if (e < 128) {
    kh[(size_t)row * 64 + e - 64] = h;
    kl[(size_t)row * 64 + e - 64] = lo;
  } else {
    size_t o2 = ((size_t)bn * 64 + (e - 128)) * 1024 + i;
    vth[o2] = h;
    vtl[o2] = lo;
  }
}

// ---------------- 3. QKV gemm topk -> bf16 hi/lo q,k + V^T ---------------------
__global__ __launch_bounds__(192) void k_qkv_topk(const float* __restrict__ coutT,
    const int* __restrict__ idx, const float* __restrict__ W, const float* __restrict__ bias,
    unsigned short* __restrict__ qh, unsigned short* __restrict__ ql,
    unsigned short* __restrict__ kh, unsigned short* __restrict__ kl,
    unsigned short* __restrict__ vth, unsigned short* __restrict__ vtl) {
  int row = blockIdx.x;              // bn*1024 + tk
  int bn = row >> 10, tk = row & 1023;
  int kk = tk >> 2, ab = tk & 3;
  int a = ab >> 1, bi = ab & 1;
  __shared__ float tl[64];
  __shared__ int ps;
  if (threadIdx.x == 0) ps = idx[bn * 256 + kk] & 1023;
  __syncthreads();
  int p = ps;
  int sh = (p >> 5) * 2 + a, sw = (p & 31) * 2 + bi;
  if (threadIdx.x < 64)
    tl[threadIdx.x] = coutT[((size_t)bn * 4096 + sh * 64 + sw) * 64 + threadIdx.x];
  __syncthreads();
  int e = threadIdx.x;
  float acc = bias[e];
  const float* wr = W + e * 64;
#pragma unroll
  for (int d = 0; d < 64; ++d) acc = fmaf(tl[d], wr[d], acc);
  unsigned short h = f32_to_bf16_rne(acc);
  unsigned short lo = f32_to_bf16_rne(acc - bf16_to_f32(h));
  if (e < 64) {
    qh[(size_t)row * 64 + e] = h;
    ql[(size_t)row * 64 + e] = lo;
  } else if (e < 128) {
    kh[(size_t)row * 64 + e - 64] = h;
    kl[(size_t)row * 64 + e - 64] = lo;
  } else {
    size_t o2 = ((size_t)bn * 64 + (e - 128)) * 1024 + tk;
    vth[o2] = h;
    vtl[o2] = lo;
  }
}

// ---------------- 4a. attention+score, split-bf16 MFMA (2-pass) ----------------
// wave w owns i-rows it*64+w*16..+15. S = K·Q^T (A=K,B=Q); PV as O^T = V^T·P^T.
// P round-trips through a per-wave LDS slab (same-wave RAW: no barrier needed).
__global__ __launch_bounds__(256) void k_attn_score_mfma(
    const unsigned short* __restrict__ qh, const unsigned short* __restrict__ ql,
    const unsigned short* __restrict__ kh, const unsigned short* __restrict__ kl,
    const unsigned short* __restrict__ vth, const unsigned short* __restrict__ vtl,
    float* __restrict__ spart, float* __restrict__ attT) {
  int bn = blockIdx.x >> 4;
  int it = blockIdx.x & 15;
  int tid = threadIdx.x;
  int w = tid >> 6;
  int lane = tid & 63;
  int g = lane >> 4;
  int c = lane & 15;
  size_t qb = (size_t)bn << 16;      // *65536 (u16 elements)

  __shared__ __align__(16) unsigned short PH[64][72];
  __shared__ __align__(16) unsigned short PL[64][72];
  __shared__ float sacc[1024];
  for (int i2 = tid; i2 < 1024; i2 += 256) sacc[i2] = 0.f;
  __syncthreads();

  // K A-frags for this wave's 16 rows (A row = lane&15)
  int irow = it * 64 + w * 16 + c;
  short8 kfh[2], kfl[2];
#pragma unroll
  for (int ch = 0; ch < 2; ++ch) {
    kfh[ch] = *(const short8*)&kh[qb + (size_t)irow * 64 + ch * 32 + g * 8];
    kfl[ch] = *(const short8*)&kl[qb + (size_t)irow * 64 + ch * 32 + g * 8];
  }

  float m[4], lsum[4];
#pragma unroll
  for (int r = 0; r < 4; ++r) { m[r] = -3.0e38f; lsum[r] = 0.f; }

  // ---- pass 1: row max / denom ----
  for (int jt = 0; jt < 16; ++jt) {
    f32x4 s[4];
#pragma unroll
    for (int su = 0; su < 4; ++su) s[su] = (f32x4){0.f, 0.f, 0.f, 0.f};
#pragma unroll
    for (int ch = 0; ch < 2; ++ch)
#pragma unroll
      for (int su = 0; su < 4; ++su) {
        size_t qo = qb + (size_t)(jt * 64 + su * 16 + c) * 64 + ch * 32 + g * 8;
        short8 qfh = *(const short8*)&qh[qo];
        short8 qfl = *(const short8*)&ql[qo];
        s[su] = __builtin_amdgcn_mfma_f32_16x16x32_bf16(kfh[ch], qfh, s[su], 0, 0, 0);
        s[su] = __builtin_amdgcn_mfma_f32_16x16x32_bf16(kfl[ch], qfh, s[su], 0, 0, 0);
        s[su] = __builtin_amdgcn_mfma_f32_16x16x32_bf16(kfh[ch], qfl, s[su], 0, 0, 0);
      }
#pragma unroll
    for (int r = 0; r < 4; ++r) {
      float tm = fmaxf(fmaxf(s[0][r], s[1][r]), fmaxf(s[2][r], s[3][r]));
#pragma unroll
      for (int off = 1; off <= 8; off <<= 1) tm = fmaxf(tm, __shfl_xor(tm, off, 64));
      float mn = fmaxf(m[r], tm);
      float ts = ((expf(s[0][r] - mn) + expf(s[1][r] - mn)) +
                  expf(s[2][r] - mn)) + expf(s[3][r] - mn);
#pragma unroll
      for (int off = 1; off <= 8; off <<= 1) ts += __shfl_xor(ts, off, 64);
      lsum[r] = lsum[r] * expf(m[r] - mn) + ts;
      m[r] = mn;
    }
  }
  float inv[4];
#pragma unroll
  for (int r = 0; r < 4; ++r) inv[r] = 1.f / lsum[r];

  f32x4 oacc[4];
#pragma unroll
  for (int d = 0; d < 4; ++d) oacc[d] = (f32x4){0.f, 0.f, 0.f, 0.f};

  // ---- pass 2: P, scores, PV ----
  for (int jt = 0; jt < 16; ++jt) {
    f32x4 s[4];
#pragma unroll
    for (int su = 0; su < 4; ++su) s[su] = (f32x4){0.f, 0.f, 0.f, 0.f};
#pragma unroll
    for (int ch = 0; ch < 2; ++ch)
#pragma unroll
      for (int su = 0; su < 4; ++su) {
        size_t qo = qb + (size_t)(jt * 64 + su * 16 + c) * 64 + ch * 32 + g * 8;
        short8 qfh = *(const short8*)&qh[qo];
        short8 qfl = *(const short8*)&ql[qo];
        s[su] = __builtin_amdgcn_mfma_f32_16x16x32_bf16(kfh[ch], qfh, s[su], 0, 0, 0);
        s[su] = __builtin_amdgcn_mfma_f32_16x16x32_bf16(kfl[ch], qfh, s[su], 0, 0, 0);
        s[su] = __builtin_amdgcn_mfma_f32_16x16x32_bf16(kfh[ch], qfl, s[su], 0, 0, 0);
      }
#pragma unroll
    for (int su = 0; su < 4; ++su) {
      float p0 = expf(s[su][0] - m[0]) * inv[0];
      float p1 = expf(s[su][1] - m[1]) * inv[1];
      float p2 = expf(s[su][2] - m[2]) * inv[2];
      float p3 = expf(s[su][3] - m[3]) * inv[3];
      float cs = ((p0 + p1) + p2) + p3;
      cs += __shfl_xor(cs, 16, 64);
      cs += __shfl_xor(cs, 32, 64);
      if (g == 0) atomicAdd(&sacc[jt * 64 + su * 16 + c], cs);
      unsigned short h0 = f32_to_bf16_rne(p0);
      unsigned short h1 = f32_to_bf16_rne(p1);
      unsigned short h2 = f32_to_bf16_rne(p2);
      unsigned short h3 = f32_to_bf16_rne(p3);
      PH[w * 16 + g * 4 + 0][su * 16 + c] = h0;
      PH[w * 16 + g * 4 + 1][su * 16 + c] = h1;
      PH[w * 16 + g * 4 + 2][su * 16 + c] = h2;
      PH[w * 16 + g * 4 + 3][su * 16 + c] = h3;
      PL[w * 16 + g * 4 + 0][su * 16 + c] = f32_to_bf16_rne(p0 - bf16_to_f32(h0));
      PL[w * 16 + g * 4 + 1][su * 16 + c] = f32_to_bf16_rne(p1 - bf16_to_f32(h1));
      PL[w * 16 + g * 4 + 2][su * 16 + c] = f32_to_bf16_rne(p2 - bf16_to_f32(h2));
      PL[w * 16 + g * 4 + 3][su * 16 + c] = f32_to_bf16_rne(p3 - bf16_to_f32(h3));
    }
#pragma unroll
    for (int ch = 0; ch < 2; ++ch) {
      short8 pfh = *(const short8*)&PH[w * 16 + c][ch * 32 + g * 8];
      short8 pfl = *(const short8*)&PL[w * 16 + c][ch * 32 + g * 8];
#pragma unroll
      for (int d = 0; d < 4; ++d) {
        size_t vo = ((size_t)(bn * 64 + d * 16 + c)) * 1024 + jt * 64 + ch * 32 + g * 8;
        short8 vfh = *(const short8*)&vth[vo];
        short8 vfl = *(const short8*)&vtl[vo];
        oacc[d] = __builtin_amdgcn_mfma_f32_16x16x32_bf16(vfh, pfh, oacc[d], 0, 0, 0);
        oacc[d] = __builtin_amdgcn_mfma_f32_16x16x32_bf16(vfl, pfh, oacc[d], 0, 0, 0);
        oacc[d] = __builtin_amdgcn_mfma_f32_16x16x32_bf16(vfh, pfl, oacc[d], 0, 0, 0);
      }
    }
  }
  // O^T D-layout: lane holds O^T[d = d*16 + g*4 + reg][i = it*64 + w*16 + c]
#pragma unroll
  for (int d = 0; d < 4; ++d)
#pragma unroll
    for (int r = 0; r < 4; ++r)
      attT[((size_t)bn * 64 + d * 16 + g * 4 + r) * 1024 + it * 64 + w * 16 + c] =
          oacc[d][r];
  __syncthreads();
  for (int i2 = tid; i2 < 1024; i2 += 256)
    spart[((size_t)bn * 16 + it) * 1024 + i2] = sacc[i2];
}

// ---------------- 4b. topk attention, split-bf16 MFMA (1-pass online) ----------
__global__ __launch_bounds__(256) void k_attn_online_mfma(
    const unsigned short* __restrict__ qh, const unsigned short* __restrict__ ql,
    const unsigned short* __restrict__ kh, const unsigned short* __restrict__ kl,
    const unsigned short* __restrict__ vth, const unsigned short* __restrict__ vtl,
    float* __restrict__ O) {
  int bn = blockIdx.x >> 4;
  int it = blockIdx.x & 15;
  int tid = threadIdx.x;
  int w = tid >> 6;
  int lane = tid & 63;
  int g = lane >> 4;
  int c = lane & 15;
  size_t qb = (size_t)bn << 16;

  __shared__ __align__(16) unsigned short PH[64][72];
  __shared__ __align__(16) unsigned short PL[64][72];

  int irow = it * 64 + w * 16 + c;
  short8 kfh[2], kfl[2];
#pragma unroll
  for (int ch = 0; ch < 2; ++ch) {
    kfh[ch] = *(const short8*)&kh[qb + (size_t)irow * 64 + ch * 32 + g * 8];
    kfl[ch] = *(const short8*)&kl[qb + (size_t)irow * 64 + ch * 32 + g * 8];
  }

  float m[4], lsum[4];
  f32x4 oacc[4];
#pragma unroll
  for (int r = 0; r < 4; ++r) { m[r] = -3.0e38f; lsum[r] = 0.f; }
#pragma unroll
  for (int d = 0; d < 4; ++d) oacc[d] = (f32x4){0.f, 0.f, 0.f, 0.f};

  for (int jt = 0; jt < 16; ++jt) {
    f32x4 s[4];
#pragma unroll
    for (int su = 0; su < 4; ++su) s[su] = (f32x4){0.f, 0.f, 0.f, 0.f};
#pragma unroll
    for (int ch = 0; ch < 2; ++ch)
#pragma unroll
      for (int su = 0; su < 4; ++su) {
        size_t qo = qb + (size_t)(jt * 64 + su * 16 + c) * 64 + ch * 32 + g * 8;
        short8 qfh = *(const short8*)&qh[qo];
        short8 qfl = *(const short8*)&ql[qo];
        s[su] = __builtin_amdgcn_mfma_f32_16x16x32_bf16(kfh[ch], qfh, s[su], 0, 0, 0);
        s[su] = __builtin_amdgcn_mfma_f32_16x16x32_bf16(kfl[ch], qfh, s[su], 0, 0, 0);
        s[su] = __builtin_amdgcn_mfma_f32_16x16x32_bf16(kfh[ch], qfl, s[su], 0, 0, 0);
      }
    float sc[4];
#pragma unroll
    for (int r = 0; r < 4; ++r) {
      float tm = fmaxf(fmaxf(s[0][r], s[1][r]), fmaxf(s[2][r], s[3][r]));
#pragma unroll
      for (int off = 1; off <= 8; off <<= 1) tm = fmaxf(tm, __shfl_xor(tm, off, 64));
      float mn = fmaxf(m[r], tm);
      sc[r] = expf(m[r] - mn);
      float p0 = expf(s[0][r] - mn);
      float p1 = expf(s[1][r] - mn);
      float p2 = expf(s[2][r] - mn);
      float p3 = expf(s[3][r] - mn);
      s[0][r] = p0; s[1][r] = p1; s[2][r] = p2; s[3][r] = p3;
      float ts = ((p0 + p1) + p2) + p3;
#pragma unroll
      for (int off = 1; off <= 8; off <<= 1) ts += __shfl_xor(ts, off, 64);
      lsum[r] = lsum[r] * sc[r] + ts;
      m[r] = mn;
    }
#pragma unroll
    for (int su = 0; su < 4; ++su) {
      unsigned short h0 = f32_to_bf16_rne(s[su][0]);
      unsigned short h1 = f32_to_bf16_rne(s[su][1]);
      unsigned short h2 = f32_to_bf16_rne(s[su][2]);
      unsigned short h3 = f32_to_bf16_rne(s[su][3]);
      PH[w * 16 + g * 4 + 0][su * 16 + c] = h0;
      PH[w * 16 + g * 4 + 1][su * 16 + c] = h1;
      PH[w * 16 + g * 4 + 2][su * 16 + c] = h2;
      PH[w * 16 + g * 4 + 3][su * 16 + c] = h3;
      PL[w * 16 + g * 4 + 0][su * 16 + c] = f32_to_bf16_rne(s[su][0] - bf16_to_f32(h0));
      PL[w * 16 + g * 4 + 1][su * 16 + c] = f32_to_bf16_rne(s[su][1] - bf16_to_f32(h1));
      PL[w * 16 + g * 4 + 2][su * 16 + c] = f32_to_bf16_rne(s[su][2] - bf16_to_f32(h2));
      PL[w * 16 + g * 4 + 3][su * 16 + c] = f32_to_bf16_rne(s[su][3] - bf16_to_f32(h3));
    }
    // rescale oacc by sc for col i=c (branchless select + shfl, rule #20 safe)
    float s01 = (c & 1) ? sc[1] : sc[0];
    float s23 = (c & 1) ? sc[3] : sc[2];
    float tmp = (c & 2) ? s23 : s01;
    float scc = __shfl(tmp, ((c >> 2) << 4) | c, 64);
#pragma unroll
    for (int d = 0; d < 4; ++d) oacc[d] *= scc;
#pragma unroll
    for (int ch = 0; ch < 2; ++ch) {
      short8 pfh = *(const short8*)&PH[w * 16 + c][ch * 32 + g * 8];
      short8 pfl = *(const short8*)&PL[w * 16 + c][ch * 32 + g * 8];
#pragma unroll
      for (int d = 0; d < 4; ++d) {
        size_t vo = ((size_t)(bn * 64 + d * 16 + c)) * 1024 + jt * 64 + ch * 32 + g * 8;
        short8 vfh = *(const short8*)&vth[vo];
        short8 vfl = *(const short8*)&vtl[vo];
        oacc[d] = __builtin_amdgcn_mfma_f32_16x16x32_bf16(vfh, pfh, oacc[d], 0, 0, 0);
        oacc[d] = __builtin_amdgcn_mfma_f32_16x16x32_bf16(vfl, pfh, oacc[d], 0, 0, 0);
        oacc[d] = __builtin_amdgcn_mfma_f32_16x16x32_bf16(vfh, pfl, oacc[d], 0, 0, 0);
      }
    }
  }
  float i01 = (c & 1) ? (1.f / lsum[1]) : (1.f / lsum[0]);
  float i23 = (c & 1) ? (1.f / lsum[3]) : (1.f / lsum[2]);
  float itmp = (c & 2) ? i23 : i01;
  float invc = __shfl(itmp, ((c >> 2) << 4) | c, 64);
  // O natural [i][d]: lane col i = it*64+w*16+c; rows d = d*16+g*4+reg (contig f32x4)
#pragma unroll
  for (int d = 0; d < 4; ++d) {
    f32x4 o4 = oacc[d] * invc;
    *(f32x4*)&O[((size_t)bn * 1024 + it * 64 + w * 16 + c) * 64 + d * 16 + g * 4] = o4;
  }
}

// ---------------- 5. deterministic score reduction (16 partials) ----------------
__global__ __launch_bounds__(256) void k_score_reduce(const float* __restrict__ part,
                                                      float* __restrict__ score) {
  int j = blockIdx.x * 256 + threadIdx.x;   // 0..32767
  int bn = j >> 10, jj = j & 1023;
  float s = 0.f;
  for (int g = 0; g < 16; ++g) s += part[((size_t)bn * 16 + g) * 1024 + jj];
  score[j] = s;
}

// ---------------- 5b. default-init idx ----------------
__global__ __launch_bounds__(256) void k_idx_init(int* __restrict__ idx) {
  int j = blockIdx.x * 256 + threadIdx.x;
  idx[j] = j & 255;
}

// ---------------- 6. top-K by rank ----------------
__global__ __launch_bounds__(1024) void k_topk(const float* __restrict__ score,
                                               int* __restrict__ idxout) {
  int bn = blockIdx.x;
  int t = threadIdx.x;
  __shared__ float s[1024];
  s[t] = score[bn * 1024 + t];
  __syncthreads();
  float my = s[t];
  int rank = 0;
  for (int j = 0; j < 1024; ++j) {
    float o = s[j];
    rank += (o > my) || (o == my && j < t);
  }
  if (rank < 256) idxout[bn * 256 + rank] = t;
}

// ---------------- 7. transposed conv: split-bf16 MFMA implicit GEMM -----------
__global__ __launch_bounds__(256) void k_conv_up_mfma(
    const float* __restrict__ attT, const unsigned short* __restrict__ whi,
    const unsigned short* __restrict__ wlo, const float* __restrict__ bias,
    float* __restrict__ cout, float* __restrict__ coutT) {
  int blk = blockIdx.x;              // ((b*4 + cls)*16 + pt)*4 + ct
  int ct = blk & 3;
  int pt = (blk >> 2) & 15;
  int cls = (blk >> 6) & 3;
  int b = blk >> 8;
  int r = cls >> 1, s = cls & 1;
  int Ib = pt * 2;
  int co0 = ct * 64;
  int tid = threadIdx.x;
  int w = tid >> 6;                  // wave 0..3
  int lane = tid & 63;
  int lq = lane >> 4;                // quarter 0..3
  int lr = lane & 15;
  int wr = w >> 1;                   // I-row within tile
  int wc = w & 1;                    // co half
  int co0w = co0 + wc * 32;

  __shared__ __align__(16) unsigned short AH[3][33][40];
  __shared__ __align__(16) unsigned short AL[3][33][40];

  f32x4 acc[2][2];
#pragma unroll
  for (int pf = 0; pf < 2; ++pf)
#pragma unroll
    for (int cf = 0; cf < 2; ++cf) acc[pf][cf] = (f32x4){0.f, 0.f, 0.f, 0.f};

  const float* ab = attT + (size_t)b * 4 * 65536;
  int ih_base = Ib + r - 1;
  int iw_base = s - 1;

  for (int ci0 = 0; ci0 < 256; ci0 += 32) {
    int n = ci0 >> 6, d0 = ci0 & 63;
    __syncthreads();
    for (int idx = tid; idx < 3168; idx += 256) {
      int ciL = idx / 99;            // 0..31
      int rem = idx - ciL * 99;
      int rho = rem / 33;
      int c = rem - rho * 33;
      int ih = ih_base + rho;
      int iw = iw_base + c;
      float v = 0.f;
      if ((unsigned)ih < 32u && (unsigned)iw < 32u)
        v = ab[((size_t)n * 64 + d0 + ciL) * 1024 + ih * 32 + iw];
      unsigned short h = f32_to_bf16_rne(v);
      unsigned short lo = f32_to_bf16_rne(v - bf16_to_f32(h));
      AH[rho][c][ciL] = h;
      AL[rho][c][ciL] = lo;
    }
    __syncthreads();
#pragma unroll
    for (int tap = 0; tap < 4; ++tap) {
      int a_ = tap >> 1, b_ = tap & 1;
      int rho = wr + 1 - a_;
      short8 ah[2], al[2];
#pragma unroll
      for (int pf = 0; pf < 2; ++pf) {
        int col = pf * 16 + lr + 1 - b_;
        ah[pf] = *(const short8*)&AH[rho][col][8 * lq];
        al[pf] = *(const short8*)&AL[rho][col][8 * lq];
      }
      size_t wb = (size_t)(cls * 4 + tap) * 65536;
      short8 bh[2], bl[2];
#pragma unroll
      for (int cf = 0; cf < 2; ++cf) {
        size_t off = wb + (size_t)(co0w + cf * 16 + lr) * 256 + ci0 + 8 * lq;
        bh[cf] = *(const short8*)&whi[off];
        bl[cf] = *(const short8*)&wlo[off];
      }
#pragma unroll
      for (int pf = 0; pf < 2; ++pf)
#pragma unroll
        for (int cf = 0; cf < 2; ++cf) {
          acc[pf][cf] = __builtin_amdgcn_mfma_f32_16x16x32_bf16(ah[pf], bh[cf], acc[pf][cf], 0, 0, 0);
          acc[pf][cf] = __builtin_amdgcn_mfma_f32_16x16x32_bf16(al[pf], bh[cf], acc[pf][cf], 0, 0, 0);
          acc[pf][cf] = __builtin_amdgcn_mfma_f32_16x16x32_bf16(ah[pf], bl[cf], acc[pf][cf], 0, 0, 0);
        }
    }
  }

  int I = Ib + wr;
  int oh = 2 * I + r;
#pragma unroll
  for (int pf = 0; pf < 2; ++pf)
#pragma unroll
    for (int cf = 0; cf < 2; ++cf) {
      int co = co0w + cf * 16 + lr;
      float bv = bias[co];
      size_t cbase = ((size_t)b * 256 + co) * 4096 + oh * 64;
      size_t tbase = ((size_t)(b * 4 + (co >> 6)) * 4096 + oh * 64);
#pragma unroll
      for (int qd = 0; qd < 4; ++qd) {
        int J = pf * 16 + lq * 4 + qd;
        int ow = 2 * J + s;
        float val = acc[pf][cf][qd] + bv;
        cout[cbase + ow] = val;
        coutT[(tbase + ow) * 64 + (co & 63)] = val;
      }
    }
}

// ---------------- 8. y = coarse_out + region ----------------
__global__ __launch_bounds__(256) void k_ybuild(const float* __restrict__ cout,
                                                float* __restrict__ y) {
  size_t e = (size_t)blockIdx.x * 256 + threadIdx.x;
  int flat = (int)(e & 4095);
  size_t bc = e >> 12;
  int p = flat >> 2, ab = flat & 3;
  int a = ab >> 1, bi = ab & 1;
  int src = ((p >> 5) * 2 + a) * 64 + (p & 31) * 2 + bi;
  const float* cb = cout + bc * 4096;
  y[e] = cb[flat] + cb[src];
}

// ---------------- 9. scatter-add attended tokens ----------------
__global__ __launch_bounds__(256) void k_scatter(const float* __restrict__ out2,
    const int* __restrict__ idx, float* __restrict__ y) {
  int e = blockIdx.x * 256 + threadIdx.x;
  int d = e & 63;
  int r = e >> 6;
  int ab = r & 3;
  int r2 = r >> 2;
  int kk = r2 & 255;
  int bn = r2 >> 8;
  int b = bn >> 2, n = bn & 3;
  int p = idx[bn * 256 + kk] & 1023;
  int flat = p * 4 + ab;
  int t = kk * 4 + ab;
  y[((size_t)(b * 256 + n * 64 + d)) * 4096 + flat] +=
      out2[((size_t)bn * 1024 + t) * 64 + d];
}

// ---------------- 10. depthwise 3x3 + BN + relu6 ----------------
__global__ __launch_bounds__(256) void k_dw(const float* __restrict__ y,
    const float* __restrict__ w, const float* __restrict__ g, const float* __restrict__ bb,
    const float* __restrict__ mm, const float* __restrict__ vv, float* __restrict__ t1) {
  size_t e = (size_t)blockIdx.x * 256 + threadIdx.x;
  int pix = (int)(e & 4095);
  int c = (int)((e >> 12) & 255);
  int oh = pix >> 6, ow = pix & 63;
  const float* yb = y + (e - pix);
  float acc = 0.f;
#pragma unroll
  for (int kh = 0; kh < 3; ++kh) {
    int ih = oh - 1 + kh;
    if ((unsigned)ih >= 64u) continue;
#pragma unroll
    for (int kw = 0; kw < 3; ++kw) {
      int iw = ow - 1 + kw;
      if ((unsigned)iw >= 64u) continue;
      acc = fmaf(yb[ih * 64 + iw], w[c * 9 + kh * 3 + kw], acc);
    }
  }
  float s = g[c] * rsqrtf(vv[c] + 1e-5f);
  float val = acc * s + (bb[c] - mm[c] * s);
  t1[e] = fminf(fmaxf(val, 0.f), 6.f);
}

// ---------------- 11. pointwise v2: 4 co per block, 16 FMA per 16B load --------
__global__ __launch_bounds__(256) void k_pw2(const float* __restrict__ t1,
    const float* __restrict__ w, const float* __restrict__ g, const float* __restrict__ bb,
    const float* __restrict__ mm, const float* __restrict__ vv, float* __restrict__ out) {
  int blk = blockIdx.x;              // (b*64 + cog)*4 + tile
  int tile = blk & 3;
  int cog = (blk >> 2) & 63;
  int b = blk >> 8;
  int co0 = cog * 4;
  int t = threadIdx.x;
  __shared__ float wl[256][4];
  for (int idx = t; idx < 1024; idx += 256) {
    int cof = idx >> 8;
    int ci = idx & 255;
    wl[ci][cof] = w[(co0 + cof) * 256 + ci];
  }
  __syncthreads();
  int px0 = tile * 1024 + t * 4;
  const float* tb = t1 + (size_t)b * 256 * 4096 + px0;
  float acc[4][4];
#pragma unroll
  for (int a = 0; a < 4; ++a)
#pragma unroll
    for (int jj = 0; jj < 4; ++jj) acc[a][jj] = 0.f;
  for (int ci = 0; ci < 256; ++ci) {
    float4 tv = *(const float4*)(tb + (size_t)ci * 4096);
    float4 wv = *(const float4*)&wl[ci][0];
    acc[0][0] = fmaf(tv.x, wv.x, acc[0][0]); acc[0][1] = fmaf(tv.y, wv.x, acc[0][1]);
    acc[0][2] = fmaf(tv.z, wv.x, acc[0][2]); acc[0][3] = fmaf(tv.w, wv.x, acc[0][3]);
    acc[1][0] = fmaf(tv.x, wv.y, acc[1][0]); acc[1][1] = fmaf(tv.y, wv.y, acc[1][1]);
    acc[1][2] = fmaf(tv.z, wv.y, acc[1][2]); acc[1][3] = fmaf(tv.w, wv.y, acc[1][3]);
    acc[2][0] = fmaf(tv.x, wv.z, acc[2][0]); acc[2][1] = fmaf(tv.y, wv.z, acc[2][1]);
    acc[2][2] = fmaf(tv.z, wv.z, acc[2][2]); acc[2][3] = fmaf(tv.w, wv.z, acc[2][3]);
    acc[3][0] = fmaf(tv.x, wv.w, acc[3][0]); acc[3][1] = fmaf(tv.y, wv.w, acc[3][1]);
    acc[3][2] = fmaf(tv.z, wv.w, acc[3][2]); acc[3][3] = fmaf(tv.w, wv.w, acc[3][3]);
  }
#pragma unroll
  for (int a = 0; a < 4; ++a) {
    int co = co0 + a;
    float s = g[co] * rsqrtf(vv[co] + 1e-5f);
    float bias = bb[co] - mm[co] * s;
    float4 o4;
    o4.x = fminf(fmaxf(acc[a][0] * s + bias, 0.f), 6.f);
    o4.y = fminf(fmaxf(acc[a][1] * s + bias, 0.f), 6.f);
    o4.z = fminf(fmaxf(acc[a][2] * s + bias, 0.f), 6.f);
    o4.w = fminf(fmaxf(acc[a][3] * s + bias, 0.f), 6.f);
    *(float4*)(out + ((size_t)(b * 256 + co)) * 4096 + px0) = o4;
  }
}

// ---------------- launcher ----------------
extern "C" void kernel_launch(void* const* d_in, const int* in_sizes, int n_in,
                              void* d_out, int out_size, void* d_ws, size_t ws_size,
                              hipStream_t stream) {
  if (ws_size < WS_FLOATS * sizeof(float)) return;

  const float* x      = (const float*)d_in[0];
  const float* down_w = (const float*)d_in[1];
  const float* down_b = (const float*)d_in[2];
  const float* up_w   = (const float*)d_in[3];
  const float* up_b   = (const float*)d_in[4];
  const float* cqkv_w = (const float*)d_in[5];
  const float* cqkv_b = (const float*)d_in[6];
  const float* tqkv_w = (const float*)d_in[7];
  const float* tqkv_b = (const float*)d_in[8];
  const float* dww    = (const float*)d_in[9];
  const float* bn1g   = (const float*)d_in[10];
  const float* bn1b   = (const float*)d_in[11];
  const float* bn1m   = (const float*)d_in[12];
  const float* bn1v   = (const float*)d_in[13];
  const float* pww    = (const float*)d_in[14];
  const float* bn2g   = (const float*)d_in[15];
  const float* bn2b   = (const float*)d_in[16];
  const float* bn2m   = (const float*)d_in[17];
  const float* bn2v   = (const float*)d_in[18];

  float* ws    = (float*)d_ws;
  float* att   = ws + OFF_ATT;
  float* spart = ws + OFF_SPART;
  float* score = ws + OFF_SCORE;
  int*   idx   = (int*)(ws + OFF_IDX);
  float* cout  = ws + OFF_COUT;
  float* y     = ws + OFF_Y;
  float* t1    = ws + OFF_T1;
  float* attT  = ws + OFF_SPART + 2097152;   // upper half of spart region
  unsigned short* whi  = (unsigned short*)(ws + OFF_XD);            // up-w hi
  unsigned short* wlo  = (unsigned short*)(ws + OFF_XD + 524288);   // up-w lo
  unsigned short* dwhi = (unsigned short*)(ws + OFF_SPART);             // down-w hi (dead after conv_down)
  unsigned short* dwlo = (unsigned short*)(ws + OFF_SPART + 524288);    // down-w lo
  unsigned short* xbh  = (unsigned short*)(ws + OFF_Q);   // x hi (Q..K regions, dead after conv_down)
  unsigned short* xbl  = (unsigned short*)(ws + OFF_V);   // x lo (V..ATT regions, dead after conv_down)
  unsigned short* qh   = (unsigned short*)(ws + OFF_Q);
  unsigned short* ql   = (unsigned short*)(ws + OFF_Q + 1048576);
  unsigned short* kh   = (unsigned short*)(ws + OFF_K);
  unsigned short* kl   = (unsigned short*)(ws + OFF_K + 1048576);
  unsigned short* vth  = (unsigned short*)(ws + OFF_V);
  unsigned short* vtl  = (unsigned short*)(ws + OFF_V + 1048576);
  float* coutT = ws + OFF_T1;                // t1 region dead until k_dw
  float* dpart = ws + OFF_Y;                 // 4 x 2M ci-split partials (dead until k_ybuild)

  k_x2bf<<<1024, 256, 0, stream>>>(x, xbh, xbl);
  k_wt_dnb<<<4096, 256, 0, stream>>>(down_w, dwhi, dwlo);
  k_conv_down_mfma<<<4096, 256, 0, stream>>>(xbh, xbl, dwhi, dwlo, down_b, dpart);
  k_qkv_coarse<<<32768, 192, 0, stream>>>(dpart, cqkv_w, cqkv_b, qh, ql, kh, kl, vth, vtl);
  k_wt_upb<<<4096, 256, 0, stream>>>(up_w, whi, wlo);
  k_attn_score_mfma<<<512, 256, 0, stream>>>(qh, ql, kh, kl, vth, vtl, spart, attT);
  k_score_reduce<<<128, 256, 0, stream>>>(spart, score);
  k_idx_init<<<32, 256, 0, stream>>>(idx);
  k_topk<<<32, 1024, 0, stream>>>(score, idx);
  k_conv_up_mfma<<<2048, 256, 0, stream>>>(attT, whi, wlo, up_b, cout, coutT);
  k_qkv_topk<<<32768, 192, 0, stream>>>(coutT, idx, tqkv_w, tqkv_b, qh, ql, kh, kl, vth, vtl);
  k_attn_online_mfma<<<512, 256, 0, stream>>>(qh, ql, kh, kl, vth, vtl, att);
  k_ybuild<<<32768, 256, 0, stream>>>(cout, y);
  k_scatter<<<8192, 256, 0, stream>>>(att, idx, y);
  k_dw<<<32768, 256, 0, stream>>>(y, dww, bn1g, bn1b, bn1m, bn1v, t1);
  k_pw2<<<2048, 256, 0, stream>>>(t1, pww, bn2g, bn2b, bn2m, bn2v, (float*)d_out);
}

// Round 7
// 1189.805 us; speedup vs baseline: 1.4292x; 1.1448x over previous
//
#include <hip/hip_runtime.h>

typedef short short8 __attribute__((ext_vector_type(8)));
typedef float f32x4 __attribute__((ext_vector_type(4)));

__device__ inline unsigned short f32_to_bf16_rne(float f) {
  unsigned int u = __float_as_uint(f);
  unsigned int r = (u + 0x7fffu + ((u >> 16) & 1u)) >> 16;
  return (unsigned short)r;
}
__device__ inline float bf16_to_f32(unsigned short h) {
  return __uint_as_float(((unsigned int)h) << 16);
}

// ---------------- workspace layout (float offsets) ----------------
// bf16 qkv: qh/ql -> Q region, kh/kl -> K region, vth/vtl (V^T [d][j]) -> V region
// att (O, fp32) -> ATT.  spart -> SPART (+ attT at +2M)  score / idx / cout / y / t1
// aliases: whi/wlo (up-w) -> XD; dwhi/dwlo (down-w) -> SPART (dead before spart use)
//          xbh -> Q..K, xbl -> V..ATT (dead after conv_down)
//          coutT -> t1 region; dpart -> y region
constexpr size_t OFF_XD    = 0;
constexpr size_t OFF_Q     = 2097152;
constexpr size_t OFF_K     = 4194304;
constexpr size_t OFF_V     = 6291456;
constexpr size_t OFF_ATT   = 8388608;
constexpr size_t OFF_SPART = 10485760;
constexpr size_t OFF_SCORE = 14680064;
constexpr size_t OFF_IDX   = 14712832;
constexpr size_t OFF_COUT  = 14721024;
constexpr size_t OFF_Y     = 23109632;
constexpr size_t OFF_T1    = 31498240;
constexpr size_t WS_FLOATS = 39886848;

// ---------------- 0a. x NCHW -> NHWC split-bf16 (xbh/xbl [b][ih][iw][ci]) ------
__global__ __launch_bounds__(256) void k_x2bf(const float* __restrict__ x,
    unsigned short* __restrict__ xbh, unsigned short* __restrict__ xbl) {
  int bid = blockIdx.x;              // b*128 + ih*2 + iwh
  int b = bid >> 7;
  int ih = (bid >> 1) & 63;
  int iwh = bid & 1;
  int t = threadIdx.x;
  __shared__ float ts[256][33];
  for (int it = 0; it < 32; ++it) {
    int idx = it * 256 + t;
    int ci = idx >> 5;
    int iwl = idx & 31;
    ts[ci][iwl] = x[(((size_t)(b * 256 + ci) * 64 + ih) * 64) + iwh * 32 + iwl];
  }
  __syncthreads();
  int iwl = t >> 3;
  int cb = (t & 7) * 32;
  size_t base = (((size_t)(b * 64 + ih) * 64) + iwh * 32 + iwl) * 256 + cb;
#pragma unroll
  for (int j = 0; j < 32; j += 2) {
    float v0 = ts[cb + j][iwl];
    float v1 = ts[cb + j + 1][iwl];
    unsigned short h0 = f32_to_bf16_rne(v0);
    unsigned short h1 = f32_to_bf16_rne(v1);
    unsigned short l0 = f32_to_bf16_rne(v0 - bf16_to_f32(h0));
    unsigned short l1 = f32_to_bf16_rne(v1 - bf16_to_f32(h1));
    *(ushort2*)&xbh[base + j] = make_ushort2(h0, h1);
    *(ushort2*)&xbl[base + j] = make_ushort2(l0, l1);
  }
}

// ---------------- 0b. down_w -> split-bf16 dwhi/dwlo [kk][co][ci] --------------
__global__ __launch_bounds__(256) void k_wt_dnb(const float* __restrict__ w,
    unsigned short* __restrict__ dwhi, unsigned short* __restrict__ dwlo) {
  int idx = blockIdx.x * 256 + threadIdx.x;   // 1,048,576 = (kk*256+co)*256+ci
  int ci = idx & 255;
  int co = (idx >> 8) & 255;
  int kk = idx >> 16;
  float v = w[((size_t)(co * 256 + ci)) * 16 + kk];
  unsigned short h = f32_to_bf16_rne(v);
  unsigned short l = f32_to_bf16_rne(v - bf16_to_f32(h));
  dwhi[idx] = h;
  dwlo[idx] = l;
}

// ---------------- 0c. up_w -> split-bf16 whi/wlo [cls][tap][co][ci] ----------
__global__ __launch_bounds__(256) void k_wt_upb(const float* __restrict__ w,
    unsigned short* __restrict__ whi, unsigned short* __restrict__ wlo) {
  int idx = blockIdx.x * 256 + threadIdx.x;   // 1,048,576
  int ci = idx & 255;
  int co = (idx >> 8) & 255;
  int tp = idx >> 16;                         // 0..15
  int cls = tp >> 2, tap = tp & 3;
  int r = cls >> 1, s = cls & 1;
  int a_ = tap >> 1, b_ = tap & 1;
  int kh = a_ ? (r ? 2 : 3) : (r ? 0 : 1);
  int kw = b_ ? (s ? 2 : 3) : (s ? 0 : 1);
  float v = w[((size_t)(ci * 256 + co)) * 16 + kh * 4 + kw];
  unsigned short h = f32_to_bf16_rne(v);
  unsigned short l = f32_to_bf16_rne(v - bf16_to_f32(h));
  whi[idx] = h;
  wlo[idx] = l;
}

// ---------------- 1. down conv: split-bf16 MFMA implicit GEMM ------------------
__global__ __launch_bounds__(256) void k_conv_down_mfma(
    const unsigned short* __restrict__ xbh, const unsigned short* __restrict__ xbl,
    const unsigned short* __restrict__ dwhi, const unsigned short* __restrict__ dwlo,
    const float* __restrict__ bias, float* __restrict__ part) {
  int blk = blockIdx.x;              // ((ks*8 + b)*4 + ct)*32 + pt
  int pt = blk & 31;
  int ct = (blk >> 5) & 3;
  int b = (blk >> 7) & 7;
  int ks = blk >> 10;
  int oh2 = pt >> 1;                 // 0..15 (pair of oh rows)
  int owh = pt & 1;                  // ow half (16)
  int tid = threadIdx.x;
  int w = tid >> 6;                  // wave 0..3 -> co quarter
  int lane = tid & 63;
  int lq = lane >> 4;
  int lr = lane & 15;
  int co = ct * 64 + w * 16 + lr;

  __shared__ __align__(16) unsigned short AH[6][34][40];
  __shared__ __align__(16) unsigned short AL[6][34][40];

  f32x4 acc[2];
  acc[0] = (f32x4){0.f, 0.f, 0.f, 0.f};
  acc[1] = (f32x4){0.f, 0.f, 0.f, 0.f};

  int ih0 = 4 * oh2 - 1;             // tile row 0
  int iw0 = owh * 32 - 1;            // tile col 0
  const short8 zero8 = {0, 0, 0, 0, 0, 0, 0, 0};

  for (int ch = 0; ch < 2; ++ch) {
    int ci0 = ks * 64 + ch * 32;
    __syncthreads();
    for (int idx = tid; idx < 6 * 34 * 4; idx += 256) {
      int q = idx & 3;
      int cell = idx >> 2;
      int row = cell / 34;
      int col = cell - row * 34;
      int ih = ih0 + row;
      int iw = iw0 + col;
      short8 h = zero8, l = zero8;
      if ((unsigned)ih < 64u && (unsigned)iw < 64u) {
        size_t gg = (((size_t)(b * 64 + ih) * 64) + iw) * 256 + ci0 + q * 8;
        h = *(const short8*)&xbh[gg];
        l = *(const short8*)&xbl[gg];
      }
      *(short8*)&AH[row][col][q * 8] = h;
      *(short8*)&AL[row][col][q * 8] = l;
    }
    __syncthreads();
#pragma unroll
    for (int tap = 0; tap < 16; ++tap) {
      int kh = tap >> 2, kw = tap & 3;
      size_t woff = ((size_t)tap * 256 + co) * 256 + ci0 + 8 * lq;
      short8 bh = *(const short8*)&dwhi[woff];
      short8 bl = *(const short8*)&dwlo[woff];
#pragma unroll
      for (int pf = 0; pf < 2; ++pf) {
        short8 ah = *(const short8*)&AH[2 * pf + kh][2 * lr + kw][8 * lq];
        short8 al = *(const short8*)&AL[2 * pf + kh][2 * lr + kw][8 * lq];
        acc[pf] = __builtin_amdgcn_mfma_f32_16x16x32_bf16(ah, bh, acc[pf], 0, 0, 0);
        acc[pf] = __builtin_amdgcn_mfma_f32_16x16x32_bf16(al, bh, acc[pf], 0, 0, 0);
        acc[pf] = __builtin_amdgcn_mfma_f32_16x16x32_bf16(ah, bl, acc[pf], 0, 0, 0);
      }
    }
  }

  float bv = (ks == 0) ? bias[co] : 0.f;
  int bn = b * 4 + ct;
  int d = w * 16 + lr;
  float* pb = part + (size_t)ks * 2097152;
#pragma unroll
  for (int pf = 0; pf < 2; ++pf) {
    int oh = 2 * oh2 + pf;
#pragma unroll
    for (int reg = 0; reg < 4; ++reg) {
      int ow = owh * 16 + lq * 4 + reg;
      int pix = oh * 32 + ow;
      pb[((size_t)bn * 1024 + pix) * 64 + d] = acc[pf][reg] + bv;
    }
  }
}

// ---------------- 2. QKV gemm coarse -> bf16 hi/lo q,k + V^T -------------------
__global__ __launch_bounds__(192) void k_qkv_coarse(const float* __restrict__ part,
    const float* __restrict__ W, const float* __restrict__ bias,
    unsigned short* __restrict__ qh, unsigned short* __restrict__ ql,
    unsigned short* __restrict__ kh, unsigned short* __restrict__ kl,
    unsigned short* __restrict__ vth, unsigned short* __restrict__ vtl) {
  int row = blockIdx.x;              // bn*1024 + i
  int bn = row >> 10, i = row & 1023;
  __shared__ float t[64];
  if (threadIdx.x < 64) {
    size_t o = (size_t)row * 64 + threadIdx.x;
    t[threadIdx.x] = ((part[o] + part[o + 2097152]) +
                      part[o + 2 * 2097152]) + part[o + 3 * 2097152];
  }
  __syncthreads();
  int e = threadIdx.x;               // 0..191
  float acc = bias[e];
  const float* wr = W + e * 64;
#pragma unroll
  for (int d = 0; d < 64; ++d) acc = fmaf(t[d], wr[d], acc);
  unsigned short h = f32_to_bf16_rne(acc);
  unsigned short lo = f32_to_bf16_rne(acc - bf16_to_f32(h));
  if (e < 64) {
    qh[(size_t)row * 64 + e] = h;
    ql[(size_t)row * 64 + e] = lo;
  } else if (e < 128) {
    kh[(size_t)row * 64 + e - 64] = h;
    kl[(size_t)row * 64 + e - 64] = lo;
  } else {
    size_t o2 = ((size_t)bn * 64 + (e - 128)) * 1024 + i;
    vth[o2] = h;
    vtl[o2] = lo;
  }
}

// ---------------- 3. QKV gemm topk -> bf16 hi/lo q,k + V^T ---------------------
__global__ __launch_bounds__(192) void k_qkv_topk(const float* __restrict__ coutT,
    const int* __restrict__ idx, const float* __restrict__ W, const float* __restrict__ bias,
    unsigned short* __restrict__ qh, unsigned short* __restrict__ ql,
    unsigned short* __restrict__ kh, unsigned short* __restrict__ kl,
    unsigned short* __restrict__ vth, unsigned short* __restrict__ vtl) {
  int row = blockIdx.x;              // bn*1024 + tk
  int bn = row >> 10, tk = row & 1023;
  int kk = tk >> 2, ab = tk & 3;
  int a = ab >> 1, bi = ab & 1;
  __shared__ float tl[64];
  __shared__ int ps;
  if (threadIdx.x == 0) ps = idx[bn * 256 + kk] & 1023;
  __syncthreads();
  int p = ps;
  int sh = (p >> 5) * 2 + a, sw = (p & 31) * 2 + bi;
  if (threadIdx.x < 64)
    tl[threadIdx.x] = coutT[((size_t)bn * 4096 + sh * 64 + sw) * 64 + threadIdx.x];
  __syncthreads();
  int e = threadIdx.x;
  float acc = bias[e];
  const float* wr = W + e * 64;
#pragma unroll
  for (int d = 0; d < 64; ++d) acc = fmaf(tl[d], wr[d], acc);
  unsigned short h = f32_to_bf16_rne(acc);
  unsigned short lo = f32_to_bf16_rne(acc - bf16_to_f32(h));
  if (e < 64) {
    qh[(size_t)row * 64 + e] = h;
    ql[(size_t)row * 64 + e] = lo;
  } else if (e < 128) {
    kh[(size_t)row * 64 + e - 64] = h;
    kl[(size_t)row * 64 + e - 64] = lo;
  } else {
    size_t o2 = ((size_t)bn * 64 + (e - 128)) * 1024 + tk;
    vth[o2] = h;
    vtl[o2] = lo;
  }
}

// ---------------- 4a. attention+score, split-bf16 MFMA (2-pass) ----------------
// LDS-staged Q/V per jt (coop, shared by all 4 waves); XCD swizzle: bn = blk&31
// so same-bn blocks land on the same XCD L2 (stride-32 block indices).
__global__ __launch_bounds__(256) void k_attn_score_mfma(
    const unsigned short* __restrict__ qh, const unsigned short* __restrict__ ql,
    const unsigned short* __restrict__ kh, const unsigned short* __restrict__ kl,
    const unsigned short* __restrict__ vth, const unsigned short* __restrict__ vtl,
    float* __restrict__ spart, float* __restrict__ attT) {
  int blk = blockIdx.x;
  int bn = blk & 31;                 // XCD-locality: same bn -> idx ≡ bn (mod 8)
  int it = blk >> 5;
  int tid = threadIdx.x;
  int w = tid >> 6;
  int lane = tid & 63;
  int g = lane >> 4;
  int c = lane & 15;
  size_t qb = (size_t)bn << 16;      // *65536 (u16 elements)

  __shared__ __align__(16) unsigned short QH[64][72];
  __shared__ __align__(16) unsigned short QL[64][72];
  __shared__ __align__(16) unsigned short VH[64][72];
  __shared__ __align__(16) unsigned short VL[64][72];
  __shared__ __align__(16) unsigned short PH[64][72];
  __shared__ __align__(16) unsigned short PL[64][72];
  __shared__ float sacc[1024];
  for (int i2 = tid; i2 < 1024; i2 += 256) sacc[i2] = 0.f;

  int r0 = tid >> 3;                 // staging row 0..31
  int c8 = (tid & 7) * 8;            // staging col (u16)

  // K A-frags for this wave's 16 rows (A row = lane&15)
  int irow = it * 64 + w * 16 + c;
  short8 kfh[2], kfl[2];
#pragma unroll
  for (int ch = 0; ch < 2; ++ch) {
    kfh[ch] = *(const short8*)&kh[qb + (size_t)irow * 64 + ch * 32 + g * 8];
    kfl[ch] = *(const short8*)&kl[qb + (size_t)irow * 64 + ch * 32 + g * 8];
  }

  float m[4], lsum[4];
#pragma unroll
  for (int r = 0; r < 4; ++r) { m[r] = -3.0e38f; lsum[r] = 0.f; }

  // ---- pass 1: row max / denom (Q staged in LDS per jt) ----
  for (int jt = 0; jt < 16; ++jt) {
    __syncthreads();
#pragma unroll
    for (int rr = 0; rr < 2; ++rr) {
      int row = r0 + rr * 32;
      size_t go = qb + (size_t)(jt * 64 + row) * 64 + c8;
      *(short8*)&QH[row][c8] = *(const short8*)&qh[go];
      *(short8*)&QL[row][c8] = *(const short8*)&ql[go];
    }
    __syncthreads();
    f32x4 s[4];
#pragma unroll
    for (int su = 0; su < 4; ++su) s[su] = (f32x4){0.f, 0.f, 0.f, 0.f};
#pragma unroll
    for (int ch = 0; ch < 2; ++ch)
#pragma unroll
      for (int su = 0; su < 4; ++su) {
        short8 qfh = *(const short8*)&QH[su * 16 + c][ch * 32 + g * 8];
        short8 qfl = *(const short8*)&QL[su * 16 + c][ch * 32 + g * 8];
        s[su] = __builtin_amdgcn_mfma_f32_16x16x32_bf16(kfh[ch], qfh, s[su], 0, 0, 0);
        s[su] = __builtin_amdgcn_mfma_f32_16x16x32_bf16(kfl[ch], qfh, s[su], 0, 0, 0);
        s[su] = __builtin_amdgcn_mfma_f32_16x16x32_bf16(kfh[ch], qfl, s[su], 0, 0, 0);
      }
#pragma unroll
    for (int r = 0; r < 4; ++r) {
      float tm = fmaxf(fmaxf(s[0][r], s[1][r]), fmaxf(s[2][r], s[3][r]));
#pragma unroll
      for (int off = 1; off <= 8; off <<= 1) tm = fmaxf(tm, __shfl_xor(tm, off, 64));
      float mn = fmaxf(m[r], tm);
      float ts = ((expf(s[0][r] - mn) + expf(s[1][r] - mn)) +
                  expf(s[2][r] - mn)) + expf(s[3][r] - mn);
#pragma unroll
      for (int off = 1; off <= 8; off <<= 1) ts += __shfl_xor(ts, off, 64);
      lsum[r] = lsum[r] * expf(m[r] - mn) + ts;
      m[r] = mn;
    }
  }
  float inv[4];
#pragma unroll
  for (int r = 0; r < 4; ++r) inv[r] = 1.f / lsum[r];

  f32x4 oacc[4];
#pragma unroll
  for (int d = 0; d < 4; ++d) oacc[d] = (f32x4){0.f, 0.f, 0.f, 0.f};

  // ---- pass 2: P, scores, PV (Q+V staged in LDS per jt) ----
  for (int jt = 0; jt < 16; ++jt) {
    __syncthreads();
#pragma unroll
    for (int rr = 0; rr < 2; ++rr) {
      int row = r0 + rr * 32;
      size_t go = qb + (size_t)(jt * 64 + row) * 64 + c8;
      *(short8*)&QH[row][c8] = *(const short8*)&qh[go];
      *(short8*)&QL[row][c8] = *(const short8*)&ql[go];
      size_t vo = ((size_t)(bn * 64 + row)) * 1024 + jt * 64 + c8;
      *(short8*)&VH[row][c8] = *(const short8*)&vth[vo];
      *(short8*)&VL[row][c8] = *(const short8*)&vtl[vo];
    }
    __syncthreads();
    f32x4 s[4];
#pragma unroll
    for (int su = 0; su < 4; ++su) s[su] = (f32x4){0.f, 0.f, 0.f, 0.f};
#pragma unroll
    for (int ch = 0; ch < 2; ++ch)
#pragma unroll
      for (int su = 0; su < 4; ++su) {
        short8 qfh = *(const short8*)&QH[su * 16 + c][ch * 32 + g * 8];
        short8 qfl = *(const short8*)&QL[su * 16 + c][ch * 32 + g * 8];
        s[su] = __builtin_amdgcn_mfma_f32_16x16x32_bf16(kfh[ch], qfh, s[su], 0, 0, 0);
        s[su] = __builtin_amdgcn_mfma_f32_16x16x32_bf16(kfl[ch], qfh, s[su], 0, 0, 0);
        s[su] = __builtin_amdgcn_mfma_f32_16x16x32_bf16(kfh[ch], qfl, s[su], 0, 0, 0);
      }
#pragma unroll
    for (int su = 0; su < 4; ++su) {
      float p0 = expf(s[su][0] - m[0]) * inv[0];
      float p1 = expf(s[su][1] - m[1]) * inv[1];
      float p2 = expf(s[su][2] - m[2]) * inv[2];
      float p3 = expf(s[su][3] - m[3]) * inv[3];
      float cs = ((p0 + p1) + p2) + p3;
      cs += __shfl_xor(cs, 16, 64);
      cs += __shfl_xor(cs, 32, 64);
      if (g == 0) atomicAdd(&sacc[jt * 64 + su * 16 + c], cs);
      unsigned short h0 = f32_to_bf16_rne(p0);
      unsigned short h1 = f32_to_bf16_rne(p1);
      unsigned short h2 = f32_to_bf16_rne(p2);
      unsigned short h3 = f32_to_bf16_rne(p3);
      PH[w * 16 + g * 4 + 0][su * 16 + c] = h0;
      PH[w * 16 + g * 4 + 1][su * 16 + c] = h1;
      PH[w * 16 + g * 4 + 2][su * 16 + c] = h2;
      PH[w * 16 + g * 4 + 3][su * 16 + c] = h3;
      PL[w * 16 + g * 4 + 0][su * 16 + c] = f32_to_bf16_rne(p0 - bf16_to_f32(h0));
      PL[w * 16 + g * 4 + 1][su * 16 + c] = f32_to_bf16_rne(p1 - bf16_to_f32(h1));
      PL[w * 16 + g * 4 + 2][su * 16 + c] = f32_to_bf16_rne(p2 - bf16_to_f32(h2));
      PL[w * 16 + g * 4 + 3][su * 16 + c] = f32_to_bf16_rne(p3 - bf16_to_f32(h3));
    }
#pragma unroll
    for (int ch = 0; ch < 2; ++ch) {
      short8 pfh = *(const short8*)&PH[w * 16 + c][ch * 32 + g * 8];
      short8 pfl = *(const short8*)&PL[w * 16 + c][ch * 32 + g * 8];
#pragma unroll
      for (int d = 0; d < 4; ++d) {
        short8 vfh = *(const short8*)&VH[d * 16 + c][ch * 32 + g * 8];
        short8 vfl = *(const short8*)&VL[d * 16 + c][ch * 32 + g * 8];
        oacc[d] = __builtin_amdgcn_mfma_f32_16x16x32_bf16(vfh, pfh, oacc[d], 0, 0, 0);
        oacc[d] = __builtin_amdgcn_mfma_f32_16x16x32_bf16(vfl, pfh, oacc[d], 0, 0, 0);
        oacc[d] = __builtin_amdgcn_mfma_f32_16x16x32_bf16(vfh, pfl, oacc[d], 0, 0, 0);
      }
    }
  }
  // O^T D-layout: lane holds O^T[d = d*16 + g*4 + reg][i = it*64 + w*16 + c]
#pragma unroll
  for (int d = 0; d < 4; ++d)
#pragma unroll
    for (int r = 0; r < 4; ++r)
      attT[((size_t)bn * 64 + d * 16 + g * 4 + r) * 1024 + it * 64 + w * 16 + c] =
          oacc[d][r];
  __syncthreads();
  for (int i2 = tid; i2 < 1024; i2 += 256)
    spart[((size_t)bn * 16 + it) * 1024 + i2] = sacc[i2];
}

// ---------------- 4b. topk attention, split-bf16 MFMA (1-pass online) ----------
__global__ __launch_bounds__(256) void k_attn_online_mfma(
    const unsigned short* __restrict__ qh, const unsigned short* __restrict__ ql,
    const unsigned short* __restrict__ kh, const unsigned short* __restrict__ kl,
    const unsigned short* __restrict__ vth, const unsigned short* __restrict__ vtl,
    float* __restrict__ O) {
  int blk = blockIdx.x;
  int bn = blk & 31;                 // XCD-locality swizzle
  int it = blk >> 5;
  int tid = threadIdx.x;
  int w = tid >> 6;
  int lane = tid & 63;
  int g = lane >> 4;
  int c = lane & 15;
  size_t qb = (size_t)bn << 16;

  __shared__ __align__(16) unsigned short QH[64][72];
  __shared__ __align__(16) unsigned short QL[64][72];
  __shared__ __align__(16) unsigned short VH[64][72];
  __shared__ __align__(16) unsigned short VL[64][72];
  __shared__ __align__(16) unsigned short PH[64][72];
  __shared__ __align__(16) unsigned short PL[64][72];

  int r0 = tid >> 3;
  int c8 = (tid & 7) * 8;

  int irow = it * 64 + w * 16 + c;
  short8 kfh[2], kfl[2];
#pragma unroll
  for (int ch = 0; ch < 2; ++ch) {
    kfh[ch] = *(const short8*)&kh[qb + (size_t)irow * 64 + ch * 32 + g * 8];
    kfl[ch] = *(const short8*)&kl[qb + (size_t)irow * 64 + ch * 32 + g * 8];
  }

  float m[4], lsum[4];
  f32x4 oacc[4];
#pragma unroll
  for (int r = 0; r < 4; ++r) { m[r] = -3.0e38f; lsum[r] = 0.f; }
#pragma unroll
  for (int d = 0; d < 4; ++d) oacc[d] = (f32x4){0.f, 0.f, 0.f, 0.f};

  for (int jt = 0; jt < 16; ++jt) {
    __syncthreads();
#pragma unroll
    for (int rr = 0; rr < 2; ++rr) {
      int row = r0 + rr * 32;
      size_t go = qb + (size_t)(jt * 64 + row) * 64 + c8;
      *(short8*)&QH[row][c8] = *(const short8*)&qh[go];
      *(short8*)&QL[row][c8] = *(const short8*)&ql[go];
      size_t vo = ((size_t)(bn * 64 + row)) * 1024 + jt * 64 + c8;
      *(short8*)&VH[row][c8] = *(const short8*)&vth[vo];
      *(short8*)&VL[row][c8] = *(const short8*)&vtl[vo];
    }
    __syncthreads();
    f32x4 s[4];
#pragma unroll
    for (int su = 0; su < 4; ++su) s[su] = (f32x4){0.f, 0.f, 0.f, 0.f};
#pragma unroll
    for (int ch = 0; ch < 2; ++ch)
#pragma unroll
      for (int su = 0; su < 4; ++su) {
        short8 qfh = *(const short8*)&QH[su * 16 + c][ch * 32 + g * 8];
        short8 qfl = *(const short8*)&QL[su * 16 + c][ch * 32 + g * 8];
        s[su] = __builtin_amdgcn_mfma_f32_16x16x32_bf16(kfh[ch], qfh, s[su], 0, 0, 0);
        s[su] = __builtin_amdgcn_mfma_f32_16x16x32_bf16(kfl[ch], qfh, s[su], 0, 0, 0);
        s[su] = __builtin_amdgcn_mfma_f32_16x16x32_bf16(kfh[ch], qfl, s[su], 0, 0, 0);
      }
    float sc[4];
#pragma unroll
    for (int r = 0; r < 4; ++r) {
      float tm = fmaxf(fmaxf(s[0][r], s[1][r]), fmaxf(s[2][r], s[3][r]));
#pragma unroll
      for (int off = 1; off <= 8; off <<= 1) tm = fmaxf(tm, __shfl_xor(tm, off, 64));
      float mn = fmaxf(m[r], tm);
      sc[r] = expf(m[r] - mn);
      float p0 = expf(s[0][r] - mn);
      float p1 = expf(s[1][r] - mn);
      float p2 = expf(s[2][r] - mn);
      float p3 = expf(s[3][r] - mn);
      s[0][r] = p0; s[1][r] = p1; s[2][r] = p2; s[3][r] = p3;
      float ts = ((p0 + p1) + p2) + p3;
#pragma unroll
      for (int off = 1; off <= 8; off <<= 1) ts += __shfl_xor(ts, off, 64);
      lsum[r] = lsum[r] * sc[r] + ts;
      m[r] = mn;
    }
#pragma unroll
    for (int su = 0; su < 4; ++su) {
      unsigned short h0 = f32_to_bf16_rne(s[su][0]);
      unsigned short h1 = f32_to_bf16_rne(s[su][1]);
      unsigned short h2 = f32_to_bf16_rne(s[su][2]);
      unsigned short h3 = f32_to_bf16_rne(s[su][3]);
      PH[w * 16 + g * 4 + 0][su * 16 + c] = h0;
      PH[w * 16 + g * 4 + 1][su * 16 + c] = h1;
      PH[w * 16 + g * 4 + 2][su * 16 + c] = h2;
      PH[w * 16 + g * 4 + 3][su * 16 + c] = h3;
      PL[w * 16 + g * 4 + 0][su * 16 + c] = f32_to_bf16_rne(s[su][0] - bf16_to_f32(h0));
      PL[w * 16 + g * 4 + 1][su * 16 + c] = f32_to_bf16_rne(s[su][1] - bf16_to_f32(h1));
      PL[w * 16 + g * 4 + 2][su * 16 + c] = f32_to_bf16_rne(s[su][2] - bf16_to_f32(h2));
      PL[w * 16 + g * 4 + 3][su * 16 + c] = f32_to_bf16_rne(s[su][3] - bf16_to_f32(h3));
    }
    // rescale oacc by sc for col i=c (branchless select + shfl, rule #20 safe)
    float s01 = (c & 1) ? sc[1] : sc[0];
    float s23 = (c & 1) ? sc[3] : sc[2];
    float tmp = (c & 2) ? s23 : s01;
    float scc = __shfl(tmp, ((c >> 2) << 4) | c, 64);
#pragma unroll
    for (int d = 0; d < 4; ++d) oacc[d] *= scc;
#pragma unroll
    for (int ch = 0; ch < 2; ++ch) {
      short8 pfh = *(const short8*)&PH[w * 16 + c][ch * 32 + g * 8];
      short8 pfl = *(const short8*)&PL[w * 16 + c][ch * 32 + g * 8];
#pragma unroll
      for (int d = 0; d < 4; ++d) {
        short8 vfh = *(const short8*)&VH[d * 16 + c][ch * 32 + g * 8];
        short8 vfl = *(const short8*)&VL[d * 16 + c][ch * 32 + g * 8];
        oacc[d] = __builtin_amdgcn_mfma_f32_16x16x32_bf16(vfh, pfh, oacc[d], 0, 0, 0);
        oacc[d] = __builtin_amdgcn_mfma_f32_16x16x32_bf16(vfl, pfh, oacc[d], 0, 0, 0);
        oacc[d] = __builtin_amdgcn_mfma_f32_16x16x32_bf16(vfh, pfl, oacc[d], 0, 0, 0);
      }
    }
  }
  float i01 = (c & 1) ? (1.f / lsum[1]) : (1.f / lsum[0]);
  float i23 = (c & 1) ? (1.f / lsum[3]) : (1.f / lsum[2]);
  float itmp = (c & 2) ? i23 : i01;
  float invc = __shfl(itmp, ((c >> 2) << 4) | c, 64);
  // O natural [i][d]: lane col i = it*64+w*16+c; rows d = d*16+g*4+reg (contig f32x4)
#pragma unroll
  for (int d = 0; d < 4; ++d) {
    f32x4 o4 = oacc[d] * invc;
    *(f32x4*)&O[((size_t)bn * 1024 + it * 64 + w * 16 + c) * 64 + d * 16 + g * 4] = o4;
  }
}

// ---------------- 5. deterministic score reduction (16 partials) ----------------
__global__ __launch_bounds__(256) void k_score_reduce(const float* __restrict__ part,
                                                      float* __restrict__ score) {
  int j = blockIdx.x * 256 + threadIdx.x;   // 0..32767
  int bn = j >> 10, jj = j & 1023;
  float s = 0.f;
  for (int g = 0; g < 16; ++g) s += part[((size_t)bn * 16 + g) * 1024 + jj];
  score[j] = s;
}

// ---------------- 5b. default-init idx ----------------
__global__ __launch_bounds__(256) void k_idx_init(int* __restrict__ idx) {
  int j = blockIdx.x * 256 + threadIdx.x;
  idx[j] = j & 255;
}

// ---------------- 6. top-K by rank ----------------
__global__ __launch_bounds__(1024) void k_topk(const float* __restrict__ score,
                                               int* __restrict__ idxout) {
  int bn = blockIdx.x;
  int t = threadIdx.x;
  __shared__ float s[1024];
  s[t] = score[bn * 1024 + t];
  __syncthreads();
  float my = s[t];
  int rank = 0;
  for (int j = 0; j < 1024; ++j) {
    float o = s[j];
    rank += (o > my) || (o == my && j < t);
  }
  if (rank < 256) idxout[bn * 256 + rank] = t;
}

// ---------------- 7. transposed conv: split-bf16 MFMA implicit GEMM -----------
__global__ __launch_bounds__(256) void k_conv_up_mfma(
    const float* __restrict__ attT, const unsigned short* __restrict__ whi,
    const unsigned short* __restrict__ wlo, const float* __restrict__ bias,
    float* __restrict__ cout, float* __restrict__ coutT) {
  int blk = blockIdx.x;              // ((b*4 + cls)*16 + pt)*4 + ct
  int ct = blk & 3;
  int pt = (blk >> 2) & 15;
  int cls = (blk >> 6) & 3;
  int b = blk >> 8;
  int r = cls >> 1, s = cls & 1;
  int Ib = pt * 2;
  int co0 = ct * 64;
  int tid = threadIdx.x;
  int w = tid >> 6;                  // wave 0..3
  int lane = tid & 63;
  int lq = lane >> 4;                // quarter 0..3
  int lr = lane & 15;
  int wr = w >> 1;                   // I-row within tile
  int wc = w & 1;                    // co half
  int co0w = co0 + wc * 32;

  __shared__ __align__(16) unsigned short AH[3][33][40];
  __shared__ __align__(16) unsigned short AL[3][33][40];

  f32x4 acc[2][2];
#pragma unroll
  for (int pf = 0; pf < 2; ++pf)
#pragma unroll
    for (int cf = 0; cf < 2; ++cf) acc[pf][cf] = (f32x4){0.f, 0.f, 0.f, 0.f};

  const float* ab = attT + (size_t)b * 4 * 65536;
  int ih_base = Ib + r - 1;
  int iw_base = s - 1;

  for (int ci0 = 0; ci0 < 256; ci0 += 32) {
    int n = ci0 >> 6, d0 = ci0 & 63;
    __syncthreads();
    for (int idx = tid; idx < 3168; idx += 256) {
      int ciL = idx / 99;            // 0..31
      int rem = idx - ciL * 99;
      int rho = rem / 33;
      int c = rem - rho * 33;
      int ih = ih_base + rho;
      int iw = iw_base + c;
      float v = 0.f;
      if ((unsigned)ih < 32u && (unsigned)iw < 32u)
        v = ab[((size_t)n * 64 + d0 + ciL) * 1024 + ih * 32 + iw];
      unsigned short h = f32_to_bf16_rne(v);
      unsigned short lo = f32_to_bf16_rne(v - bf16_to_f32(h));
      AH[rho][c][ciL] = h;
      AL[rho][c][ciL] = lo;
    }
    __syncthreads();
#pragma unroll
    for (int tap = 0; tap < 4; ++tap) {
      int a_ = tap >> 1, b_ = tap & 1;
      int rho = wr + 1 - a_;
      short8 ah[2], al[2];
#pragma unroll
      for (int pf = 0; pf < 2; ++pf) {
        int col = pf * 16 + lr + 1 - b_;
        ah[pf] = *(const short8*)&AH[rho][col][8 * lq];
        al[pf] = *(const short8*)&AL[rho][col][8 * lq];
      }
      size_t wb = (size_t)(cls * 4 + tap) * 65536;
      short8 bh[2], bl[2];
#pragma unroll
      for (int cf = 0; cf < 2; ++cf) {
        size_t off = wb + (size_t)(co0w + cf * 16 + lr) * 256 + ci0 + 8 * lq;
        bh[cf] = *(const short8*)&whi[off];
        bl[cf] = *(const short8*)&wlo[off];
      }
#pragma unroll
      for (int pf = 0; pf < 2; ++pf)
#pragma unroll
        for (int cf = 0; cf < 2; ++cf) {
          acc[pf][cf] = __builtin_amdgcn_mfma_f32_16x16x32_bf16(ah[pf], bh[cf], acc[pf][cf], 0, 0, 0);
          acc[pf][cf] = __builtin_amdgcn_mfma_f32_16x16x32_bf16(al[pf], bh[cf], acc[pf][cf], 0, 0, 0);
          acc[pf][cf] = __builtin_amdgcn_mfma_f32_16x16x32_bf16(ah[pf], bl[cf], acc[pf][cf], 0, 0, 0);
        }
    }
  }

  int I = Ib + wr;
  int oh = 2 * I + r;
#pragma unroll
  for (int pf = 0; pf < 2; ++pf)
#pragma unroll
    for (int cf = 0; cf < 2; ++cf) {
      int co = co0w + cf * 16 + lr;
      float bv = bias[co];
      size_t cbase = ((size_t)b * 256 + co) * 4096 + oh * 64;
      size_t tbase = ((size_t)(b * 4 + (co >> 6)) * 4096 + oh * 64);
#pragma unroll
      for (int qd = 0; qd < 4; ++qd) {
        int J = pf * 16 + lq * 4 + qd;
        int ow = 2 * J + s;
        float val = acc[pf][cf][qd] + bv;
        cout[cbase + ow] = val;
        coutT[(tbase + ow) * 64 + (co & 63)] = val;
      }
    }
}

// ---------------- 8. y = coarse_out + region ----------------
__global__ __launch_bounds__(256) void k_ybuild(const float* __restrict__ cout,
                                                float* __restrict__ y) {
  size_t e = (size_t)blockIdx.x * 256 + threadIdx.x;
  int flat = (int)(e & 4095);
  size_t bc = e >> 12;
  int p = flat >> 2, ab = flat & 3;
  int a = ab >> 1, bi = ab & 1;
  int src = ((p >> 5) * 2 + a) * 64 + (p & 31) * 2 + bi;
  const float* cb = cout + bc * 4096;
  y[e] = cb[flat] + cb[src];
}

// ---------------- 9. scatter-add attended tokens ----------------
__global__ __launch_bounds__(256) void k_scatter(const float* __restrict__ out2,
    const int* __restrict__ idx, float* __restrict__ y) {
  int e = blockIdx.x * 256 + threadIdx.x;
  int d = e & 63;
  int r = e >> 6;
  int ab = r & 3;
  int r2 = r >> 2;
  int kk = r2 & 255;
  int bn = r2 >> 8;
  int b = bn >> 2, n = bn & 3;
  int p = idx[bn * 256 + kk] & 1023;
  int flat = p * 4 + ab;
  int t = kk * 4 + ab;
  y[((size_t)(b * 256 + n * 64 + d)) * 4096 + flat] +=
      out2[((size_t)bn * 1024 + t) * 64 + d];
}

// ---------------- 10. depthwise 3x3 + BN + relu6 ----------------
__global__ __launch_bounds__(256) void k_dw(const float* __restrict__ y,
    const float* __restrict__ w, const float* __restrict__ g, const float* __restrict__ bb,
    const float* __restrict__ mm, const float* __restrict__ vv, float* __restrict__ t1) {
  size_t e = (size_t)blockIdx.x * 256 + threadIdx.x;
  int pix = (int)(e & 4095);
  int c = (int)((e >> 12) & 255);
  int oh = pix >> 6, ow = pix & 63;
  const float* yb = y + (e - pix);
  float acc = 0.f;
#pragma unroll
  for (int kh = 0; kh < 3; ++kh) {
    int ih = oh - 1 + kh;
    if ((unsigned)ih >= 64u) continue;
#pragma unroll
    for (int kw = 0; kw < 3; ++kw) {
      int iw = ow - 1 + kw;
      if ((unsigned)iw >= 64u) continue;
      acc = fmaf(yb[ih * 64 + iw], w[c * 9 + kh * 3 + kw], acc);
    }
  }
  float s = g[c] * rsqrtf(vv[c] + 1e-5f);
  float val = acc * s + (bb[c] - mm[c] * s);
  t1[e] = fminf(fmaxf(val, 0.f), 6.f);
}

// ---------------- 11. pointwise v2: 4 co per block, 16 FMA per 16B load --------
__global__ __launch_bounds__(256) void k_pw2(const float* __restrict__ t1,
    const float* __restrict__ w, const float* __restrict__ g, const float* __restrict__ bb,
    const float* __restrict__ mm, const float* __restrict__ vv, float* __restrict__ out) {
  int blk = blockIdx.x;              // (b*64 + cog)*4 + tile
  int tile = blk & 3;
  int cog = (blk >> 2) & 63;
  int b = blk >> 8;
  int co0 = cog * 4;
  int t = threadIdx.x;
  __shared__ float wl[256][4];
  for (int idx = t; idx < 1024; idx += 256) {
    int cof = idx >> 8;
    int ci = idx & 255;
    wl[ci][cof] = w[(co0 + cof) * 256 + ci];
  }
  __syncthreads();
  int px0 = tile * 1024 + t * 4;
  const float* tb = t1 + (size_t)b * 256 * 4096 + px0;
  float acc[4][4];
#pragma unroll
  for (int a = 0; a < 4; ++a)
#pragma unroll
    for (int jj = 0; jj < 4; ++jj) acc[a][jj] = 0.f;
  for (int ci = 0; ci < 256; ++ci) {
    float4 tv = *(const float4*)(tb + (size_t)ci * 4096);
    float4 wv = *(const float4*)&wl[ci][0];
    acc[0][0] = fmaf(tv.x, wv.x, acc[0][0]); acc[0][1] = fmaf(tv.y, wv.x, acc[0][1]);
    acc[0][2] = fmaf(tv.z, wv.x, acc[0][2]); acc[0][3] = fmaf(tv.w, wv.x, acc[0][3]);
    acc[1][0] = fmaf(tv.x, wv.y, acc[1][0]); acc[1][1] = fmaf(tv.y, wv.y, acc[1][1]);
    acc[1][2] = fmaf(tv.z, wv.y, acc[1][2]); acc[1][3] = fmaf(tv.w, wv.y, acc[1][3]);
    acc[2][0] = fmaf(tv.x, wv.z, acc[2][0]); acc[2][1] = fmaf(tv.y, wv.z, acc[2][1]);
    acc[2][2] = fmaf(tv.z, wv.z, acc[2][2]); acc[2][3] = fmaf(tv.w, wv.z, acc[2][3]);
    acc[3][0] = fmaf(tv.x, wv.w, acc[3][0]); acc[3][1] = fmaf(tv.y, wv.w, acc[3][1]);
    acc[3][2] = fmaf(tv.z, wv.w, acc[3][2]); acc[3][3] = fmaf(tv.w, wv.w, acc[3][3]);
  }
#pragma unroll
  for (int a = 0; a < 4; ++a) {
    int co = co0 + a;
    float s = g[co] * rsqrtf(vv[co] + 1e-5f);
    float bias = bb[co] - mm[co] * s;
    float4 o4;
    o4.x = fminf(fmaxf(acc[a][0] * s + bias, 0.f), 6.f);
    o4.y = fminf(fmaxf(acc[a][1] * s + bias, 0.f), 6.f);
    o4.z = fminf(fmaxf(acc[a][2] * s + bias, 0.f), 6.f);
    o4.w = fminf(fmaxf(acc[a][3] * s + bias, 0.f), 6.f);
    *(float4*)(out + ((size_t)(b * 256 + co)) * 4096 + px0) = o4;
  }
}

// ---------------- launcher ----------------
extern "C" void kernel_launch(void* const* d_in, const int* in_sizes, int n_in,
                              void* d_out, int out_size, void* d_ws, size_t ws_size,
                              hipStream_t stream) {
  if (ws_size < WS_FLOATS * sizeof(float)) return;

  const float* x      = (const float*)d_in[0];
  const float* down_w = (const float*)d_in[1];
  const float* down_b = (const float*)d_in[2];
  const float* up_w   = (const float*)d_in[3];
  const float* up_b   = (const float*)d_in[4];
  const float* cqkv_w = (const float*)d_in[5];
  const float* cqkv_b = (const float*)d_in[6];
  const float* tqkv_w = (const float*)d_in[7];
  const float* tqkv_b = (const float*)d_in[8];
  const float* dww    = (const float*)d_in[9];
  const float* bn1g   = (const float*)d_in[10];
  const float* bn1b   = (const float*)d_in[11];
  const float* bn1m   = (const float*)d_in[12];
  const float* bn1v   = (const float*)d_in[13];
  const float* pww    = (const float*)d_in[14];
  const float* bn2g   = (const float*)d_in[15];
  const float* bn2b   = (const float*)d_in[16];
  const float* bn2m   = (const float*)d_in[17];
  const float* bn2v   = (const float*)d_in[18];

  float* ws    = (float*)d_ws;
  float* att   = ws + OFF_ATT;
  float* spart = ws + OFF_SPART;
  float* score = ws + OFF_SCORE;
  int*   idx   = (int*)(ws + OFF_IDX);
  float* cout  = ws + OFF_COUT;
  float* y     = ws + OFF_Y;
  float* t1    = ws + OFF_T1;
  float* attT  = ws + OFF_SPART + 2097152;   // upper half of spart region
  unsigned short* whi  = (unsigned short*)(ws + OFF_XD);            // up-w hi
  unsigned short* wlo  = (unsigned short*)(ws + OFF_XD + 524288);   // up-w lo
  unsigned short* dwhi = (unsigned short*)(ws + OFF_SPART);             // down-w hi (dead after conv_down)
  unsigned short* dwlo = (unsigned short*)(ws + OFF_SPART + 524288);    // down-w lo
  unsigned short* xbh  = (unsigned short*)(ws + OFF_Q);   // x hi (Q..K regions, dead after conv_down)
  unsigned short* xbl  = (unsigned short*)(ws + OFF_V);   // x lo (V..ATT regions, dead after conv_down)
  unsigned short* qh   = (unsigned short*)(ws + OFF_Q);
  unsigned short* ql   = (unsigned short*)(ws + OFF_Q + 1048576);
  unsigned short* kh   = (unsigned short*)(ws + OFF_K);
  unsigned short* kl   = (unsigned short*)(ws + OFF_K + 1048576);
  unsigned short* vth  = (unsigned short*)(ws + OFF_V);
  unsigned short* vtl  = (unsigned short*)(ws + OFF_V + 1048576);
  float* coutT = ws + OFF_T1;                // t1 region dead until k_dw
  float* dpart = ws + OFF_Y;                 // 4 x 2M ci-split partials (dead until k_ybuild)

  k_x2bf<<<1024, 256, 0, stream>>>(x, xbh, xbl);
  k_wt_dnb<<<4096, 256, 0, stream>>>(down_w, dwhi, dwlo);
  k_conv_down_mfma<<<4096, 256, 0, stream>>>(xbh, xbl, dwhi, dwlo, down_b, dpart);
  k_qkv_coarse<<<32768, 192, 0, stream>>>(dpart, cqkv_w, cqkv_b, qh, ql, kh, kl, vth, vtl);
  k_wt_upb<<<4096, 256, 0, stream>>>(up_w, whi, wlo);
  k_attn_score_mfma<<<512, 256, 0, stream>>>(qh, ql, kh, kl, vth, vtl, spart, attT);
  k_score_reduce<<<128, 256, 0, stream>>>(spart, score);
  k_idx_init<<<32, 256, 0, stream>>>(idx);
  k_topk<<<32, 1024, 0, stream>>>(score, idx);
  k_conv_up_mfma<<<2048, 256, 0, stream>>>(attT, whi, wlo, up_b, cout, coutT);
  k_qkv_topk<<<32768, 192, 0, stream>>>(coutT, idx, tqkv_w, tqkv_b, qh, ql, kh, kl, vth, vtl);
  k_attn_online_mfma<<<512, 256, 0, stream>>>(qh, ql, kh, kl, vth, vtl, att);
  k_ybuild<<<32768, 256, 0, stream>>>(cout, y);
  k_scatter<<<8192, 256, 0, stream>>>(att, idx, y);
  k_dw<<<32768, 256, 0, stream>>>(y, dww, bn1g, bn1b, bn1m, bn1v, t1);
  k_pw2<<<2048, 256, 0, stream>>>(t1, pww, bn2g, bn2b, bn2m, bn2v, (float*)d_out);
}

// Round 8
// 927.792 us; speedup vs baseline: 1.8328x; 1.2824x over previous
//
#include <hip/hip_runtime.h>

typedef short short8 __attribute__((ext_vector_type(8)));
typedef float f32x4 __attribute__((ext_vector_type(4)));

__device__ inline unsigned short f32_to_bf16_rne(float f) {
  unsigned int u = __float_as_uint(f);
  unsigned int r = (u + 0x7fffu + ((u >> 16) & 1u)) >> 16;
  return (unsigned short)r;
}
__device__ inline float bf16_to_f32(unsigned short h) {
  return __uint_as_float(((unsigned int)h) << 16);
}

// ---------------- workspace layout (float offsets) ----------------
// bf16 qkv: qh/ql -> Q region, kh/kl -> K region, vth/vtl (V^T [d][j]) -> V region
// att (O, fp32) -> ATT.  spart -> SPART (+ attT at +2M)  score / idx / cout / y / t1
// aliases: whi/wlo (up-w) -> XD; dwhi/dwlo (down-w) -> SPART (dead before spart use)
//          xbh -> Q..K, xbl -> V..ATT (dead after conv_down)
//          coutT -> t1 region; dpart -> y region
constexpr size_t OFF_XD    = 0;
constexpr size_t OFF_Q     = 2097152;
constexpr size_t OFF_K     = 4194304;
constexpr size_t OFF_V     = 6291456;
constexpr size_t OFF_ATT   = 8388608;
constexpr size_t OFF_SPART = 10485760;
constexpr size_t OFF_SCORE = 14680064;
constexpr size_t OFF_IDX   = 14712832;
constexpr size_t OFF_COUT  = 14721024;
constexpr size_t OFF_Y     = 23109632;
constexpr size_t OFF_T1    = 31498240;
constexpr size_t WS_FLOATS = 39886848;

// ---------------- 0a. x NCHW -> NHWC split-bf16 (xbh/xbl [b][ih][iw][ci]) ------
__global__ __launch_bounds__(256) void k_x2bf(const float* __restrict__ x,
    unsigned short* __restrict__ xbh, unsigned short* __restrict__ xbl) {
  int bid = blockIdx.x;              // b*128 + ih*2 + iwh
  int b = bid >> 7;
  int ih = (bid >> 1) & 63;
  int iwh = bid & 1;
  int t = threadIdx.x;
  __shared__ float ts[256][33];
  for (int it = 0; it < 32; ++it) {
    int idx = it * 256 + t;
    int ci = idx >> 5;
    int iwl = idx & 31;
    ts[ci][iwl] = x[(((size_t)(b * 256 + ci) * 64 + ih) * 64) + iwh * 32 + iwl];
  }
  __syncthreads();
  int iwl = t >> 3;
  int cb = (t & 7) * 32;
  size_t base = (((size_t)(b * 64 + ih) * 64) + iwh * 32 + iwl) * 256 + cb;
#pragma unroll
  for (int j = 0; j < 32; j += 2) {
    float v0 = ts[cb + j][iwl];
    float v1 = ts[cb + j + 1][iwl];
    unsigned short h0 = f32_to_bf16_rne(v0);
    unsigned short h1 = f32_to_bf16_rne(v1);
    unsigned short l0 = f32_to_bf16_rne(v0 - bf16_to_f32(h0));
    unsigned short l1 = f32_to_bf16_rne(v1 - bf16_to_f32(h1));
    *(ushort2*)&xbh[base + j] = make_ushort2(h0, h1);
    *(ushort2*)&xbl[base + j] = make_ushort2(l0, l1);
  }
}

// ---------------- 0b. down_w -> split-bf16 dwhi/dwlo [kk][co][ci] --------------
__global__ __launch_bounds__(256) void k_wt_dnb(const float* __restrict__ w,
    unsigned short* __restrict__ dwhi, unsigned short* __restrict__ dwlo) {
  int idx = blockIdx.x * 256 + threadIdx.x;   // 1,048,576 = (kk*256+co)*256+ci
  int ci = idx & 255;
  int co = (idx >> 8) & 255;
  int kk = idx >> 16;
  float v = w[((size_t)(co * 256 + ci)) * 16 + kk];
  unsigned short h = f32_to_bf16_rne(v);
  unsigned short l = f32_to_bf16_rne(v - bf16_to_f32(h));
  dwhi[idx] = h;
  dwlo[idx] = l;
}

// ---------------- 0c. up_w -> split-bf16 whi/wlo [cls][tap][co][ci] ----------
__global__ __launch_bounds__(256) void k_wt_upb(const float* __restrict__ w,
    unsigned short* __restrict__ whi, unsigned short* __restrict__ wlo) {
  int idx = blockIdx.x * 256 + threadIdx.x;   // 1,048,576
  int ci = idx & 255;
  int co = (idx >> 8) & 255;
  int tp = idx >> 16;                         // 0..15
  int cls = tp >> 2, tap = tp & 3;
  int r = cls >> 1, s = cls & 1;
  int a_ = tap >> 1, b_ = tap & 1;
  int kh = a_ ? (r ? 2 : 3) : (r ? 0 : 1);
  int kw = b_ ? (s ? 2 : 3) : (s ? 0 : 1);
  float v = w[((size_t)(ci * 256 + co)) * 16 + kh * 4 + kw];
  unsigned short h = f32_to_bf16_rne(v);
  unsigned short l = f32_to_bf16_rne(v - bf16_to_f32(h));
  whi[idx] = h;
  wlo[idx] = l;
}

// ---------------- 1. down conv: split-bf16 MFMA implicit GEMM ------------------
__global__ __launch_bounds__(256) void k_conv_down_mfma(
    const unsigned short* __restrict__ xbh, const unsigned short* __restrict__ xbl,
    const unsigned short* __restrict__ dwhi, const unsigned short* __restrict__ dwlo,
    const float* __restrict__ bias, float* __restrict__ part) {
  int blk = blockIdx.x;              // ((ks*8 + b)*4 + ct)*32 + pt
  int pt = blk & 31;
  int ct = (blk >> 5) & 3;
  int b = (blk >> 7) & 7;
  int ks = blk >> 10;
  int oh2 = pt >> 1;                 // 0..15 (pair of oh rows)
  int owh = pt & 1;                  // ow half (16)
  int tid = threadIdx.x;
  int w = tid >> 6;                  // wave 0..3 -> co quarter
  int lane = tid & 63;
  int lq = lane >> 4;
  int lr = lane & 15;
  int co = ct * 64 + w * 16 + lr;

  __shared__ __align__(16) unsigned short AH[6][34][40];
  __shared__ __align__(16) unsigned short AL[6][34][40];

  f32x4 acc[2];
  acc[0] = (f32x4){0.f, 0.f, 0.f, 0.f};
  acc[1] = (f32x4){0.f, 0.f, 0.f, 0.f};

  int ih0 = 4 * oh2 - 1;             // tile row 0
  int iw0 = owh * 32 - 1;            // tile col 0
  const short8 zero8 = {0, 0, 0, 0, 0, 0, 0, 0};

  for (int ch = 0; ch < 2; ++ch) {
    int ci0 = ks * 64 + ch * 32;
    __syncthreads();
    for (int idx = tid; idx < 6 * 34 * 4; idx += 256) {
      int q = idx & 3;
      int cell = idx >> 2;
      int row = cell / 34;
      int col = cell - row * 34;
      int ih = ih0 + row;
      int iw = iw0 + col;
      short8 h = zero8, l = zero8;
      if ((unsigned)ih < 64u && (unsigned)iw < 64u) {
        size_t gg = (((size_t)(b * 64 + ih) * 64) + iw) * 256 + ci0 + q * 8;
        h = *(const short8*)&xbh[gg];
        l = *(const short8*)&xbl[gg];
      }
      *(short8*)&AH[row][col][q * 8] = h;
      *(short8*)&AL[row][col][q * 8] = l;
    }
    __syncthreads();
#pragma unroll
    for (int tap = 0; tap < 16; ++tap) {
      int kh = tap >> 2, kw = tap & 3;
      size_t woff = ((size_t)tap * 256 + co) * 256 + ci0 + 8 * lq;
      short8 bh = *(const short8*)&dwhi[woff];
      short8 bl = *(const short8*)&dwlo[woff];
#pragma unroll
      for (int pf = 0; pf < 2; ++pf) {
        short8 ah = *(const short8*)&AH[2 * pf + kh][2 * lr + kw][8 * lq];
        short8 al = *(const short8*)&AL[2 * pf + kh][2 * lr + kw][8 * lq];
        acc[pf] = __builtin_amdgcn_mfma_f32_16x16x32_bf16(ah, bh, acc[pf], 0, 0, 0);
        acc[pf] = __builtin_amdgcn_mfma_f32_16x16x32_bf16(al, bh, acc[pf], 0, 0, 0);
        acc[pf] = __builtin_amdgcn_mfma_f32_16x16x32_bf16(ah, bl, acc[pf], 0, 0, 0);
      }
    }
  }

  float bv = (ks == 0) ? bias[co] : 0.f;
  int bn = b * 4 + ct;
  int d = w * 16 + lr;
  float* pb = part + (size_t)ks * 2097152;
#pragma unroll
  for (int pf = 0; pf < 2; ++pf) {
    int oh = 2 * oh2 + pf;
#pragma unroll
    for (int reg = 0; reg < 4; ++reg) {
      int ow = owh * 16 + lq * 4 + reg;
      int pix = oh * 32 + ow;
      pb[((size_t)bn * 1024 + pix) * 64 + d] = acc[pf][reg] + bv;
    }
  }
}

// ---------------- 2. QKV coarse v2: 64-row tile, waves = (q,k,v), coalesced ----
// grid 512 = bn*16 + rt. LDS: ts[64][68] + Ws[192][64]; output staged via
// per-wave [64][72] u16 slabs (overlaying ts/Ws after barrier) -> coalesced
// global stores; v wave does the V^T transpose in LDS.
__global__ __launch_bounds__(192) void k_qkv_coarse(const float* __restrict__ part,
    const float* __restrict__ W, const float* __restrict__ bias,
    unsigned short* __restrict__ qh, unsigned short* __restrict__ ql,
    unsigned short* __restrict__ kh, unsigned short* __restrict__ kl,
    unsigned short* __restrict__ vth, unsigned short* __restrict__ vtl) {
  int blk = blockIdx.x;
  int bn = blk >> 4;
  int i0 = (blk & 15) * 64;
  int tid = threadIdx.x;
  int w = tid >> 6;                  // 0=q, 1=k, 2=v
  int lane = tid & 63;

  __shared__ __align__(16) char lraw[66560];
  float (*ts)[68] = (float(*)[68])lraw;                 // [64][68]
  float (*Ws)[64] = (float(*)[64])(lraw + 17408);       // [192][64]

  for (int idx = tid; idx < 1024; idx += 192) {
    int row = idx >> 4, c4 = (idx & 15) * 4;
    size_t o = ((size_t)(bn * 1024 + i0 + row)) * 64 + c4;
    float4 v0 = *(const float4*)&part[o];
    float4 v1 = *(const float4*)&part[o + 2097152];
    float4 v2 = *(const float4*)&part[o + 2 * 2097152];
    float4 v3 = *(const float4*)&part[o + 3 * 2097152];
    float4 sv = make_float4(((v0.x + v1.x) + v2.x) + v3.x,
                            ((v0.y + v1.y) + v2.y) + v3.y,
                            ((v0.z + v1.z) + v2.z) + v3.z,
                            ((v0.w + v1.w) + v2.w) + v3.w);
    *(float4*)&ts[row][c4] = sv;
  }
  for (int idx = tid; idx < 3072; idx += 192) {
    int e = idx >> 4, c4 = (idx & 15) * 4;
    *(float4*)&Ws[e][c4] = *(const float4*)&W[(size_t)e * 64 + c4];
  }
  __syncthreads();

  float t[64];
#pragma unroll
  for (int c = 0; c < 16; ++c) {
    float4 v = *(const float4*)&ts[lane][c * 4];
    t[c * 4] = v.x; t[c * 4 + 1] = v.y; t[c * 4 + 2] = v.z; t[c * 4 + 3] = v.w;
  }
  int e0 = w * 64;
  short8 ph[8], pl[8];
#pragma unroll
  for (int ec = 0; ec < 8; ++ec) {
    short8 hh, ll;
#pragma unroll
    for (int k = 0; k < 8; ++k) {
      int e = e0 + ec * 8 + k;
      float acc = bias[e];
#pragma unroll
      for (int d = 0; d < 64; ++d) acc = fmaf(t[d], Ws[e][d], acc);
      unsigned short h = f32_to_bf16_rne(acc);
      hh[k] = (short)h;
      ll[k] = (short)f32_to_bf16_rne(acc - bf16_to_f32(h));
    }
    ph[ec] = hh; pl[ec] = ll;
  }
  __syncthreads();   // all waves done reading ts/Ws -> reuse LDS for out staging
  unsigned short* outH = (unsigned short*)(lraw + w * 18432);
  unsigned short* outL = (unsigned short*)(lraw + w * 18432 + 9216);
#pragma unroll
  for (int ec = 0; ec < 8; ++ec) {
    *(short8*)&outH[lane * 72 + ec * 8] = ph[ec];
    *(short8*)&outL[lane * 72 + ec * 8] = pl[ec];
  }
  // same-wave RAW below: no barrier needed
  if (w < 2) {
    unsigned short* dh = w ? kh : qh;
    unsigned short* dl = w ? kl : ql;
#pragma unroll
    for (int k = 0; k < 8; ++k) {
      int flat = (lane + k * 64) * 8;
      int row = flat >> 6, d = flat & 63;
      size_t go = ((size_t)(bn * 1024 + i0 + row)) * 64 + d;
      *(short8*)&dh[go] = *(const short8*)&outH[row * 72 + d];
      *(short8*)&dl[go] = *(const short8*)&outL[row * 72 + d];
    }
  } else {
    int db = lane >> 3, i8 = (lane & 7) * 8;
#pragma unroll
    for (int k = 0; k < 8; ++k) {
      int dd = db + k * 8;
      short8 hh, ll;
#pragma unroll
      for (int tt = 0; tt < 8; ++tt) {
        hh[tt] = (short)outH[(i8 + tt) * 72 + dd];
        ll[tt] = (short)outL[(i8 + tt) * 72 + dd];
      }
      size_t go = ((size_t)(bn * 64 + dd)) * 1024 + i0 + i8;
      *(short8*)&vth[go] = hh;
      *(short8*)&vtl[go] = ll;
    }
  }
}

// ---------------- 3. QKV topk v2: gathered 64-row tile, same core --------------
__global__ __launch_bounds__(192) void k_qkv_topk(const float* __restrict__ coutT,
    const int* __restrict__ idxb, const float* __restrict__ W, const float* __restrict__ bias,
    unsigned short* __restrict__ qh, unsigned short* __restrict__ ql,
    unsigned short* __restrict__ kh, unsigned short* __restrict__ kl,
    unsigned short* __restrict__ vth, unsigned short* __restrict__ vtl) {
  int blk = blockIdx.x;
  int bn = blk >> 4;
  int i0 = (blk & 15) * 64;
  int tid = threadIdx.x;
  int w = tid >> 6;
  int lane = tid & 63;

  __shared__ __align__(16) char lraw[66560];
  float (*ts)[68] = (float(*)[68])lraw;
  float (*Ws)[64] = (float(*)[64])(lraw + 17408);
  __shared__ int gs[64];

  if (tid < 64) {
    int row = tid;
    int p = idxb[bn * 256 + ((i0 + row) >> 2)] & 1023;
    int a = (row >> 1) & 1, b = row & 1;
    gs[row] = ((p >> 5) * 2 + a) * 64 + (p & 31) * 2 + b;
  }
  __syncthreads();
  for (int idx = tid; idx < 1024; idx += 192) {
    int row = idx >> 4, c4 = (idx & 15) * 4;
    *(float4*)&ts[row][c4] =
        *(const float4*)&coutT[((size_t)bn * 4096 + gs[row]) * 64 + c4];
  }
  for (int idx = tid; idx < 3072; idx += 192) {
    int e = idx >> 4, c4 = (idx & 15) * 4;
    *(float4*)&Ws[e][c4] = *(const float4*)&W[(size_t)e * 64 + c4];
  }
  __syncthreads();

  float t[64];
#pragma unroll
  for (int c = 0; c < 16; ++c) {
    float4 v = *(const float4*)&ts[lane][c * 4];
    t[c * 4] = v.x; t[c * 4 + 1] = v.y; t[c * 4 + 2] = v.z; t[c * 4 + 3] = v.w;
  }
  int e0 = w * 64;
  short8 ph[8], pl[8];
#pragma unroll
  for (int ec = 0; ec < 8; ++ec) {
    short8 hh, ll;
#pragma unroll
    for (int k = 0; k < 8; ++k) {
      int e = e0 + ec * 8 + k;
      float acc = bias[e];
#pragma unroll
      for (int d = 0; d < 64; ++d) acc = fmaf(t[d], Ws[e][d], acc);
      unsigned short h = f32_to_bf16_rne(acc);
      hh[k] = (short)h;
      ll[k] = (short)f32_to_bf16_rne(acc - bf16_to_f32(h));
    }
    ph[ec] = hh; pl[ec] = ll;
  }
  __syncthreads();
  unsigned short* outH = (unsigned short*)(lraw + w * 18432);
  unsigned short* outL = (unsigned short*)(lraw + w * 18432 + 9216);
#pragma unroll
  for (int ec = 0; ec < 8; ++ec) {
    *(short8*)&outH[lane * 72 + ec * 8] = ph[ec];
    *(short8*)&outL[lane * 72 + ec * 8] = pl[ec];
  }
  if (w < 2) {
    unsigned short* dh = w ? kh : qh;
    unsigned short* dl = w ? kl : ql;
#pragma unroll
    for (int k = 0; k < 8; ++k) {
      int flat = (lane + k * 64) * 8;
      int row = flat >> 6, d = flat & 63;
      size_t go = ((size_t)(bn * 1024 + i0 + row)) * 64 + d;
      *(short8*)&dh[go] = *(const short8*)&outH[row * 72 + d];
      *(short8*)&dl[go] = *(const short8*)&outL[row * 72 + d];
    }
  } else {
    int db = lane >> 3, i8 = (lane & 7) * 8;
#pragma unroll
    for (int k = 0; k < 8; ++k) {
      int dd = db + k * 8;
      short8 hh, ll;
#pragma unroll
      for (int tt = 0; tt < 8; ++tt) {
        hh[tt] = (short)outH[(i8 + tt) * 72 + dd];
        ll[tt] = (short)outL[(i8 + tt) * 72 + dd];
      }
      size_t go = ((size_t)(bn * 64 + dd)) * 1024 + i0 + i8;
      *(short8*)&vth[go] = hh;
      *(short8*)&vtl[go] = ll;
    }
  }
}

// ---------------- 4a. attention+score, split-bf16 MFMA (2-pass) ----------------
// LDS-staged Q/V per jt (coop, shared by all 4 waves); XCD swizzle: bn = blk&31
// so same-bn blocks land on the same XCD L2 (stride-32 block indices).
__global__ __launch_bounds__(256) void k_attn_score_mfma(
    const unsigned short* __restrict__ qh, const unsigned short* __restrict__ ql,
    const unsigned short* __restrict__ kh, const unsigned short* __restrict__ kl,
    const unsigned short* __restrict__ vth, const unsigned short* __restrict__ vtl,
    float* __restrict__ spart, float* __restrict__ attT) {
  int blk = blockIdx.x;
  int bn = blk & 31;                 // XCD-locality: same bn -> idx ≡ bn (mod 8)
  int it = blk >> 5;
  int tid = threadIdx.x;
  int w = tid >> 6;
  int lane = tid & 63;
  int g = lane >> 4;
  int c = lane & 15;
  size_t qb = (size_t)bn << 16;      // *65536 (u16 elements)

  __shared__ __align__(16) unsigned short QH[64][72];
  __shared__ __align__(16) unsigned short QL[64][72];
  __shared__ __align__(16) unsigned short VH[64][72];
  __shared__ __align__(16) unsigned short VL[64][72];
  __shared__ __align__(16) unsigned short PH[64][72];
  __shared__ __align__(16) unsigned short PL[64][72];
  __shared__ float sacc[1024];
  for (int i2 = tid; i2 < 1024; i2 += 256) sacc[i2] = 0.f;

  int r0 = tid >> 3;                 // staging row 0..31
  int c8 = (tid & 7) * 8;            // staging col (u16)

  // K A-frags for this wave's 16 rows (A row = lane&15)
  int irow = it * 64 + w * 16 + c;
  short8 kfh[2], kfl[2];
#pragma unroll
  for (int ch = 0; ch < 2; ++ch) {
    kfh[ch] = *(const short8*)&kh[qb + (size_t)irow * 64 + ch * 32 + g * 8];
    kfl[ch] = *(const short8*)&kl[qb + (size_t)irow * 64 + ch * 32 + g * 8];
  }

  float m[4], lsum[4];
#pragma unroll
  for (int r = 0; r < 4; ++r) { m[r] = -3.0e38f; lsum[r] = 0.f; }

  // ---- pass 1: row max / denom (Q staged in LDS per jt) ----
  for (int jt = 0; jt < 16; ++jt) {
    __syncthreads();
#pragma unroll
    for (int rr = 0; rr < 2; ++rr) {
      int row = r0 + rr * 32;
      size_t go = qb + (size_t)(jt * 64 + row) * 64 + c8;
      *(short8*)&QH[row][c8] = *(const short8*)&qh[go];
      *(short8*)&QL[row][c8] = *(const short8*)&ql[go];
    }
    __syncthreads();
    f32x4 s[4];
#pragma unroll
    for (int su = 0; su < 4; ++su) s[su] = (f32x4){0.f, 0.f, 0.f, 0.f};
#pragma unroll
    for (int ch = 0; ch < 2; ++ch)
#pragma unroll
      for (int su = 0; su < 4; ++su) {
        short8 qfh = *(const short8*)&QH[su * 16 + c][ch * 32 + g * 8];
        short8 qfl = *(const short8*)&QL[su * 16 + c][ch * 32 + g * 8];
        s[su] = __builtin_amdgcn_mfma_f32_16x16x32_bf16(kfh[ch], qfh, s[su], 0, 0, 0);
        s[su] = __builtin_amdgcn_mfma_f32_16x16x32_bf16(kfl[ch], qfh, s[su], 0, 0, 0);
        s[su] = __builtin_amdgcn_mfma_f32_16x16x32_bf16(kfh[ch], qfl, s[su], 0, 0, 0);
      }
#pragma unroll
    for (int r = 0; r < 4; ++r) {
      float tm = fmaxf(fmaxf(s[0][r], s[1][r]), fmaxf(s[2][r], s[3][r]));
#pragma unroll
      for (int off = 1; off <= 8; off <<= 1) tm = fmaxf(tm, __shfl_xor(tm, off, 64));
      float mn = fmaxf(m[r], tm);
      float ts = ((expf(s[0][r] - mn) + expf(s[1][r] - mn)) +
                  expf(s[2][r] - mn)) + expf(s[3][r] - mn);
#pragma unroll
      for (int off = 1; off <= 8; off <<= 1) ts += __shfl_xor(ts, off, 64);
      lsum[r] = lsum[r] * expf(m[r] - mn) + ts;
      m[r] = mn;
    }
  }
  float inv[4];
#pragma unroll
  for (int r = 0; r < 4; ++r) inv[r] = 1.f / lsum[r];

  f32x4 oacc[4];
#pragma unroll
  for (int d = 0; d < 4; ++d) oacc[d] = (f32x4){0.f, 0.f, 0.f, 0.f};

  // ---- pass 2: P, scores, PV (Q+V staged in LDS per jt) ----
  for (int jt = 0; jt < 16; ++jt) {
    __syncthreads();
#pragma unroll
    for (int rr = 0; rr < 2; ++rr) {
      int row = r0 + rr * 32;
      size_t go = qb + (size_t)(jt * 64 + row) * 64 + c8;
      *(short8*)&QH[row][c8] = *(const short8*)&qh[go];
      *(short8*)&QL[row][c8] = *(const short8*)&ql[go];
      size_t vo = ((size_t)(bn * 64 + row)) * 1024 + jt * 64 + c8;
      *(short8*)&VH[row][c8] = *(const short8*)&vth[vo];
      *(short8*)&VL[row][c8] = *(const short8*)&vtl[vo];
    }
    __syncthreads();
    f32x4 s[4];
#pragma unroll
    for (int su = 0; su < 4; ++su) s[su] = (f32x4){0.f, 0.f, 0.f, 0.f};
#pragma unroll
    for (int ch = 0; ch < 2; ++ch)
#pragma unroll
      for (int su = 0; su < 4; ++su) {
        short8 qfh = *(const short8*)&QH[su * 16 + c][ch * 32 + g * 8];
        short8 qfl = *(const short8*)&QL[su * 16 + c][ch * 32 + g * 8];
        s[su] = __builtin_amdgcn_mfma_f32_16x16x32_bf16(kfh[ch], qfh, s[su], 0, 0, 0);
        s[su] = __builtin_amdgcn_mfma_f32_16x16x32_bf16(kfl[ch], qfh, s[su], 0, 0, 0);
        s[su] = __builtin_amdgcn_mfma_f32_16x16x32_bf16(kfh[ch], qfl, s[su], 0, 0, 0);
      }
#pragma unroll
    for (int su = 0; su < 4; ++su) {
      float p0 = expf(s[su][0] - m[0]) * inv[0];
      float p1 = expf(s[su][1] - m[1]) * inv[1];
      float p2 = expf(s[su][2] - m[2]) * inv[2];
      float p3 = expf(s[su][3] - m[3]) * inv[3];
      float cs = ((p0 + p1) + p2) + p3;
      cs += __shfl_xor(cs, 16, 64);
      cs += __shfl_xor(cs, 32, 64);
      if (g == 0) atomicAdd(&sacc[jt * 64 + su * 16 + c], cs);
      unsigned short h0 = f32_to_bf16_rne(p0);
      unsigned short h1 = f32_to_bf16_rne(p1);
      unsigned short h2 = f32_to_bf16_rne(p2);
      unsigned short h3 = f32_to_bf16_rne(p3);
      PH[w * 16 + g * 4 + 0][su * 16 + c] = h0;
      PH[w * 16 + g * 4 + 1][su * 16 + c] = h1;
      PH[w * 16 + g * 4 + 2][su * 16 + c] = h2;
      PH[w * 16 + g * 4 + 3][su * 16 + c] = h3;
      PL[w * 16 + g * 4 + 0][su * 16 + c] = f32_to_bf16_rne(p0 - bf16_to_f32(h0));
      PL[w * 16 + g * 4 + 1][su * 16 + c] = f32_to_bf16_rne(p1 - bf16_to_f32(h1));
      PL[w * 16 + g * 4 + 2][su * 16 + c] = f32_to_bf16_rne(p2 - bf16_to_f32(h2));
      PL[w * 16 + g * 4 + 3][su * 16 + c] = f32_to_bf16_rne(p3 - bf16_to_f32(h3));
    }
#pragma unroll
    for (int ch = 0; ch < 2; ++ch) {
      short8 pfh = *(const short8*)&PH[w * 16 + c][ch * 32 + g * 8];
      short8 pfl = *(const short8*)&PL[w * 16 + c][ch * 32 + g * 8];
#pragma unroll
      for (int d = 0; d < 4; ++d) {
        short8 vfh = *(const short8*)&VH[d * 16 + c][ch * 32 + g * 8];
        short8 vfl = *(const short8*)&VL[d * 16 + c][ch * 32 + g * 8];
        oacc[d] = __builtin_amdgcn_mfma_f32_16x16x32_bf16(vfh, pfh, oacc[d], 0, 0, 0);
        oacc[d] = __builtin_amdgcn_mfma_f32_16x16x32_bf16(vfl, pfh, oacc[d], 0, 0, 0);
        oacc[d] = __builtin_amdgcn_mfma_f32_16x16x32_bf16(vfh, pfl, oacc[d], 0, 0, 0);
      }
    }
  }
  // O^T D-layout: lane holds O^T[d = d*16 + g*4 + reg][i = it*64 + w*16 + c]
#pragma unroll
  for (int d = 0; d < 4; ++d)
#pragma unroll
    for (int r = 0; r < 4; ++r)
      attT[((size_t)bn * 64 + d * 16 + g * 4 + r) * 1024 + it * 64 + w * 16 + c] =
          oacc[d][r];
  __syncthreads();
  for (int i2 = tid; i2 < 1024; i2 += 256)
    spart[((size_t)bn * 16 + it) * 1024 + i2] = sacc[i2];
}

// ---------------- 4b. topk attention, split-bf16 MFMA (1-pass online) ----------
__global__ __launch_bounds__(256) void k_attn_online_mfma(
    const unsigned short* __restrict__ qh, const unsigned short* __restrict__ ql,
    const unsigned short* __restrict__ kh, const unsigned short* __restrict__ kl,
    const unsigned short* __restrict__ vth, const unsigned short* __restrict__ vtl,
    float* __restrict__ O) {
  int blk = blockIdx.x;
  int bn = blk & 31;                 // XCD-locality swizzle
  int it = blk >> 5;
  int tid = threadIdx.x;
  int w = tid >> 6;
  int lane = tid & 63;
  int g = lane >> 4;
  int c = lane & 15;
  size_t qb = (size_t)bn << 16;

  __shared__ __align__(16) unsigned short QH[64][72];
  __shared__ __align__(16) unsigned short QL[64][72];
  __shared__ __align__(16) unsigned short VH[64][72];
  __shared__ __align__(16) unsigned short VL[64][72];
  __shared__ __align__(16) unsigned short PH[64][72];
  __shared__ __align__(16) unsigned short PL[64][72];

  int r0 = tid >> 3;
  int c8 = (tid & 7) * 8;

  int irow = it * 64 + w * 16 + c;
  short8 kfh[2], kfl[2];
#pragma unroll
  for (int ch = 0; ch < 2; ++ch) {
    kfh[ch] = *(const short8*)&kh[qb + (size_t)irow * 64 + ch * 32 + g * 8];
    kfl[ch] = *(const short8*)&kl[qb + (size_t)irow * 64 + ch * 32 + g * 8];
  }

  float m[4], lsum[4];
  f32x4 oacc[4];
#pragma unroll
  for (int r = 0; r < 4; ++r) { m[r] = -3.0e38f; lsum[r] = 0.f; }
#pragma unroll
  for (int d = 0; d < 4; ++d) oacc[d] = (f32x4){0.f, 0.f, 0.f, 0.f};

  for (int jt = 0; jt < 16; ++jt) {
    __syncthreads();
#pragma unroll
    for (int rr = 0; rr < 2; ++rr) {
      int row = r0 + rr * 32;
      size_t go = qb + (size_t)(jt * 64 + row) * 64 + c8;
      *(short8*)&QH[row][c8] = *(const short8*)&qh[go];
      *(short8*)&QL[row][c8] = *(const short8*)&ql[go];
      size_t vo = ((size_t)(bn * 64 + row)) * 1024 + jt * 64 + c8;
      *(short8*)&VH[row][c8] = *(const short8*)&vth[vo];
      *(short8*)&VL[row][c8] = *(const short8*)&vtl[vo];
    }
    __syncthreads();
    f32x4 s[4];
#pragma unroll
    for (int su = 0; su < 4; ++su) s[su] = (f32x4){0.f, 0.f, 0.f, 0.f};
#pragma unroll
    for (int ch = 0; ch < 2; ++ch)
#pragma unroll
      for (int su = 0; su < 4; ++su) {
        short8 qfh = *(const short8*)&QH[su * 16 + c][ch * 32 + g * 8];
        short8 qfl = *(const short8*)&QL[su * 16 + c][ch * 32 + g * 8];
        s[su] = __builtin_amdgcn_mfma_f32_16x16x32_bf16(kfh[ch], qfh, s[su], 0, 0, 0);
        s[su] = __builtin_amdgcn_mfma_f32_16x16x32_bf16(kfl[ch], qfh, s[su], 0, 0, 0);
        s[su] = __builtin_amdgcn_mfma_f32_16x16x32_bf16(kfh[ch], qfl, s[su], 0, 0, 0);
      }
    float sc[4];
#pragma unroll
    for (int r = 0; r < 4; ++r) {
      float tm = fmaxf(fmaxf(s[0][r], s[1][r]), fmaxf(s[2][r], s[3][r]));
#pragma unroll
      for (int off = 1; off <= 8; off <<= 1) tm = fmaxf(tm, __shfl_xor(tm, off, 64));
      float mn = fmaxf(m[r], tm);
      sc[r] = expf(m[r] - mn);
      float p0 = expf(s[0][r] - mn);
      float p1 = expf(s[1][r] - mn);
      float p2 = expf(s[2][r] - mn);
      float p3 = expf(s[3][r] - mn);
      s[0][r] = p0; s[1][r] = p1; s[2][r] = p2; s[3][r] = p3;
      float ts = ((p0 + p1) + p2) + p3;
#pragma unroll
      for (int off = 1; off <= 8; off <<= 1) ts += __shfl_xor(ts, off, 64);
      lsum[r] = lsum[r] * sc[r] + ts;
      m[r] = mn;
    }
#pragma unroll
    for (int su = 0; su < 4; ++su) {
      unsigned short h0 = f32_to_bf16_rne(s[su][0]);
      unsigned short h1 = f32_to_bf16_rne(s[su][1]);
      unsigned short h2 = f32_to_bf16_rne(s[su][2]);
      unsigned short h3 = f32_to_bf16_rne(s[su][3]);
      PH[w * 16 + g * 4 + 0][su * 16 + c] = h0;
      PH[w * 16 + g * 4 + 1][su * 16 + c] = h1;
      PH[w * 16 + g * 4 + 2][su * 16 + c] = h2;
      PH[w * 16 + g * 4 + 3][su * 16 + c] = h3;
      PL[w * 16 + g * 4 + 0][su * 16 + c] = f32_to_bf16_rne(s[su][0] - bf16_to_f32(h0));
      PL[w * 16 + g * 4 + 1][su * 16 + c] = f32_to_bf16_rne(s[su][1] - bf16_to_f32(h1));
      PL[w * 16 + g * 4 + 2][su * 16 + c] = f32_to_bf16_rne(s[su][2] - bf16_to_f32(h2));
      PL[w * 16 + g * 4 + 3][su * 16 + c] = f32_to_bf16_rne(s[su][3] - bf16_to_f32(h3));
    }
    // rescale oacc by sc for col i=c (branchless select + shfl, rule #20 safe)
    float s01 = (c & 1) ? sc[1] : sc[0];
    float s23 = (c & 1) ? sc[3] : sc[2];
    float tmp = (c & 2) ? s23 : s01;
    float scc = __shfl(tmp, ((c >> 2) << 4) | c, 64);
#pragma unroll
    for (int d = 0; d < 4; ++d) oacc[d] *= scc;
#pragma unroll
    for (int ch = 0; ch < 2; ++ch) {
      short8 pfh = *(const short8*)&PH[w * 16 + c][ch * 32 + g * 8];
      short8 pfl = *(const short8*)&PL[w * 16 + c][ch * 32 + g * 8];
#pragma unroll
      for (int d = 0; d < 4; ++d) {
        short8 vfh = *(const short8*)&VH[d * 16 + c][ch * 32 + g * 8];
        short8 vfl = *(const short8*)&VL[d * 16 + c][ch * 32 + g * 8];
        oacc[d] = __builtin_amdgcn_mfma_f32_16x16x32_bf16(vfh, pfh, oacc[d], 0, 0, 0);
        oacc[d] = __builtin_amdgcn_mfma_f32_16x16x32_bf16(vfl, pfh, oacc[d], 0, 0, 0);
        oacc[d] = __builtin_amdgcn_mfma_f32_16x16x32_bf16(vfh, pfl, oacc[d], 0, 0, 0);
      }
    }
  }
  float i01 = (c & 1) ? (1.f / lsum[1]) : (1.f / lsum[0]);
  float i23 = (c & 1) ? (1.f / lsum[3]) : (1.f / lsum[2]);
  float itmp = (c & 2) ? i23 : i01;
  float invc = __shfl(itmp, ((c >> 2) << 4) | c, 64);
  // O natural [i][d]: lane col i = it*64+w*16+c; rows d = d*16+g*4+reg (contig f32x4)
#pragma unroll
  for (int d = 0; d < 4; ++d) {
    f32x4 o4 = oacc[d] * invc;
    *(f32x4*)&O[((size_t)bn * 1024 + it * 64 + w * 16 + c) * 64 + d * 16 + g * 4] = o4;
  }
}

// ---------------- 5. deterministic score reduction (16 partials) ----------------
__global__ __launch_bounds__(256) void k_score_reduce(const float* __restrict__ part,
                                                      float* __restrict__ score) {
  int j = blockIdx.x * 256 + threadIdx.x;   // 0..32767
  int bn = j >> 10, jj = j & 1023;
  float s = 0.f;
  for (int g = 0; g < 16; ++g) s += part[((size_t)bn * 16 + g) * 1024 + jj];
  score[j] = s;
}

// ---------------- 5b. default-init idx ----------------
__global__ __launch_bounds__(256) void k_idx_init(int* __restrict__ idx) {
  int j = blockIdx.x * 256 + threadIdx.x;
  idx[j] = j & 255;
}

// ---------------- 6. top-K by rank ----------------
__global__ __launch_bounds__(1024) void k_topk(const float* __restrict__ score,
                                               int* __restrict__ idxout) {
  int bn = blockIdx.x;
  int t = threadIdx.x;
  __shared__ float s[1024];
  s[t] = score[bn * 1024 + t];
  __syncthreads();
  float my = s[t];
  int rank = 0;
  for (int j = 0; j < 1024; ++j) {
    float o = s[j];
    rank += (o > my) || (o == my && j < t);
  }
  if (rank < 256) idxout[bn * 256 + rank] = t;
}

// ---------------- 7. transposed conv: split-bf16 MFMA implicit GEMM -----------
__global__ __launch_bounds__(256) void k_conv_up_mfma(
    const float* __restrict__ attT, const unsigned short* __restrict__ whi,
    const unsigned short* __restrict__ wlo, const float* __restrict__ bias,
    float* __restrict__ cout, float* __restrict__ coutT) {
  int blk = blockIdx.x;              // ((b*4 + cls)*16 + pt)*4 + ct
  int ct = blk & 3;
  int pt = (blk >> 2) & 15;
  int cls = (blk >> 6) & 3;
  int b = blk >> 8;
  int r = cls >> 1, s = cls & 1;
  int Ib = pt * 2;
  int co0 = ct * 64;
  int tid = threadIdx.x;
  int w = tid >> 6;                  // wave 0..3
  int lane = tid & 63;
  int lq = lane >> 4;                // quarter 0..3
  int lr = lane & 15;
  int wr = w >> 1;                   // I-row within tile
  int wc = w & 1;                    // co half
  int co0w = co0 + wc * 32;

  __shared__ __align__(16) unsigned short AH[3][33][40];
  __shared__ __align__(16) unsigned short AL[3][33][40];

  f32x4 acc[2][2];
#pragma unroll
  for (int pf = 0; pf < 2; ++pf)
#pragma unroll
    for (int cf = 0; cf < 2; ++cf) acc[pf][cf] = (f32x4){0.f, 0.f, 0.f, 0.f};

  const float* ab = attT + (size_t)b * 4 * 65536;
  int ih_base = Ib + r - 1;
  int iw_base = s - 1;

  for (int ci0 = 0; ci0 < 256; ci0 += 32) {
    int n = ci0 >> 6, d0 = ci0 & 63;
    __syncthreads();
    for (int idx = tid; idx < 3168; idx += 256) {
      int ciL = idx / 99;            // 0..31
      int rem = idx - ciL * 99;
      int rho = rem / 33;
      int c = rem - rho * 33;
      int ih = ih_base + rho;
      int iw = iw_base + c;
      float v = 0.f;
      if ((unsigned)ih < 32u && (unsigned)iw < 32u)
        v = ab[((size_t)n * 64 + d0 + ciL) * 1024 + ih * 32 + iw];
      unsigned short h = f32_to_bf16_rne(v);
      unsigned short lo = f32_to_bf16_rne(v - bf16_to_f32(h));
      AH[rho][c][ciL] = h;
      AL[rho][c][ciL] = lo;
    }
    __syncthreads();
#pragma unroll
    for (int tap = 0; tap < 4; ++tap) {
      int a_ = tap >> 1, b_ = tap & 1;
      int rho = wr + 1 - a_;
      short8 ah[2], al[2];
#pragma unroll
      for (int pf = 0; pf < 2; ++pf) {
        int col = pf * 16 + lr + 1 - b_;
        ah[pf] = *(const short8*)&AH[rho][col][8 * lq];
        al[pf] = *(const short8*)&AL[rho][col][8 * lq];
      }
      size_t wb = (size_t)(cls * 4 + tap) * 65536;
      short8 bh[2], bl[2];
#pragma unroll
      for (int cf = 0; cf < 2; ++cf) {
        size_t off = wb + (size_t)(co0w + cf * 16 + lr) * 256 + ci0 + 8 * lq;
        bh[cf] = *(const short8*)&whi[off];
        bl[cf] = *(const short8*)&wlo[off];
      }
#pragma unroll
      for (int pf = 0; pf < 2; ++pf)
#pragma unroll
        for (int cf = 0; cf < 2; ++cf) {
          acc[pf][cf] = __builtin_amdgcn_mfma_f32_16x16x32_bf16(ah[pf], bh[cf], acc[pf][cf], 0, 0, 0);
          acc[pf][cf] = __builtin_amdgcn_mfma_f32_16x16x32_bf16(al[pf], bh[cf], acc[pf][cf], 0, 0, 0);
          acc[pf][cf] = __builtin_amdgcn_mfma_f32_16x16x32_bf16(ah[pf], bl[cf], acc[pf][cf], 0, 0, 0);
        }
    }
  }

  int I = Ib + wr;
  int oh = 2 * I + r;
#pragma unroll
  for (int pf = 0; pf < 2; ++pf)
#pragma unroll
    for (int cf = 0; cf < 2; ++cf) {
      int co = co0w + cf * 16 + lr;
      float bv = bias[co];
      size_t cbase = ((size_t)b * 256 + co) * 4096 + oh * 64;
      size_t tbase = ((size_t)(b * 4 + (co >> 6)) * 4096 + oh * 64);
#pragma unroll
      for (int qd = 0; qd < 4; ++qd) {
        int J = pf * 16 + lq * 4 + qd;
        int ow = 2 * J + s;
        float val = acc[pf][cf][qd] + bv;
        cout[cbase + ow] = val;
        coutT[(tbase + ow) * 64 + (co & 63)] = val;
      }
    }
}

// ---------------- 8. y = coarse_out + region ----------------
__global__ __launch_bounds__(256) void k_ybuild(const float* __restrict__ cout,
                                                float* __restrict__ y) {
  size_t e = (size_t)blockIdx.x * 256 + threadIdx.x;
  int flat = (int)(e & 4095);
  size_t bc = e >> 12;
  int p = flat >> 2, ab = flat & 3;
  int a = ab >> 1, bi = ab & 1;
  int src = ((p >> 5) * 2 + a) * 64 + (p & 31) * 2 + bi;
  const float* cb = cout + bc * 4096;
  y[e] = cb[flat] + cb[src];
}

// ---------------- 9. scatter-add attended tokens ----------------
__global__ __launch_bounds__(256) void k_scatter(const float* __restrict__ out2,
    const int* __restrict__ idx, float* __restrict__ y) {
  int e = blockIdx.x * 256 + threadIdx.x;
  int d = e & 63;
  int r = e >> 6;
  int ab = r & 3;
  int r2 = r >> 2;
  int kk = r2 & 255;
  int bn = r2 >> 8;
  int b = bn >> 2, n = bn & 3;
  int p = idx[bn * 256 + kk] & 1023;
  int flat = p * 4 + ab;
  int t = kk * 4 + ab;
  y[((size_t)(b * 256 + n * 64 + d)) * 4096 + flat] +=
      out2[((size_t)bn * 1024 + t) * 64 + d];
}

// ---------------- 10. depthwise 3x3 + BN + relu6 ----------------
__global__ __launch_bounds__(256) void k_dw(const float* __restrict__ y,
    const float* __restrict__ w, const float* __restrict__ g, const float* __restrict__ bb,
    const float* __restrict__ mm, const float* __restrict__ vv, float* __restrict__ t1) {
  size_t e = (size_t)blockIdx.x * 256 + threadIdx.x;
  int pix = (int)(e & 4095);
  int c = (int)((e >> 12) & 255);
  int oh = pix >> 6, ow = pix & 63;
  const float* yb = y + (e - pix);
  float acc = 0.f;
#pragma unroll
  for (int kh = 0; kh < 3; ++kh) {
    int ih = oh - 1 + kh;
    if ((unsigned)ih >= 64u) continue;
#pragma unroll
    for (int kw = 0; kw < 3; ++kw) {
      int iw = ow - 1 + kw;
      if ((unsigned)iw >= 64u) continue;
      acc = fmaf(yb[ih * 64 + iw], w[c * 9 + kh * 3 + kw], acc);
    }
  }
  float s = g[c] * rsqrtf(vv[c] + 1e-5f);
  float val = acc * s + (bb[c] - mm[c] * s);
  t1[e] = fminf(fmaxf(val, 0.f), 6.f);
}

// ---------------- 11. pointwise v2: 4 co per block, 16 FMA per 16B load --------
__global__ __launch_bounds__(256) void k_pw2(const float* __restrict__ t1,
    const float* __restrict__ w, const float* __restrict__ g, const float* __restrict__ bb,
    const float* __restrict__ mm, const float* __restrict__ vv, float* __restrict__ out) {
  int blk = blockIdx.x;              // (b*64 + cog)*4 + tile
  int tile = blk & 3;
  int cog = (blk >> 2) & 63;
  int b = blk >> 8;
  int co0 = cog * 4;
  int t = threadIdx.x;
  __shared__ float wl[256][4];
  for (int idx = t; idx < 1024; idx += 256) {
    int cof = idx >> 8;
    int ci = idx & 255;
    wl[ci][cof] = w[(co0 + cof) * 256 + ci];
  }
  __syncthreads();
  int px0 = tile * 1024 + t * 4;
  const float* tb = t1 + (size_t)b * 256 * 4096 + px0;
  float acc[4][4];
#pragma unroll
  for (int a = 0; a < 4; ++a)
#pragma unroll
    for (int jj = 0; jj < 4; ++jj) acc[a][jj] = 0.f;
  for (int ci = 0; ci < 256; ++ci) {
    float4 tv = *(const float4*)(tb + (size_t)ci * 4096);
    float4 wv = *(const float4*)&wl[ci][0];
    acc[0][0] = fmaf(tv.x, wv.x, acc[0][0]); acc[0][1] = fmaf(tv.y, wv.x, acc[0][1]);
    acc[0][2] = fmaf(tv.z, wv.x, acc[0][2]); acc[0][3] = fmaf(tv.w, wv.x, acc[0][3]);
    acc[1][0] = fmaf(tv.x, wv.y, acc[1][0]); acc[1][1] = fmaf(tv.y, wv.y, acc[1][1]);
    acc[1][2] = fmaf(tv.z, wv.y, acc[1][2]); acc[1][3] = fmaf(tv.w, wv.y, acc[1][3]);
    acc[2][0] = fmaf(tv.x, wv.z, acc[2][0]); acc[2][1] = fmaf(tv.y, wv.z, acc[2][1]);
    acc[2][2] = fmaf(tv.z, wv.z, acc[2][2]); acc[2][3] = fmaf(tv.w, wv.z, acc[2][3]);
    acc[3][0] = fmaf(tv.x, wv.w, acc[3][0]); acc[3][1] = fmaf(tv.y, wv.w, acc[3][1]);
    acc[3][2] = fmaf(tv.z, wv.w, acc[3][2]); acc[3][3] = fmaf(tv.w, wv.w, acc[3][3]);
  }
#pragma unroll
  for (int a = 0; a < 4; ++a) {
    int co = co0 + a;
    float s = g[co] * rsqrtf(vv[co] + 1e-5f);
    float bias = bb[co] - mm[co] * s;
    float4 o4;
    o4.x = fminf(fmaxf(acc[a][0] * s + bias, 0.f), 6.f);
    o4.y = fminf(fmaxf(acc[a][1] * s + bias, 0.f), 6.f);
    o4.z = fminf(fmaxf(acc[a][2] * s + bias, 0.f), 6.f);
    o4.w = fminf(fmaxf(acc[a][3] * s + bias, 0.f), 6.f);
    *(float4*)(out + ((size_t)(b * 256 + co)) * 4096 + px0) = o4;
  }
}

// ---------------- launcher ----------------
extern "C" void kernel_launch(void* const* d_in, const int* in_sizes, int n_in,
                              void* d_out, int out_size, void* d_ws, size_t ws_size,
                              hipStream_t stream) {
  if (ws_size < WS_FLOATS * sizeof(float)) return;

  const float* x      = (const float*)d_in[0];
  const float* down_w = (const float*)d_in[1];
  const float* down_b = (const float*)d_in[2];
  const float* up_w   = (const float*)d_in[3];
  const float* up_b   = (const float*)d_in[4];
  const float* cqkv_w = (const float*)d_in[5];
  const float* cqkv_b = (const float*)d_in[6];
  const float* tqkv_w = (const float*)d_in[7];
  const float* tqkv_b = (const float*)d_in[8];
  const float* dww    = (const float*)d_in[9];
  const float* bn1g   = (const float*)d_in[10];
  const float* bn1b   = (const float*)d_in[11];
  const float* bn1m   = (const float*)d_in[12];
  const float* bn1v   = (const float*)d_in[13];
  const float* pww    = (const float*)d_in[14];
  const float* bn2g   = (const float*)d_in[15];
  const float* bn2b   = (const float*)d_in[16];
  const float* bn2m   = (const float*)d_in[17];
  const float* bn2v   = (const float*)d_in[18];

  float* ws    = (float*)d_ws;
  float* att   = ws + OFF_ATT;
  float* spart = ws + OFF_SPART;
  float* score = ws + OFF_SCORE;
  int*   idx   = (int*)(ws + OFF_IDX);
  float* cout  = ws + OFF_COUT;
  float* y     = ws + OFF_Y;
  float* t1    = ws + OFF_T1;
  float* attT  = ws + OFF_SPART + 2097152;   // upper half of spart region
  unsigned short* whi  = (unsigned short*)(ws + OFF_XD);            // up-w hi
  unsigned short* wlo  = (unsigned short*)(ws + OFF_XD + 524288);   // up-w lo
  unsigned short* dwhi = (unsigned short*)(ws + OFF_SPART);             // down-w hi (dead after conv_down)
  unsigned short* dwlo = (unsigned short*)(ws + OFF_SPART + 524288);    // down-w lo
  unsigned short* xbh  = (unsigned short*)(ws + OFF_Q);   // x hi (Q..K regions, dead after conv_down)
  unsigned short* xbl  = (unsigned short*)(ws + OFF_V);   // x lo (V..ATT regions, dead after conv_down)
  unsigned short* qh   = (unsigned short*)(ws + OFF_Q);
  unsigned short* ql   = (unsigned short*)(ws + OFF_Q + 1048576);
  unsigned short* kh   = (unsigned short*)(ws + OFF_K);
  unsigned short* kl   = (unsigned short*)(ws + OFF_K + 1048576);
  unsigned short* vth  = (unsigned short*)(ws + OFF_V);
  unsigned short* vtl  = (unsigned short*)(ws + OFF_V + 1048576);
  float* coutT = ws + OFF_T1;                // t1 region dead until k_dw
  float* dpart = ws + OFF_Y;                 // 4 x 2M ci-split partials (dead until k_ybuild)

  k_x2bf<<<1024, 256, 0, stream>>>(x, xbh, xbl);
  k_wt_dnb<<<4096, 256, 0, stream>>>(down_w, dwhi, dwlo);
  k_conv_down_mfma<<<4096, 256, 0, stream>>>(xbh, xbl, dwhi, dwlo, down_b, dpart);
  k_qkv_coarse<<<512, 192, 0, stream>>>(dpart, cqkv_w, cqkv_b, qh, ql, kh, kl, vth, vtl);
  k_wt_upb<<<4096, 256, 0, stream>>>(up_w, whi, wlo);
  k_attn_score_mfma<<<512, 256, 0, stream>>>(qh, ql, kh, kl, vth, vtl, spart, attT);
  k_score_reduce<<<128, 256, 0, stream>>>(spart, score);
  k_idx_init<<<32, 256, 0, stream>>>(idx);
  k_topk<<<32, 1024, 0, stream>>>(score, idx);
  k_conv_up_mfma<<<2048, 256, 0, stream>>>(attT, whi, wlo, up_b, cout, coutT);
  k_qkv_topk<<<512, 192, 0, stream>>>(coutT, idx, tqkv_w, tqkv_b, qh, ql, kh, kl, vth, vtl);
  k_attn_online_mfma<<<512, 256, 0, stream>>>(qh, ql, kh, kl, vth, vtl, att);
  k_ybuild<<<32768, 256, 0, stream>>>(cout, y);
  k_scatter<<<8192, 256, 0, stream>>>(att, idx, y);
  k_dw<<<32768, 256, 0, stream>>>(y, dww, bn1g, bn1b, bn1m, bn1v, t1);
  k_pw2<<<2048, 256, 0, stream>>>(t1, pww, bn2g, bn2b, bn2m, bn2v, (float*)d_out);
}

// Round 9
// 890.778 us; speedup vs baseline: 1.9090x; 1.0416x over previous
//
#include <hip/hip_runtime.h>

typedef short short8 __attribute__((ext_vector_type(8)));
typedef float f32x4 __attribute__((ext_vector_type(4)));

__device__ inline unsigned short f32_to_bf16_rne(float f) {
  unsigned int u = __float_as_uint(f);
  unsigned int r = (u + 0x7fffu + ((u >> 16) & 1u)) >> 16;
  return (unsigned short)r;
}
__device__ inline float bf16_to_f32(unsigned short h) {
  return __uint_as_float(((unsigned int)h) << 16);
}

// ---------------- workspace layout (float offsets) ----------------
// bf16 qkv: qh/ql -> Q region, kh/kl -> K region, vth/vtl (V^T [d][j]) -> V region
// att (O, fp32) -> ATT.  spart -> SPART; atth/attl (bf16 O^T) at SPART+2M/+3M
// score / idx / cout / y / t1
// aliases: whi/wlo (up-w) -> XD; dwhi/dwlo (down-w) -> SPART (dead before spart use)
//          xbh -> Q..K, xbl -> V..ATT (dead after conv_down)
//          coutT -> t1 region; dpart -> y region
constexpr size_t OFF_XD    = 0;
constexpr size_t OFF_Q     = 2097152;
constexpr size_t OFF_K     = 4194304;
constexpr size_t OFF_V     = 6291456;
constexpr size_t OFF_ATT   = 8388608;
constexpr size_t OFF_SPART = 10485760;
constexpr size_t OFF_SCORE = 14680064;
constexpr size_t OFF_IDX   = 14712832;
constexpr size_t OFF_COUT  = 14721024;
constexpr size_t OFF_Y     = 23109632;
constexpr size_t OFF_T1    = 31498240;
constexpr size_t WS_FLOATS = 39886848;

// ---------------- 0a. x NCHW -> NHWC split-bf16 (xbh/xbl [b][ih][iw][ci]) ------
__global__ __launch_bounds__(256) void k_x2bf(const float* __restrict__ x,
    unsigned short* __restrict__ xbh, unsigned short* __restrict__ xbl) {
  int bid = blockIdx.x;              // b*128 + ih*2 + iwh
  int b = bid >> 7;
  int ih = (bid >> 1) & 63;
  int iwh = bid & 1;
  int t = threadIdx.x;
  __shared__ float ts[256][33];
  for (int it = 0; it < 32; ++it) {
    int idx = it * 256 + t;
    int ci = idx >> 5;
    int iwl = idx & 31;
    ts[ci][iwl] = x[(((size_t)(b * 256 + ci) * 64 + ih) * 64) + iwh * 32 + iwl];
  }
  __syncthreads();
  int iwl = t >> 3;
  int cb = (t & 7) * 32;
  size_t base = (((size_t)(b * 64 + ih) * 64) + iwh * 32 + iwl) * 256 + cb;
#pragma unroll
  for (int j = 0; j < 32; j += 2) {
    float v0 = ts[cb + j][iwl];
    float v1 = ts[cb + j + 1][iwl];
    unsigned short h0 = f32_to_bf16_rne(v0);
    unsigned short h1 = f32_to_bf16_rne(v1);
    unsigned short l0 = f32_to_bf16_rne(v0 - bf16_to_f32(h0));
    unsigned short l1 = f32_to_bf16_rne(v1 - bf16_to_f32(h1));
    *(ushort2*)&xbh[base + j] = make_ushort2(h0, h1);
    *(ushort2*)&xbl[base + j] = make_ushort2(l0, l1);
  }
}

// ---------------- 0b. down_w -> split-bf16 dwhi/dwlo [kk][co][ci] --------------
__global__ __launch_bounds__(256) void k_wt_dnb(const float* __restrict__ w,
    unsigned short* __restrict__ dwhi, unsigned short* __restrict__ dwlo) {
  int idx = blockIdx.x * 256 + threadIdx.x;   // 1,048,576 = (kk*256+co)*256+ci
  int ci = idx & 255;
  int co = (idx >> 8) & 255;
  int kk = idx >> 16;
  float v = w[((size_t)(co * 256 + ci)) * 16 + kk];
  unsigned short h = f32_to_bf16_rne(v);
  unsigned short l = f32_to_bf16_rne(v - bf16_to_f32(h));
  dwhi[idx] = h;
  dwlo[idx] = l;
}

// ---------------- 0c. up_w -> split-bf16 whi/wlo [cls][tap][co][ci] ----------
__global__ __launch_bounds__(256) void k_wt_upb(const float* __restrict__ w,
    unsigned short* __restrict__ whi, unsigned short* __restrict__ wlo) {
  int idx = blockIdx.x * 256 + threadIdx.x;   // 1,048,576
  int ci = idx & 255;
  int co = (idx >> 8) & 255;
  int tp = idx >> 16;                         // 0..15
  int cls = tp >> 2, tap = tp & 3;
  int r = cls >> 1, s = cls & 1;
  int a_ = tap >> 1, b_ = tap & 1;
  int kh = a_ ? (r ? 2 : 3) : (r ? 0 : 1);
  int kw = b_ ? (s ? 2 : 3) : (s ? 0 : 1);
  float v = w[((size_t)(ci * 256 + co)) * 16 + kh * 4 + kw];
  unsigned short h = f32_to_bf16_rne(v);
  unsigned short l = f32_to_bf16_rne(v - bf16_to_f32(h));
  whi[idx] = h;
  wlo[idx] = l;
}

// ---------------- 1. down conv: split-bf16 MFMA implicit GEMM ------------------
__global__ __launch_bounds__(256) void k_conv_down_mfma(
    const unsigned short* __restrict__ xbh, const unsigned short* __restrict__ xbl,
    const unsigned short* __restrict__ dwhi, const unsigned short* __restrict__ dwlo,
    const float* __restrict__ bias, float* __restrict__ part) {
  int blk = blockIdx.x;              // ((ks*8 + b)*4 + ct)*32 + pt
  int pt = blk & 31;
  int ct = (blk >> 5) & 3;
  int b = (blk >> 7) & 7;
  int ks = blk >> 10;
  int oh2 = pt >> 1;                 // 0..15 (pair of oh rows)
  int owh = pt & 1;                  // ow half (16)
  int tid = threadIdx.x;
  int w = tid >> 6;                  // wave 0..3 -> co quarter
  int lane = tid & 63;
  int lq = lane >> 4;
  int lr = lane & 15;
  int co = ct * 64 + w * 16 + lr;

  __shared__ __align__(16) unsigned short AH[6][34][40];
  __shared__ __align__(16) unsigned short AL[6][34][40];

  f32x4 acc[2];
  acc[0] = (f32x4){0.f, 0.f, 0.f, 0.f};
  acc[1] = (f32x4){0.f, 0.f, 0.f, 0.f};

  int ih0 = 4 * oh2 - 1;             // tile row 0
  int iw0 = owh * 32 - 1;            // tile col 0
  const short8 zero8 = {0, 0, 0, 0, 0, 0, 0, 0};

  for (int ch = 0; ch < 2; ++ch) {
    int ci0 = ks * 64 + ch * 32;
    __syncthreads();
    for (int idx = tid; idx < 6 * 34 * 4; idx += 256) {
      int q = idx & 3;
      int cell = idx >> 2;
      int row = cell / 34;
      int col = cell - row * 34;
      int ih = ih0 + row;
      int iw = iw0 + col;
      short8 h = zero8, l = zero8;
      if ((unsigned)ih < 64u && (unsigned)iw < 64u) {
        size_t gg = (((size_t)(b * 64 + ih) * 64) + iw) * 256 + ci0 + q * 8;
        h = *(const short8*)&xbh[gg];
        l = *(const short8*)&xbl[gg];
      }
      *(short8*)&AH[row][col][q * 8] = h;
      *(short8*)&AL[row][col][q * 8] = l;
    }
    __syncthreads();
#pragma unroll
    for (int tap = 0; tap < 16; ++tap) {
      int kh = tap >> 2, kw = tap & 3;
      size_t woff = ((size_t)tap * 256 + co) * 256 + ci0 + 8 * lq;
      short8 bh = *(const short8*)&dwhi[woff];
      short8 bl = *(const short8*)&dwlo[woff];
#pragma unroll
      for (int pf = 0; pf < 2; ++pf) {
        short8 ah = *(const short8*)&AH[2 * pf + kh][2 * lr + kw][8 * lq];
        short8 al = *(const short8*)&AL[2 * pf + kh][2 * lr + kw][8 * lq];
        acc[pf] = __builtin_amdgcn_mfma_f32_16x16x32_bf16(ah, bh, acc[pf], 0, 0, 0);
        acc[pf] = __builtin_amdgcn_mfma_f32_16x16x32_bf16(al, bh, acc[pf], 0, 0, 0);
        acc[pf] = __builtin_amdgcn_mfma_f32_16x16x32_bf16(ah, bl, acc[pf], 0, 0, 0);
      }
    }
  }

  float bv = (ks == 0) ? bias[co] : 0.f;
  int bn = b * 4 + ct;
  int d = w * 16 + lr;
  float* pb = part + (size_t)ks * 2097152;
#pragma unroll
  for (int pf = 0; pf < 2; ++pf) {
    int oh = 2 * oh2 + pf;
#pragma unroll
    for (int reg = 0; reg < 4; ++reg) {
      int ow = owh * 16 + lq * 4 + reg;
      int pix = oh * 32 + ow;
      pb[((size_t)bn * 1024 + pix) * 64 + d] = acc[pf][reg] + bv;
    }
  }
}

// ---------------- 2. QKV coarse v2: 64-row tile, waves = (q,k,v), coalesced ----
__global__ __launch_bounds__(192) void k_qkv_coarse(const float* __restrict__ part,
    const float* __restrict__ W, const float* __restrict__ bias,
    unsigned short* __restrict__ qh, unsigned short* __restrict__ ql,
    unsigned short* __restrict__ kh, unsigned short* __restrict__ kl,
    unsigned short* __restrict__ vth, unsigned short* __restrict__ vtl) {
  int blk = blockIdx.x;
  int bn = blk >> 4;
  int i0 = (blk & 15) * 64;
  int tid = threadIdx.x;
  int w = tid >> 6;                  // 0=q, 1=k, 2=v
  int lane = tid & 63;

  __shared__ __align__(16) char lraw[66560];
  float (*ts)[68] = (float(*)[68])lraw;                 // [64][68]
  float (*Ws)[64] = (float(*)[64])(lraw + 17408);       // [192][64]

  for (int idx = tid; idx < 1024; idx += 192) {
    int row = idx >> 4, c4 = (idx & 15) * 4;
    size_t o = ((size_t)(bn * 1024 + i0 + row)) * 64 + c4;
    float4 v0 = *(const float4*)&part[o];
    float4 v1 = *(const float4*)&part[o + 2097152];
    float4 v2 = *(const float4*)&part[o + 2 * 2097152];
    float4 v3 = *(const float4*)&part[o + 3 * 2097152];
    float4 sv = make_float4(((v0.x + v1.x) + v2.x) + v3.x,
                            ((v0.y + v1.y) + v2.y) + v3.y,
                            ((v0.z + v1.z) + v2.z) + v3.z,
                            ((v0.w + v1.w) + v2.w) + v3.w);
    *(float4*)&ts[row][c4] = sv;
  }
  for (int idx = tid; idx < 3072; idx += 192) {
    int e = idx >> 4, c4 = (idx & 15) * 4;
    *(float4*)&Ws[e][c4] = *(const float4*)&W[(size_t)e * 64 + c4];
  }
  __syncthreads();

  float t[64];
#pragma unroll
  for (int c = 0; c < 16; ++c) {
    float4 v = *(const float4*)&ts[lane][c * 4];
    t[c * 4] = v.x; t[c * 4 + 1] = v.y; t[c * 4 + 2] = v.z; t[c * 4 + 3] = v.w;
  }
  int e0 = w * 64;
  short8 ph[8], pl[8];
#pragma unroll
  for (int ec = 0; ec < 8; ++ec) {
    short8 hh, ll;
#pragma unroll
    for (int k = 0; k < 8; ++k) {
      int e = e0 + ec * 8 + k;
      float acc = bias[e];
#pragma unroll
      for (int d = 0; d < 64; ++d) acc = fmaf(t[d], Ws[e][d], acc);
      unsigned short h = f32_to_bf16_rne(acc);
      hh[k] = (short)h;
      ll[k] = (short)f32_to_bf16_rne(acc - bf16_to_f32(h));
    }
    ph[ec] = hh; pl[ec] = ll;
  }
  __syncthreads();   // all waves done reading ts/Ws -> reuse LDS for out staging
  unsigned short* outH = (unsigned short*)(lraw + w * 18432);
  unsigned short* outL = (unsigned short*)(lraw + w * 18432 + 9216);
#pragma unroll
  for (int ec = 0; ec < 8; ++ec) {
    *(short8*)&outH[lane * 72 + ec * 8] = ph[ec];
    *(short8*)&outL[lane * 72 + ec * 8] = pl[ec];
  }
  // same-wave RAW below: no barrier needed
  if (w < 2) {
    unsigned short* dh = w ? kh : qh;
    unsigned short* dl = w ? kl : ql;
#pragma unroll
    for (int k = 0; k < 8; ++k) {
      int flat = (lane + k * 64) * 8;
      int row = flat >> 6, d = flat & 63;
      size_t go = ((size_t)(bn * 1024 + i0 + row)) * 64 + d;
      *(short8*)&dh[go] = *(const short8*)&outH[row * 72 + d];
      *(short8*)&dl[go] = *(const short8*)&outL[row * 72 + d];
    }
  } else {
    int db = lane >> 3, i8 = (lane & 7) * 8;
#pragma unroll
    for (int k = 0; k < 8; ++k) {
      int dd = db + k * 8;
      short8 hh, ll;
#pragma unroll
      for (int tt = 0; tt < 8; ++tt) {
        hh[tt] = (short)outH[(i8 + tt) * 72 + dd];
        ll[tt] = (short)outL[(i8 + tt) * 72 + dd];
      }
      size_t go = ((size_t)(bn * 64 + dd)) * 1024 + i0 + i8;
      *(short8*)&vth[go] = hh;
      *(short8*)&vtl[go] = ll;
    }
  }
}

// ---------------- 3. QKV topk v2: gathered 64-row tile, same core --------------
__global__ __launch_bounds__(192) void k_qkv_topk(const float* __restrict__ coutT,
    const int* __restrict__ idxb, const float* __restrict__ W, const float* __restrict__ bias,
    unsigned short* __restrict__ qh, unsigned short* __restrict__ ql,
    unsigned short* __restrict__ kh, unsigned short* __restrict__ kl,
    unsigned short* __restrict__ vth, unsigned short* __restrict__ vtl) {
  int blk = blockIdx.x;
  int bn = blk >> 4;
  int i0 = (blk & 15) * 64;
  int tid = threadIdx.x;
  int w = tid >> 6;
  int lane = tid & 63;

  __shared__ __align__(16) char lraw[66560];
  float (*ts)[68] = (float(*)[68])lraw;
  float (*Ws)[64] = (float(*)[64])(lraw + 17408);
  __shared__ int gs[64];

  if (tid < 64) {
    int row = tid;
    int p = idxb[bn * 256 + ((i0 + row) >> 2)] & 1023;
    int a = (row >> 1) & 1, b = row & 1;
    gs[row] = ((p >> 5) * 2 + a) * 64 + (p & 31) * 2 + b;
  }
  __syncthreads();
  for (int idx = tid; idx < 1024; idx += 192) {
    int row = idx >> 4, c4 = (idx & 15) * 4;
    *(float4*)&ts[row][c4] =
        *(const float4*)&coutT[((size_t)bn * 4096 + gs[row]) * 64 + c4];
  }
  for (int idx = tid; idx < 3072; idx += 192) {
    int e = idx >> 4, c4 = (idx & 15) * 4;
    *(float4*)&Ws[e][c4] = *(const float4*)&W[(size_t)e * 64 + c4];
  }
  __syncthreads();

  float t[64];
#pragma unroll
  for (int c = 0; c < 16; ++c) {
    float4 v = *(const float4*)&ts[lane][c * 4];
    t[c * 4] = v.x; t[c * 4 + 1] = v.y; t[c * 4 + 2] = v.z; t[c * 4 + 3] = v.w;
  }
  int e0 = w * 64;
  short8 ph[8], pl[8];
#pragma unroll
  for (int ec = 0; ec < 8; ++ec) {
    short8 hh, ll;
#pragma unroll
    for (int k = 0; k < 8; ++k) {
      int e = e0 + ec * 8 + k;
      float acc = bias[e];
#pragma unroll
      for (int d = 0; d < 64; ++d) acc = fmaf(t[d], Ws[e][d], acc);
      unsigned short h = f32_to_bf16_rne(acc);
      hh[k] = (short)h;
      ll[k] = (short)f32_to_bf16_rne(acc - bf16_to_f32(h));
    }
    ph[ec] = hh; pl[ec] = ll;
  }
  __syncthreads();
  unsigned short* outH = (unsigned short*)(lraw + w * 18432);
  unsigned short* outL = (unsigned short*)(lraw + w * 18432 + 9216);
#pragma unroll
  for (int ec = 0; ec < 8; ++ec) {
    *(short8*)&outH[lane * 72 + ec * 8] = ph[ec];
    *(short8*)&outL[lane * 72 + ec * 8] = pl[ec];
  }
  if (w < 2) {
    unsigned short* dh = w ? kh : qh;
    unsigned short* dl = w ? kl : ql;
#pragma unroll
    for (int k = 0; k < 8; ++k) {
      int flat = (lane + k * 64) * 8;
      int row = flat >> 6, d = flat & 63;
      size_t go = ((size_t)(bn * 1024 + i0 + row)) * 64 + d;
      *(short8*)&dh[go] = *(const short8*)&outH[row * 72 + d];
      *(short8*)&dl[go] = *(const short8*)&outL[row * 72 + d];
    }
  } else {
    int db = lane >> 3, i8 = (lane & 7) * 8;
#pragma unroll
    for (int k = 0; k < 8; ++k) {
      int dd = db + k * 8;
      short8 hh, ll;
#pragma unroll
      for (int tt = 0; tt < 8; ++tt) {
        hh[tt] = (short)outH[(i8 + tt) * 72 + dd];
        ll[tt] = (short)outL[(i8 + tt) * 72 + dd];
      }
      size_t go = ((size_t)(bn * 64 + dd)) * 1024 + i0 + i8;
      *(short8*)&vth[go] = hh;
      *(short8*)&vtl[go] = ll;
    }
  }
}

// ---------------- 4a. attention+score, split-bf16 MFMA (2-pass) ----------------
// LDS-staged Q/V per jt; XCD swizzle bn = blk&31. O^T emitted as bf16 hi/lo
// (atth/attl) so conv_up stages without converting.
__global__ __launch_bounds__(256) void k_attn_score_mfma(
    const unsigned short* __restrict__ qh, const unsigned short* __restrict__ ql,
    const unsigned short* __restrict__ kh, const unsigned short* __restrict__ kl,
    const unsigned short* __restrict__ vth, const unsigned short* __restrict__ vtl,
    float* __restrict__ spart, unsigned short* __restrict__ atth,
    unsigned short* __restrict__ attl) {
  int blk = blockIdx.x;
  int bn = blk & 31;                 // XCD-locality: same bn -> idx ≡ bn (mod 8)
  int it = blk >> 5;
  int tid = threadIdx.x;
  int w = tid >> 6;
  int lane = tid & 63;
  int g = lane >> 4;
  int c = lane & 15;
  size_t qb = (size_t)bn << 16;      // *65536 (u16 elements)

  __shared__ __align__(16) unsigned short QH[64][72];
  __shared__ __align__(16) unsigned short QL[64][72];
  __shared__ __align__(16) unsigned short VH[64][72];
  __shared__ __align__(16) unsigned short VL[64][72];
  __shared__ __align__(16) unsigned short PH[64][72];
  __shared__ __align__(16) unsigned short PL[64][72];
  __shared__ float sacc[1024];
  for (int i2 = tid; i2 < 1024; i2 += 256) sacc[i2] = 0.f;

  int r0 = tid >> 3;                 // staging row 0..31
  int c8 = (tid & 7) * 8;            // staging col (u16)

  // K A-frags for this wave's 16 rows (A row = lane&15)
  int irow = it * 64 + w * 16 + c;
  short8 kfh[2], kfl[2];
#pragma unroll
  for (int ch = 0; ch < 2; ++ch) {
    kfh[ch] = *(const short8*)&kh[qb + (size_t)irow * 64 + ch * 32 + g * 8];
    kfl[ch] = *(const short8*)&kl[qb + (size_t)irow * 64 + ch * 32 + g * 8];
  }

  float m[4], lsum[4];
#pragma unroll
  for (int r = 0; r < 4; ++r) { m[r] = -3.0e38f; lsum[r] = 0.f; }

  // ---- pass 1: row max / denom (Q staged in LDS per jt) ----
  for (int jt = 0; jt < 16; ++jt) {
    __syncthreads();
#pragma unroll
    for (int rr = 0; rr < 2; ++rr) {
      int row = r0 + rr * 32;
      size_t go = qb + (size_t)(jt * 64 + row) * 64 + c8;
      *(short8*)&QH[row][c8] = *(const short8*)&qh[go];
      *(short8*)&QL[row][c8] = *(const short8*)&ql[go];
    }
    __syncthreads();
    f32x4 s[4];
#pragma unroll
    for (int su = 0; su < 4; ++su) s[su] = (f32x4){0.f, 0.f, 0.f, 0.f};
#pragma unroll
    for (int ch = 0; ch < 2; ++ch)
#pragma unroll
      for (int su = 0; su < 4; ++su) {
        short8 qfh = *(const short8*)&QH[su * 16 + c][ch * 32 + g * 8];
        short8 qfl = *(const short8*)&QL[su * 16 + c][ch * 32 + g * 8];
        s[su] = __builtin_amdgcn_mfma_f32_16x16x32_bf16(kfh[ch], qfh, s[su], 0, 0, 0);
        s[su] = __builtin_amdgcn_mfma_f32_16x16x32_bf16(kfl[ch], qfh, s[su], 0, 0, 0);
        s[su] = __builtin_amdgcn_mfma_f32_16x16x32_bf16(kfh[ch], qfl, s[su], 0, 0, 0);
      }
#pragma unroll
    for (int r = 0; r < 4; ++r) {
      float tm = fmaxf(fmaxf(s[0][r], s[1][r]), fmaxf(s[2][r], s[3][r]));
#pragma unroll
      for (int off = 1; off <= 8; off <<= 1) tm = fmaxf(tm, __shfl_xor(tm, off, 64));
      float mn = fmaxf(m[r], tm);
      float ts = ((expf(s[0][r] - mn) + expf(s[1][r] - mn)) +
                  expf(s[2][r] - mn)) + expf(s[3][r] - mn);
#pragma unroll
      for (int off = 1; off <= 8; off <<= 1) ts += __shfl_xor(ts, off, 64);
      lsum[r] = lsum[r] * expf(m[r] - mn) + ts;
      m[r] = mn;
    }
  }
  float inv[4];
#pragma unroll
  for (int r = 0; r < 4; ++r) inv[r] = 1.f / lsum[r];

  f32x4 oacc[4];
#pragma unroll
  for (int d = 0; d < 4; ++d) oacc[d] = (f32x4){0.f, 0.f, 0.f, 0.f};

  // ---- pass 2: P, scores, PV (Q+V staged in LDS per jt) ----
  for (int jt = 0; jt < 16; ++jt) {
    __syncthreads();
#pragma unroll
    for (int rr = 0; rr < 2; ++rr) {
      int row = r0 + rr * 32;
      size_t go = qb + (size_t)(jt * 64 + row) * 64 + c8;
      *(short8*)&QH[row][c8] = *(const short8*)&qh[go];
      *(short8*)&QL[row][c8] = *(const short8*)&ql[go];
      size_t vo = ((size_t)(bn * 64 + row)) * 1024 + jt * 64 + c8;
      *(short8*)&VH[row][c8] = *(const short8*)&vth[vo];
      *(short8*)&VL[row][c8] = *(const short8*)&vtl[vo];
    }
    __syncthreads();
    f32x4 s[4];
#pragma unroll
    for (int su = 0; su < 4; ++su) s[su] = (f32x4){0.f, 0.f, 0.f, 0.f};
#pragma unroll
    for (int ch = 0; ch < 2; ++ch)
#pragma unroll
      for (int su = 0; su < 4; ++su) {
        short8 qfh = *(const short8*)&QH[su * 16 + c][ch * 32 + g * 8];
        short8 qfl = *(const short8*)&QL[su * 16 + c][ch * 32 + g * 8];
        s[su] = __builtin_amdgcn_mfma_f32_16x16x32_bf16(kfh[ch], qfh, s[su], 0, 0, 0);
        s[su] = __builtin_amdgcn_mfma_f32_16x16x32_bf16(kfl[ch], qfh, s[su], 0, 0, 0);
        s[su] = __builtin_amdgcn_mfma_f32_16x16x32_bf16(kfh[ch], qfl, s[su], 0, 0, 0);
      }
#pragma unroll
    for (int su = 0; su < 4; ++su) {
      float p0 = expf(s[su][0] - m[0]) * inv[0];
      float p1 = expf(s[su][1] - m[1]) * inv[1];
      float p2 = expf(s[su][2] - m[2]) * inv[2];
      float p3 = expf(s[su][3] - m[3]) * inv[3];
      float cs = ((p0 + p1) + p2) + p3;
      cs += __shfl_xor(cs, 16, 64);
      cs += __shfl_xor(cs, 32, 64);
      if (g == 0) atomicAdd(&sacc[jt * 64 + su * 16 + c], cs);
      unsigned short h0 = f32_to_bf16_rne(p0);
      unsigned short h1 = f32_to_bf16_rne(p1);
      unsigned short h2 = f32_to_bf16_rne(p2);
      unsigned short h3 = f32_to_bf16_rne(p3);
      PH[w * 16 + g * 4 + 0][su * 16 + c] = h0;
      PH[w * 16 + g * 4 + 1][su * 16 + c] = h1;
      PH[w * 16 + g * 4 + 2][su * 16 + c] = h2;
      PH[w * 16 + g * 4 + 3][su * 16 + c] = h3;
      PL[w * 16 + g * 4 + 0][su * 16 + c] = f32_to_bf16_rne(p0 - bf16_to_f32(h0));
      PL[w * 16 + g * 4 + 1][su * 16 + c] = f32_to_bf16_rne(p1 - bf16_to_f32(h1));
      PL[w * 16 + g * 4 + 2][su * 16 + c] = f32_to_bf16_rne(p2 - bf16_to_f32(h2));
      PL[w * 16 + g * 4 + 3][su * 16 + c] = f32_to_bf16_rne(p3 - bf16_to_f32(h3));
    }
#pragma unroll
    for (int ch = 0; ch < 2; ++ch) {
      short8 pfh = *(const short8*)&PH[w * 16 + c][ch * 32 + g * 8];
      short8 pfl = *(const short8*)&PL[w * 16 + c][ch * 32 + g * 8];
#pragma unroll
      for (int d = 0; d < 4; ++d) {
        short8 vfh = *(const short8*)&VH[d * 16 + c][ch * 32 + g * 8];
        short8 vfl = *(const short8*)&VL[d * 16 + c][ch * 32 + g * 8];
        oacc[d] = __builtin_amdgcn_mfma_f32_16x16x32_bf16(vfh, pfh, oacc[d], 0, 0, 0);
        oacc[d] = __builtin_amdgcn_mfma_f32_16x16x32_bf16(vfl, pfh, oacc[d], 0, 0, 0);
        oacc[d] = __builtin_amdgcn_mfma_f32_16x16x32_bf16(vfh, pfl, oacc[d], 0, 0, 0);
      }
    }
  }
  // O^T D-layout, emitted as split-bf16: lane holds O^T[d*16+g*4+r][it*64+w*16+c]
#pragma unroll
  for (int d = 0; d < 4; ++d)
#pragma unroll
    for (int r = 0; r < 4; ++r) {
      float v = oacc[d][r];
      unsigned short h = f32_to_bf16_rne(v);
      unsigned short l = f32_to_bf16_rne(v - bf16_to_f32(h));
      size_t o = ((size_t)bn * 64 + d * 16 + g * 4 + r) * 1024 + it * 64 + w * 16 + c;
      atth[o] = h;
      attl[o] = l;
    }
  __syncthreads();
  for (int i2 = tid; i2 < 1024; i2 += 256)
    spart[((size_t)bn * 16 + it) * 1024 + i2] = sacc[i2];
}

// ---------------- 4b. topk attention, split-bf16 MFMA (1-pass online) ----------
__global__ __launch_bounds__(256) void k_attn_online_mfma(
    const unsigned short* __restrict__ qh, const unsigned short* __restrict__ ql,
    const unsigned short* __restrict__ kh, const unsigned short* __restrict__ kl,
    const unsigned short* __restrict__ vth, const unsigned short* __restrict__ vtl,
    float* __restrict__ O) {
  int blk = blockIdx.x;
  int bn = blk & 31;                 // XCD-locality swizzle
  int it = blk >> 5;
  int tid = threadIdx.x;
  int w = tid >> 6;
  int lane = tid & 63;
  int g = lane >> 4;
  int c = lane & 15;
  size_t qb = (size_t)bn << 16;

  __shared__ __align__(16) unsigned short QH[64][72];
  __shared__ __align__(16) unsigned short QL[64][72];
  __shared__ __align__(16) unsigned short VH[64][72];
  __shared__ __align__(16) unsigned short VL[64][72];
  __shared__ __align__(16) unsigned short PH[64][72];
  __shared__ __align__(16) unsigned short PL[64][72];

  int r0 = tid >> 3;
  int c8 = (tid & 7) * 8;

  int irow = it * 64 + w * 16 + c;
  short8 kfh[2], kfl[2];
#pragma unroll
  for (int ch = 0; ch < 2; ++ch) {
    kfh[ch] = *(const short8*)&kh[qb + (size_t)irow * 64 + ch * 32 + g * 8];
    kfl[ch] = *(const short8*)&kl[qb + (size_t)irow * 64 + ch * 32 + g * 8];
  }

  float m[4], lsum[4];
  f32x4 oacc[4];
#pragma unroll
  for (int r = 0; r < 4; ++r) { m[r] = -3.0e38f; lsum[r] = 0.f; }
#pragma unroll
  for (int d = 0; d < 4; ++d) oacc[d] = (f32x4){0.f, 0.f, 0.f, 0.f};

  for (int jt = 0; jt < 16; ++jt) {
    __syncthreads();
#pragma unroll
    for (int rr = 0; rr < 2; ++rr) {
      int row = r0 + rr * 32;
      size_t go = qb + (size_t)(jt * 64 + row) * 64 + c8;
      *(short8*)&QH[row][c8] = *(const short8*)&qh[go];
      *(short8*)&QL[row][c8] = *(const short8*)&ql[go];
      size_t vo = ((size_t)(bn * 64 + row)) * 1024 + jt * 64 + c8;
      *(short8*)&VH[row][c8] = *(const short8*)&vth[vo];
      *(short8*)&VL[row][c8] = *(const short8*)&vtl[vo];
    }
    __syncthreads();
    f32x4 s[4];
#pragma unroll
    for (int su = 0; su < 4; ++su) s[su] = (f32x4){0.f, 0.f, 0.f, 0.f};
#pragma unroll
    for (int ch = 0; ch < 2; ++ch)
#pragma unroll
      for (int su = 0; su < 4; ++su) {
        short8 qfh = *(const short8*)&QH[su * 16 + c][ch * 32 + g * 8];
        short8 qfl = *(const short8*)&QL[su * 16 + c][ch * 32 + g * 8];
        s[su] = __builtin_amdgcn_mfma_f32_16x16x32_bf16(kfh[ch], qfh, s[su], 0, 0, 0);
        s[su] = __builtin_amdgcn_mfma_f32_16x16x32_bf16(kfl[ch], qfh, s[su], 0, 0, 0);
        s[su] = __builtin_amdgcn_mfma_f32_16x16x32_bf16(kfh[ch], qfl, s[su], 0, 0, 0);
      }
    float sc[4];
#pragma unroll
    for (int r = 0; r < 4; ++r) {
      float tm = fmaxf(fmaxf(s[0][r], s[1][r]), fmaxf(s[2][r], s[3][r]));
#pragma unroll
      for (int off = 1; off <= 8; off <<= 1) tm = fmaxf(tm, __shfl_xor(tm, off, 64));
      float mn = fmaxf(m[r], tm);
      sc[r] = expf(m[r] - mn);
      float p0 = expf(s[0][r] - mn);
      float p1 = expf(s[1][r] - mn);
      float p2 = expf(s[2][r] - mn);
      float p3 = expf(s[3][r] - mn);
      s[0][r] = p0; s[1][r] = p1; s[2][r] = p2; s[3][r] = p3;
      float ts = ((p0 + p1) + p2) + p3;
#pragma unroll
      for (int off = 1; off <= 8; off <<= 1) ts += __shfl_xor(ts, off, 64);
      lsum[r] = lsum[r] * sc[r] + ts;
      m[r] = mn;
    }
#pragma unroll
    for (int su = 0; su < 4; ++su) {
      unsigned short h0 = f32_to_bf16_rne(s[su][0]);
      unsigned short h1 = f32_to_bf16_rne(s[su][1]);
      unsigned short h2 = f32_to_bf16_rne(s[su][2]);
      unsigned short h3 = f32_to_bf16_rne(s[su][3]);
      PH[w * 16 + g * 4 + 0][su * 16 + c] = h0;
      PH[w * 16 + g * 4 + 1][su * 16 + c] = h1;
      PH[w * 16 + g * 4 + 2][su * 16 + c] = h2;
      PH[w * 16 + g * 4 + 3][su * 16 + c] = h3;
      PL[w * 16 + g * 4 + 0][su * 16 + c] = f32_to_bf16_rne(s[su][0] - bf16_to_f32(h0));
      PL[w * 16 + g * 4 + 1][su * 16 + c] = f32_to_bf16_rne(s[su][1] - bf16_to_f32(h1));
      PL[w * 16 + g * 4 + 2][su * 16 + c] = f32_to_bf16_rne(s[su][2] - bf16_to_f32(h2));
      PL[w * 16 + g * 4 + 3][su * 16 + c] = f32_to_bf16_rne(s[su][3] - bf16_to_f32(h3));
    }
    // rescale oacc by sc for col i=c (branchless select + shfl, rule #20 safe)
    float s01 = (c & 1) ? sc[1] : sc[0];
    float s23 = (c & 1) ? sc[3] : sc[2];
    float tmp = (c & 2) ? s23 : s01;
    float scc = __shfl(tmp, ((c >> 2) << 4) | c, 64);
#pragma unroll
    for (int d = 0; d < 4; ++d) oacc[d] *= scc;
#pragma unroll
    for (int ch = 0; ch < 2; ++ch) {
      short8 pfh = *(const short8*)&PH[w * 16 + c][ch * 32 + g * 8];
      short8 pfl = *(const short8*)&PL[w * 16 + c][ch * 32 + g * 8];
#pragma unroll
      for (int d = 0; d < 4; ++d) {
        short8 vfh = *(const short8*)&VH[d * 16 + c][ch * 32 + g * 8];
        short8 vfl = *(const short8*)&VL[d * 16 + c][ch * 32 + g * 8];
        oacc[d] = __builtin_amdgcn_mfma_f32_16x16x32_bf16(vfh, pfh, oacc[d], 0, 0, 0);
        oacc[d] = __builtin_amdgcn_mfma_f32_16x16x32_bf16(vfl, pfh, oacc[d], 0, 0, 0);
        oacc[d] = __builtin_amdgcn_mfma_f32_16x16x32_bf16(vfh, pfl, oacc[d], 0, 0, 0);
      }
    }
  }
  float i01 = (c & 1) ? (1.f / lsum[1]) : (1.f / lsum[0]);
  float i23 = (c & 1) ? (1.f / lsum[3]) : (1.f / lsum[2]);
  float itmp = (c & 2) ? i23 : i01;
  float invc = __shfl(itmp, ((c >> 2) << 4) | c, 64);
  // O natural [i][d]: lane col i = it*64+w*16+c; rows d = d*16+g*4+reg (contig f32x4)
#pragma unroll
  for (int d = 0; d < 4; ++d) {
    f32x4 o4 = oacc[d] * invc;
    *(f32x4*)&O[((size_t)bn * 1024 + it * 64 + w * 16 + c) * 64 + d * 16 + g * 4] = o4;
  }
}

// ---------------- 5. deterministic score reduction (16 partials) ----------------
__global__ __launch_bounds__(256) void k_score_reduce(const float* __restrict__ part,
                                                      float* __restrict__ score) {
  int j = blockIdx.x * 256 + threadIdx.x;   // 0..32767
  int bn = j >> 10, jj = j & 1023;
  float s = 0.f;
  for (int g = 0; g < 16; ++g) s += part[((size_t)bn * 16 + g) * 1024 + jj];
  score[j] = s;
}

// ---------------- 5b. default-init idx ----------------
__global__ __launch_bounds__(256) void k_idx_init(int* __restrict__ idx) {
  int j = blockIdx.x * 256 + threadIdx.x;
  idx[j] = j & 255;
}

// ---------------- 6. top-K by rank ----------------
__global__ __launch_bounds__(1024) void k_topk(const float* __restrict__ score,
                                               int* __restrict__ idxout) {
  int bn = blockIdx.x;
  int t = threadIdx.x;
  __shared__ float s[1024];
  s[t] = score[bn * 1024 + t];
  __syncthreads();
  float my = s[t];
  int rank = 0;
  for (int j = 0; j < 1024; ++j) {
    float o = s[j];
    rank += (o > my) || (o == my && j < t);
  }
  if (rank < 256) idxout[bn * 256 + rank] = t;
}

// ---------------- 7. transposed conv v5: block = (b, r, I), 256 co + both s ----
// Staging amortized 8x vs v4 (no ct/s split, no conversion: atth/attl pre-split).
// cout store: float2 over (2J, 2J+1) -> fixes stride-2 write amplification.
__global__ __launch_bounds__(256) void k_conv_up_mfma(
    const unsigned short* __restrict__ atth, const unsigned short* __restrict__ attl,
    const unsigned short* __restrict__ whi, const unsigned short* __restrict__ wlo,
    const float* __restrict__ bias, float* __restrict__ cout,
    float* __restrict__ coutT) {
  int blk = blockIdx.x;              // (b*2 + r)*32 + I
  int I = blk & 31;
  int r = (blk >> 5) & 1;
  int b = blk >> 6;
  int tid = threadIdx.x;
  int w = tid >> 6;                  // wave -> co block w*64 (bn = b*4 + w)
  int lane = tid & 63;
  int lq = lane >> 4;
  int lr = lane & 15;

  __shared__ __align__(16) unsigned short AH[2][34][40];
  __shared__ __align__(16) unsigned short AL[2][34][40];

  f32x4 acc[2][2][4];                // [s][pfJ][cf]
#pragma unroll
  for (int s = 0; s < 2; ++s)
#pragma unroll
    for (int pf = 0; pf < 2; ++pf)
#pragma unroll
      for (int cf = 0; cf < 4; ++cf) acc[s][pf][cf] = (f32x4){0.f, 0.f, 0.f, 0.f};

  const unsigned short* abh = atth + (size_t)b * 262144;
  const unsigned short* abl = attl + (size_t)b * 262144;
  int ih0 = I + r - 1;

  for (int ci0 = 0; ci0 < 256; ci0 += 32) {
    int n = ci0 >> 6, d0 = ci0 & 63;
    __syncthreads();
    // stage 2 ih-rows x 34 iw x 32 ci (pure copy, no conversion)
    for (int idx = tid; idx < 2176; idx += 256) {
      int cr = idx / 34;             // ciL*2 + rho
      int col = idx - cr * 34;
      int ciL = cr >> 1, rho = cr & 1;
      int ih = ih0 + rho;
      int iw = col - 1;
      unsigned short h = 0, l = 0;
      if ((unsigned)ih < 32u && (unsigned)iw < 32u) {
        size_t gg = ((size_t)(n * 64 + d0 + ciL)) * 1024 + ih * 32 + iw;
        h = abh[gg];
        l = abl[gg];
      }
      AH[rho][col][ciL] = h;
      AL[rho][col][ciL] = l;
    }
    __syncthreads();
#pragma unroll
    for (int tap = 0; tap < 4; ++tap) {
      int a_ = tap >> 1, b_ = tap & 1;
      int rho = 1 - a_;
#pragma unroll
      for (int s = 0; s < 2; ++s) {
        int cls = r * 2 + s;
        size_t wb = (size_t)(cls * 4 + tap) * 65536;
        short8 bh[4], bl[4];
#pragma unroll
        for (int cf = 0; cf < 4; ++cf) {
          size_t off = wb + (size_t)(w * 64 + cf * 16 + lr) * 256 + ci0 + 8 * lq;
          bh[cf] = *(const short8*)&whi[off];
          bl[cf] = *(const short8*)&wlo[off];
        }
        short8 ah[2], al[2];
#pragma unroll
        for (int pf = 0; pf < 2; ++pf) {
          int col = pf * 16 + lr + s - b_ + 1;
          ah[pf] = *(const short8*)&AH[rho][col][8 * lq];
          al[pf] = *(const short8*)&AL[rho][col][8 * lq];
        }
#pragma unroll
        for (int pf = 0; pf < 2; ++pf)
#pragma unroll
          for (int cf = 0; cf < 4; ++cf) {
            acc[s][pf][cf] = __builtin_amdgcn_mfma_f32_16x16x32_bf16(ah[pf], bh[cf], acc[s][pf][cf], 0, 0, 0);
            acc[s][pf][cf] = __builtin_amdgcn_mfma_f32_16x16x32_bf16(al[pf], bh[cf], acc[s][pf][cf], 0, 0, 0);
            acc[s][pf][cf] = __builtin_amdgcn_mfma_f32_16x16x32_bf16(ah[pf], bl[cf], acc[s][pf][cf], 0, 0, 0);
          }
      }
    }
  }

  int oh = 2 * I + r;
#pragma unroll
  for (int cf = 0; cf < 4; ++cf) {
    int co = w * 64 + cf * 16 + lr;
    float bv = bias[co];
    size_t cbase = ((size_t)b * 256 + co) * 4096 + (size_t)oh * 64;
    size_t tbase = (((size_t)(b * 4 + w) * 4096) + oh * 64) * 64 + (co & 63);
#pragma unroll
    for (int pf = 0; pf < 2; ++pf)
#pragma unroll
      for (int reg = 0; reg < 4; ++reg) {
        int J = pf * 16 + lq * 4 + reg;
        float v0 = acc[0][pf][cf][reg] + bv;
        float v1 = acc[1][pf][cf][reg] + bv;
        *(float2*)&cout[cbase + 2 * J] = make_float2(v0, v1);
        coutT[tbase + (size_t)(2 * J) * 64] = v0;
        coutT[tbase + (size_t)(2 * J + 1) * 64] = v1;
      }
  }
}

// ---------------- 8. y = coarse_out + region ----------------
__global__ __launch_bounds__(256) void k_ybuild(const float* __restrict__ cout,
                                                float* __restrict__ y) {
  size_t e = (size_t)blockIdx.x * 256 + threadIdx.x;
  int flat = (int)(e & 4095);
  size_t bc = e >> 12;
  int p = flat >> 2, ab = flat & 3;
  int a = ab >> 1, bi = ab & 1;
  int src = ((p >> 5) * 2 + a) * 64 + (p & 31) * 2 + bi;
  const float* cb = cout + bc * 4096;
  y[e] = cb[flat] + cb[src];
}

// ---------------- 9. scatter-add attended tokens ----------------
__global__ __launch_bounds__(256) void k_scatter(const float* __restrict__ out2,
    const int* __restrict__ idx, float* __restrict__ y) {
  int e = blockIdx.x * 256 + threadIdx.x;
  int d = e & 63;
  int r = e >> 6;
  int ab = r & 3;
  int r2 = r >> 2;
  int kk = r2 & 255;
  int bn = r2 >> 8;
  int b = bn >> 2, n = bn & 3;
  int p = idx[bn * 256 + kk] & 1023;
  int flat = p * 4 + ab;
  int t = kk * 4 + ab;
  y[((size_t)(b * 256 + n * 64 + d)) * 4096 + flat] +=
      out2[((size_t)bn * 1024 + t) * 64 + d];
}

// ---------------- 10. depthwise 3x3 + BN + relu6 ----------------
__global__ __launch_bounds__(256) void k_dw(const float* __restrict__ y,
    const float* __restrict__ w, const float* __restrict__ g, const float* __restrict__ bb,
    const float* __restrict__ mm, const float* __restrict__ vv, float* __restrict__ t1) {
  size_t e = (size_t)blockIdx.x * 256 + threadIdx.x;
  int pix = (int)(e & 4095);
  int c = (int)((e >> 12) & 255);
  int oh = pix >> 6, ow = pix & 63;
  const float* yb = y + (e - pix);
  float acc = 0.f;
#pragma unroll
  for (int kh = 0; kh < 3; ++kh) {
    int ih = oh - 1 + kh;
    if ((unsigned)ih >= 64u) continue;
#pragma unroll
    for (int kw = 0; kw < 3; ++kw) {
      int iw = ow - 1 + kw;
      if ((unsigned)iw >= 64u) continue;
      acc = fmaf(yb[ih * 64 + iw], w[c * 9 + kh * 3 + kw], acc);
    }
  }
  float s = g[c] * rsqrtf(vv[c] + 1e-5f);
  float val = acc * s + (bb[c] - mm[c] * s);
  t1[e] = fminf(fmaxf(val, 0.f), 6.f);
}

// ---------------- 11. pointwise v2: 4 co per block, 16 FMA per 16B load --------
__global__ __launch_bounds__(256) void k_pw2(const float* __restrict__ t1,
    const float* __restrict__ w, const float* __restrict__ g, const float* __restrict__ bb,
    const float* __restrict__ mm, const float* __restrict__ vv, float* __restrict__ out) {
  int blk = blockIdx.x;              // (b*64 + cog)*4 + tile
  int tile = blk & 3;
  int cog = (blk >> 2) & 63;
  int b = blk >> 8;
  int co0 = cog * 4;
  int t = threadIdx.x;
  __shared__ float wl[256][4];
  for (int idx = t; idx < 1024; idx += 256) {
    int cof = idx >> 8;
    int ci = idx & 255;
    wl[ci][cof] = w[(co0 + cof) * 256 + ci];
  }
  __syncthreads();
  int px0 = tile * 1024 + t * 4;
  const float* tb = t1 + (size_t)b * 256 * 4096 + px0;
  float acc[4][4];
#pragma unroll
  for (int a = 0; a < 4; ++a)
#pragma unroll
    for (int jj = 0; jj < 4; ++jj) acc[a][jj] = 0.f;
  for (int ci = 0; ci < 256; ++ci) {
    float4 tv = *(const float4*)(tb + (size_t)ci * 4096);
    float4 wv = *(const float4*)&wl[ci][0];
    acc[0][0] = fmaf(tv.x, wv.x, acc[0][0]); acc[0][1] = fmaf(tv.y, wv.x, acc[0][1]);
    acc[0][2] = fmaf(tv.z, wv.x, acc[0][2]); acc[0][3] = fmaf(tv.w, wv.x, acc[0][3]);
    acc[1][0] = fmaf(tv.x, wv.y, acc[1][0]); acc[1][1] = fmaf(tv.y, wv.y, acc[1][1]);
    acc[1][2] = fmaf(tv.z, wv.y, acc[1][2]); acc[1][3] = fmaf(tv.w, wv.y, acc[1][3]);
    acc[2][0] = fmaf(tv.x, wv.z, acc[2][0]); acc[2][1] = fmaf(tv.y, wv.z, acc[2][1]);
    acc[2][2] = fmaf(tv.z, wv.z, acc[2][2]); acc[2][3] = fmaf(tv.w, wv.z, acc[2][3]);
    acc[3][0] = fmaf(tv.x, wv.w, acc[3][0]); acc[3][1] = fmaf(tv.y, wv.w, acc[3][1]);
    acc[3][2] = fmaf(tv.z, wv.w, acc[3][2]); acc[3][3] = fmaf(tv.w, wv.w, acc[3][3]);
  }
#pragma unroll
  for (int a = 0; a < 4; ++a) {
    int co = co0 + a;
    float s = g[co] * rsqrtf(vv[co] + 1e-5f);
    float bias = bb[co] - mm[co] * s;
    float4 o4;
    o4.x = fminf(fmaxf(acc[a][0] * s + bias, 0.f), 6.f);
    o4.y = fminf(fmaxf(acc[a][1] * s + bias, 0.f), 6.f);
    o4.z = fminf(fmaxf(acc[a][2] * s + bias, 0.f), 6.f);
    o4.w = fminf(fmaxf(acc[a][3] * s + bias, 0.f), 6.f);
    *(float4*)(out + ((size_t)(b * 256 + co)) * 4096 + px0) = o4;
  }
}

// ---------------- launcher ----------------
extern "C" void kernel_launch(void* const* d_in, const int* in_sizes, int n_in,
                              void* d_out, int out_size, void* d_ws, size_t ws_size,
                              hipStream_t stream) {
  if (ws_size < WS_FLOATS * sizeof(float)) return;

  const float* x      = (const float*)d_in[0];
  const float* down_w = (const float*)d_in[1];
  const float* down_b = (const float*)d_in[2];
  const float* up_w   = (const float*)d_in[3];
  const float* up_b   = (const float*)d_in[4];
  const float* cqkv_w = (const float*)d_in[5];
  const float* cqkv_b = (const float*)d_in[6];
  const float* tqkv_w = (const float*)d_in[7];
  const float* tqkv_b = (const float*)d_in[8];
  const float* dww    = (const float*)d_in[9];
  const float* bn1g   = (const float*)d_in[10];
  const float* bn1b   = (const float*)d_in[11];
  const float* bn1m   = (const float*)d_in[12];
  const float* bn1v   = (const float*)d_in[13];
  const float* pww    = (const float*)d_in[14];
  const float* bn2g   = (const float*)d_in[15];
  const float* bn2b   = (const float*)d_in[16];
  const float* bn2m   = (const float*)d_in[17];
  const float* bn2v   = (const float*)d_in[18];

  float* ws    = (float*)d_ws;
  float* att   = ws + OFF_ATT;
  float* spart = ws + OFF_SPART;
  float* score = ws + OFF_SCORE;
  int*   idx   = (int*)(ws + OFF_IDX);
  float* cout  = ws + OFF_COUT;
  float* y     = ws + OFF_Y;
  float* t1    = ws + OFF_T1;
  unsigned short* atth = (unsigned short*)(ws + OFF_SPART + 2097152);  // O^T hi (2M u16)
  unsigned short* attl = (unsigned short*)(ws + OFF_SPART + 3145728);  // O^T lo (2M u16)
  unsigned short* whi  = (unsigned short*)(ws + OFF_XD);            // up-w hi
  unsigned short* wlo  = (unsigned short*)(ws + OFF_XD + 524288);   // up-w lo
  unsigned short* dwhi = (unsigned short*)(ws + OFF_SPART);             // down-w hi (dead after conv_down)
  unsigned short* dwlo = (unsigned short*)(ws + OFF_SPART + 524288);    // down-w lo
  unsigned short* xbh  = (unsigned short*)(ws + OFF_Q);   // x hi (Q..K regions, dead after conv_down)
  unsigned short* xbl  = (unsigned short*)(ws + OFF_V);   // x lo (V..ATT regions, dead after conv_down)
  unsigned short* qh   = (unsigned short*)(ws + OFF_Q);
  unsigned short* ql   = (unsigned short*)(ws + OFF_Q + 1048576);
  unsigned short* kh   = (unsigned short*)(ws + OFF_K);
  unsigned short* kl   = (unsigned short*)(ws + OFF_K + 1048576);
  unsigned short* vth  = (unsigned short*)(ws + OFF_V);
  unsigned short* vtl  = (unsigned short*)(ws + OFF_V + 1048576);
  float* coutT = ws + OFF_T1;                // t1 region dead until k_dw
  float* dpart = ws + OFF_Y;                 // 4 x 2M ci-split partials (dead until k_ybuild)

  k_x2bf<<<1024, 256, 0, stream>>>(x, xbh, xbl);
  k_wt_dnb<<<4096, 256, 0, stream>>>(down_w, dwhi, dwlo);
  k_conv_down_mfma<<<4096, 256, 0, stream>>>(xbh, xbl, dwhi, dwlo, down_b, dpart);
  k_qkv_coarse<<<512, 192, 0, stream>>>(dpart, cqkv_w, cqkv_b, qh, ql, kh, kl, vth, vtl);
  k_wt_upb<<<4096, 256, 0, stream>>>(up_w, whi, wlo);
  k_attn_score_mfma<<<512, 256, 0, stream>>>(qh, ql, kh, kl, vth, vtl, spart, atth, attl);
  k_score_reduce<<<128, 256, 0, stream>>>(spart, score);
  k_idx_init<<<32, 256, 0, stream>>>(idx);
  k_topk<<<32, 1024, 0, stream>>>(score, idx);
  k_conv_up_mfma<<<512, 256, 0, stream>>>(atth, attl, whi, wlo, up_b, cout, coutT);
  k_qkv_topk<<<512, 192, 0, stream>>>(coutT, idx, tqkv_w, tqkv_b, qh, ql, kh, kl, vth, vtl);
  k_attn_online_mfma<<<512, 256, 0, stream>>>(qh, ql, kh, kl, vth, vtl, att);
  k_ybuild<<<32768, 256, 0, stream>>>(cout, y);
  k_scatter<<<8192, 256, 0, stream>>>(att, idx, y);
  k_dw<<<32768, 256, 0, stream>>>(y, dww, bn1g, bn1b, bn1m, bn1v, t1);
  k_pw2<<<2048, 256, 0, stream>>>(t1, pww, bn2g, bn2b, bn2m, bn2v, (float*)d_out);
}